// Round 1
// baseline (6993.675 us; speedup 1.0000x reference)
//
#include <hip/hip_runtime.h>
#include <hip/hip_bf16.h>
#include <cstdint>

// AttnLayerBU: DIM=256, NH=8, hd=32; B=16, L_INNER=128, L_LEAF=64, L_ROOT=16.
// Round 1: correct fp32 implementation.
//   leaf_p degenerates (softmax over 1 key == 1) -> per-inner-token vec, broadcast.
//   Generic fused per-(batch,head) attention kernel computes Q/K/V proj in-block
//   (weights from L2, k-outer register-cached), attention in LDS, O -> ws fp32.
//   Combine kernels do out-proj + softmax-weighted mixing.
// ws usage: ~136.6 MB fp32 intermediates.

#define DIM 256
#define NH 8
#define HD 32

static constexpr float SCALE = 0.17677669529663687f; // 32^-0.5

__device__ __forceinline__ float dot4(const float4 a, const float4 b) {
    return a.x * b.x + a.y * b.y + a.z * b.z + a.w * b.w;
}

// ---------------------------------------------------------------------------
// Fused attention: one block per (batch, head). Computes
//   Q = (Xq  @ Wq^T + bq) * SCALE      (rows   0..255 of Wi)
//   K = (Xkv @ Wk^T + bk)              (rows 256..511)
//   V = (Xkv @ Wv^T + bv)              (rows 512..767)
//   O[b, t, h*32+d] = softmax(Q K^T)[t,:] . V[:,d]
// ---------------------------------------------------------------------------
template <int LQ, int LK, int RQ>
__global__ __launch_bounds__(256) void attn_fused(
    const float* __restrict__ Xq, const float* __restrict__ Xkv,
    const float* __restrict__ Wi, const float* __restrict__ Bi,
    float* __restrict__ O)
{
    const int b   = blockIdx.x >> 3;
    const int h   = blockIdx.x & 7;
    const int tid = threadIdx.x;

    __shared__ float Ks[LK][33];     // +1 pad: stride 33 coprime with 32 banks
    __shared__ float Vs[LK][33];
    __shared__ float Qs[LQ][33];
    __shared__ float S[RQ][LK + 1];

    const float* xq  = Xq  + (size_t)b * LQ * DIM;
    const float* xkv = Xkv + (size_t)b * LK * DIM;

    // ---- K,V projection: thread -> (which,d) = tid&63, t-group = tid>>6 ----
    {
        const int col   = tid & 63;
        const int which = col >> 5;          // 0 = K, 1 = V
        const int d     = col & 31;
        const int row   = DIM + which * DIM + h * HD + d;
        const float4* wr = (const float4*)(Wi + (size_t)row * DIM);
        const float bias = Bi[row];
        constexpr int TT = LK / 4;
        float acc[TT];
#pragma unroll
        for (int i = 0; i < TT; ++i) acc[i] = 0.f;
        const int t0 = tid >> 6;             // 0..3
        for (int k4 = 0; k4 < DIM / 4; ++k4) {
            const float4 w = wr[k4];
#pragma unroll
            for (int i = 0; i < TT; ++i) {
                const int t = t0 + 4 * i;
                const float4 a = ((const float4*)(xkv + (size_t)t * DIM))[k4];
                acc[i] += dot4(a, w);
            }
        }
#pragma unroll
        for (int i = 0; i < TT; ++i) {
            const int t = t0 + 4 * i;
            if (which == 0) Ks[t][d] = acc[i] + bias;
            else            Vs[t][d] = acc[i] + bias;
        }
    }

    // ---- Q projection: thread -> d = tid&31, t-group = tid>>5 ----
    {
        constexpr int TGQ = (LQ >= 8) ? 8 : LQ;
        constexpr int TT  = LQ / TGQ;
        if (tid < 32 * TGQ) {
            const int d   = tid & 31;
            const int row = h * HD + d;
            const float4* wr = (const float4*)(Wi + (size_t)row * DIM);
            const float bias = Bi[row];
            float acc[TT];
#pragma unroll
            for (int i = 0; i < TT; ++i) acc[i] = 0.f;
            const int t0 = tid >> 5;
            for (int k4 = 0; k4 < DIM / 4; ++k4) {
                const float4 w = wr[k4];
#pragma unroll
                for (int i = 0; i < TT; ++i) {
                    const int t = t0 + TGQ * i;
                    const float4 a = ((const float4*)(xq + (size_t)t * DIM))[k4];
                    acc[i] += dot4(a, w);
                }
            }
#pragma unroll
            for (int i = 0; i < TT; ++i) {
                const int t = t0 + TGQ * i;
                Qs[t][d] = (acc[i] + bias) * SCALE;
            }
        }
    }
    __syncthreads();

    // ---- attention, RQ query rows at a time ----
    for (int q0 = 0; q0 < LQ; q0 += RQ) {
        // scores
        for (int idx = tid; idx < RQ * LK; idx += 256) {
            const int r = idx / LK;
            const int j = idx - r * LK;
            float acc = 0.f;
#pragma unroll
            for (int d = 0; d < HD; ++d)
                acc += Qs[q0 + r][d] * Ks[j][d];
            S[r][j] = acc;
        }
        __syncthreads();
        // softmax: 8 lanes per row (lanes contiguous within a wave)
        if (tid < RQ * 8) {
            const int r   = tid >> 3;
            const int sub = tid & 7;
            float m = -1e30f;
            for (int j = sub; j < LK; j += 8) m = fmaxf(m, S[r][j]);
#pragma unroll
            for (int off = 4; off; off >>= 1) m = fmaxf(m, __shfl_xor(m, off, 8));
            float sum = 0.f;
            for (int j = sub; j < LK; j += 8) {
                const float p = __expf(S[r][j] - m);
                S[r][j] = p;
                sum += p;
            }
#pragma unroll
            for (int off = 4; off; off >>= 1) sum += __shfl_xor(sum, off, 8);
            const float inv = 1.0f / sum;
            for (int j = sub; j < LK; j += 8) S[r][j] *= inv;
        }
        __syncthreads();
        // O chunk = P @ V
        for (int idx = tid; idx < RQ * HD; idx += 256) {
            const int r = idx >> 5;
            const int d = idx & 31;
            float acc = 0.f;
            for (int j = 0; j < LK; ++j)
                acc += S[r][j] * Vs[j][d];
            O[((size_t)(b * LQ + q0 + r)) * DIM + h * HD + d] = acc;
        }
        __syncthreads();
    }
}

// ---------------------------------------------------------------------------
// leaf_p degenerate path: tP[i,:] = Wo0 @ (Wv0 @ inner[i] + bv0) + bo0
// ---------------------------------------------------------------------------
__global__ __launch_bounds__(256) void leafp_kernel(
    const float* __restrict__ inner, const float* __restrict__ Wi,
    const float* __restrict__ Bi, const float* __restrict__ Wo,
    const float* __restrict__ Bo, float* __restrict__ tP)
{
    const int i   = blockIdx.x;
    const int tid = threadIdx.x;
    __shared__ float xv[DIM];
    __shared__ float vv[DIM];
    xv[tid] = inner[(size_t)i * DIM + tid];
    __syncthreads();
    {
        const int row = 2 * DIM + tid;  // V rows
        const float4* wr = (const float4*)(Wi + (size_t)row * DIM);
        const float4* xr = (const float4*)xv;
        float acc = Bi[row];
        for (int k = 0; k < DIM / 4; ++k) acc += dot4(xr[k], wr[k]);
        vv[tid] = acc;
    }
    __syncthreads();
    {
        const float4* wr = (const float4*)(Wo + (size_t)tid * DIM);
        const float4* vr = (const float4*)vv;
        float acc = Bo[tid];
        for (int k = 0; k < DIM / 4; ++k) acc += dot4(vr[k], wr[k]);
        tP[(size_t)i * DIM + tid] = acc;
    }
}

// ---------------------------------------------------------------------------
// leaf_out[n,o] = wl0 * tP[n>>6, o] + wl1 * (O1[n,:] . Wo[o,:] + bo[o])
// ---------------------------------------------------------------------------
__global__ __launch_bounds__(256) void combine_leaf(
    const float* __restrict__ O1, const float* __restrict__ tP,
    const float* __restrict__ Wo, const float* __restrict__ Bo,
    const float* __restrict__ wleaf, float* __restrict__ out)
{
    const int n0 = blockIdx.x * 32;
    const int o  = threadIdx.x;
    __shared__ float Ts[32][DIM];
    for (int idx = threadIdx.x; idx < 32 * DIM; idx += 256)
        Ts[idx >> 8][idx & 255] = O1[(size_t)n0 * DIM + idx];
    __syncthreads();
    float acc[32];
#pragma unroll
    for (int r = 0; r < 32; ++r) acc[r] = 0.f;
    const float4* wr = (const float4*)(Wo + (size_t)o * DIM);
    for (int k4 = 0; k4 < DIM / 4; ++k4) {
        const float4 w = wr[k4];
#pragma unroll
        for (int r = 0; r < 32; ++r) {
            const float4 a = *(const float4*)&Ts[r][k4 * 4];
            acc[r] += dot4(a, w);
        }
    }
    const float e0 = __expf(wleaf[0]), e1 = __expf(wleaf[1]);
    const float wl0 = e0 / (e0 + e1), wl1 = e1 / (e0 + e1);
    const float bo = Bo[o];
#pragma unroll
    for (int r = 0; r < 32; ++r) {
        const int n = n0 + r;
        out[(size_t)n * DIM + o] =
            wl0 * tP[(size_t)(n >> 6) * DIM + o] + wl1 * (acc[r] + bo);
    }
}

// ---------------------------------------------------------------------------
// inner_out[n,o] = sum_t w_t * (Ot[n,:] . Wt[o,:] + bt[o])
// ---------------------------------------------------------------------------
__global__ __launch_bounds__(256) void combine_inner(
    const float* __restrict__ Op, const float* __restrict__ Osf,
    const float* __restrict__ Oc,
    const float* __restrict__ W2, const float* __restrict__ B2,
    const float* __restrict__ W3, const float* __restrict__ B3,
    const float* __restrict__ W4, const float* __restrict__ B4,
    const float* __restrict__ winner, float* __restrict__ out)
{
    const int n0 = blockIdx.x * 32;
    const int o  = threadIdx.x;
    __shared__ float Ts[32][DIM];
    const float e0 = __expf(winner[0]), e1 = __expf(winner[1]), e2 = __expf(winner[2]);
    const float inv = 1.f / (e0 + e1 + e2);
    const float wt0 = e0 * inv, wt1 = e1 * inv, wt2 = e2 * inv;

    float acc[32];
#pragma unroll
    for (int r = 0; r < 32; ++r) acc[r] = 0.f;
    const float biasacc = wt0 * B2[o] + wt1 * B3[o] + wt2 * B4[o];

#pragma unroll
    for (int term = 0; term < 3; ++term) {
        const float* Ob = (term == 0) ? Op : (term == 1) ? Osf : Oc;
        const float* Wb = (term == 0) ? W2 : (term == 1) ? W3 : W4;
        const float wt  = (term == 0) ? wt0 : (term == 1) ? wt1 : wt2;
        __syncthreads();
        for (int idx = threadIdx.x; idx < 32 * DIM; idx += 256)
            Ts[idx >> 8][idx & 255] = Ob[(size_t)n0 * DIM + idx];
        __syncthreads();
        const float4* wr = (const float4*)(Wb + (size_t)o * DIM);
        for (int k4 = 0; k4 < DIM / 4; ++k4) {
            float4 w = wr[k4];
            w.x *= wt; w.y *= wt; w.z *= wt; w.w *= wt;
#pragma unroll
            for (int r = 0; r < 32; ++r) {
                const float4 a = *(const float4*)&Ts[r][k4 * 4];
                acc[r] += dot4(a, w);
            }
        }
    }
#pragma unroll
    for (int r = 0; r < 32; ++r)
        out[(size_t)(n0 + r) * DIM + o] = acc[r] + biasacc;
}

// ---------------------------------------------------------------------------
// root_out[n,o] = (wr0*Ors[n,:] + wr1*Orc[n,:]) . W5[o,:] + b5[o]
// (same params for both terms; softmax weights sum to 1 so bias factors out)
// ---------------------------------------------------------------------------
__global__ __launch_bounds__(256) void combine_root(
    const float* __restrict__ Ors, const float* __restrict__ Orc,
    const float* __restrict__ W5, const float* __restrict__ B5,
    const float* __restrict__ wroot, float* __restrict__ out)
{
    const int n0 = blockIdx.x * 32;
    const int o  = threadIdx.x;
    __shared__ float Ts[32][DIM];
    const float e0 = __expf(wroot[0]), e1 = __expf(wroot[1]);
    const float w0 = e0 / (e0 + e1), w1 = e1 / (e0 + e1);
    for (int idx = threadIdx.x; idx < 32 * DIM; idx += 256)
        Ts[idx >> 8][idx & 255] = w0 * Ors[(size_t)n0 * DIM + idx] +
                                  w1 * Orc[(size_t)n0 * DIM + idx];
    __syncthreads();
    float acc[32];
#pragma unroll
    for (int r = 0; r < 32; ++r) acc[r] = 0.f;
    const float4* wr = (const float4*)(W5 + (size_t)o * DIM);
    for (int k4 = 0; k4 < DIM / 4; ++k4) {
        const float4 w = wr[k4];
#pragma unroll
        for (int r = 0; r < 32; ++r) {
            const float4 a = *(const float4*)&Ts[r][k4 * 4];
            acc[r] += dot4(a, w);
        }
    }
    const float bo = B5[o];
#pragma unroll
    for (int r = 0; r < 32; ++r)
        out[(size_t)(n0 + r) * DIM + o] = acc[r] + bo;
}

// ---------------------------------------------------------------------------
extern "C" void kernel_launch(void* const* d_in, const int* in_sizes, int n_in,
                              void* d_out, int out_size, void* d_ws, size_t ws_size,
                              hipStream_t stream)
{
    const float* leaf   = (const float*)d_in[0];  // (2048, 64, 256)
    const float* inner  = (const float*)d_in[1];  // (16, 128, 256) == (2048, 256)
    const float* root   = (const float*)d_in[2];  // (16, 16, 256)
    const float* w_in   = (const float*)d_in[3];  // (7, 768, 256)
    const float* b_in   = (const float*)d_in[4];  // (7, 768)
    const float* w_out  = (const float*)d_in[5];  // (7, 256, 256)
    const float* b_out  = (const float*)d_in[6];  // (7, 256)
    const float* wleaf  = (const float*)d_in[7];
    const float* winner = (const float*)d_in[8];
    const float* wroot  = (const float*)d_in[9];
    float* out = (float*)d_out;

    // per-parameter-set pointers
    const size_t WI = 768 * 256, BI = 768, WO = 256 * 256, BO = 256;
    const float *Wi0 = w_in,          *Bi0 = b_in;
    const float *Wi1 = w_in + 1 * WI, *Bi1 = b_in + 1 * BI;
    const float *Wi2 = w_in + 2 * WI, *Bi2 = b_in + 2 * BI;
    const float *Wi3 = w_in + 3 * WI, *Bi3 = b_in + 3 * BI;
    const float *Wi4 = w_in + 4 * WI, *Bi4 = b_in + 4 * BI;
    const float *Wi5 = w_in + 5 * WI, *Bi5 = b_in + 5 * BI;
    const float *Wo0 = w_out,          *Bo0 = b_out;
    const float *Wo1 = w_out + 1 * WO, *Bo1 = b_out + 1 * BO;
    const float *Wo2 = w_out + 2 * WO, *Bo2 = b_out + 2 * BO;
    const float *Wo3 = w_out + 3 * WO, *Bo3 = b_out + 3 * BO;
    const float *Wo4 = w_out + 4 * WO, *Bo4 = b_out + 4 * BO;
    const float *Wo5 = w_out + 5 * WO, *Bo5 = b_out + 5 * BO;

    // workspace layout (fp32), total ~136.6 MB
    char* ws = (char*)d_ws;
    float* tP  = (float*)(ws);                              //  2048*256
    float* O1  = (float*)(ws + 2097152);                    // 131072*256 (leaf_s)
    float* Oc  = (float*)(ws + 2097152 + 134217728);        //  2048*256 (inner_c)
    float* Op  = (float*)((char*)Oc + 2097152);             //  2048*256 (inner_p)
    float* Osf = (float*)((char*)Op + 2097152);             //  2048*256 (inner_s)
    float* Ors = (float*)((char*)Osf + 2097152);            //   256*256 (root_s)
    float* Orc = (float*)((char*)Ors + 262144);             //   256*256 (root_c)

    // leaf_p degenerate path
    leafp_kernel<<<2048, 256, 0, stream>>>(inner, Wi0, Bi0, Wo0, Bo0, tP);

    // attention cores
    attn_fused<64, 64, 32><<<2048 * 8, 256, 0, stream>>>(leaf, leaf, Wi1, Bi1, O1);
    attn_fused<1, 64, 1><<<2048 * 8, 256, 0, stream>>>(inner, leaf, Wi4, Bi4, Oc);
    attn_fused<128, 16, 32><<<16 * 8, 256, 0, stream>>>(inner, root, Wi2, Bi2, Op);
    attn_fused<128, 128, 16><<<16 * 8, 256, 0, stream>>>(inner, inner, Wi3, Bi3, Osf);
    attn_fused<16, 16, 16><<<16 * 8, 256, 0, stream>>>(root, root, Wi5, Bi5, Ors);
    attn_fused<16, 128, 16><<<16 * 8, 256, 0, stream>>>(root, inner, Wi5, Bi5, Orc);

    // out-projections + weighted combines
    combine_leaf<<<131072 / 32, 256, 0, stream>>>(O1, tP, Wo1, Bo1, wleaf, out);
    combine_inner<<<2048 / 32, 256, 0, stream>>>(Op, Osf, Oc, Wo2, Bo2, Wo3, Bo3,
                                                 Wo4, Bo4, winner, out + 33554432);
    combine_root<<<256 / 32, 256, 0, stream>>>(Ors, Orc, Wo5, Bo5, wroot,
                                               out + 33554432 + 524288);
}

// Round 2
// 1668.233 us; speedup vs baseline: 4.1923x; 4.1923x over previous
//
#include <hip/hip_runtime.h>
#include <hip/hip_bf16.h>
#include <cstdint>

// AttnLayerBU round 2: bf16 MFMA for leaf_s / inner_c projections and the
// leaf out-projection. Small paths stay fp32 VALU.

#define DIM 256
#define NH 8
#define HD 32

static constexpr float SCALE = 0.17677669529663687f; // 32^-0.5

typedef __bf16 bf16x8 __attribute__((ext_vector_type(8)));
typedef float  f32x4  __attribute__((ext_vector_type(4)));

__device__ __forceinline__ float dot4(const float4 a, const float4 b) {
    return a.x * b.x + a.y * b.y + a.z * b.z + a.w * b.w;
}

// ---------------------------------------------------------------------------
// fp32 -> bf16 converter (weights), n multiple of 4
// ---------------------------------------------------------------------------
__global__ __launch_bounds__(256) void cvt_f2b(const float* __restrict__ s,
                                               __bf16* __restrict__ d, int n) {
    int i = (blockIdx.x * 256 + threadIdx.x) * 4;
    if (i < n) {
        float4 v = *(const float4*)(s + i);
        d[i + 0] = (__bf16)v.x; d[i + 1] = (__bf16)v.y;
        d[i + 2] = (__bf16)v.z; d[i + 3] = (__bf16)v.w;
    }
}

// ---------------------------------------------------------------------------
// leaf_s fused MFMA attention. Block = (b,h); b = bid&2047, h = bid>>11 so all
// 8 heads of a leaf tile land on one XCD (bid%8 == b%8).
// ---------------------------------------------------------------------------
__global__ __launch_bounds__(256) void leafs_mfma(
    const float* __restrict__ X,     // leaf (131072, 256) fp32
    const __bf16* __restrict__ Wb,   // W1 bf16 (768, 256)
    const float* __restrict__ Bi,    // b_in set1 (768)
    __bf16* __restrict__ O)          // (131072, 256) bf16
{
    const int b    = blockIdx.x & 2047;
    const int h    = blockIdx.x >> 11;
    const int tid  = threadIdx.x;
    const int wid  = tid >> 6;
    const int lane = tid & 63;
    const int lr   = lane & 15;        // frag row / col index
    const int lk   = (lane >> 4) * 8;  // frag k offset

    __shared__ __bf16 Qs[64][56];      // 112 B rows: 16B aligned, 2-way banks
    __shared__ __bf16 Ks[64][56];
    __shared__ __bf16 Vt[32][72];      // transposed V: [d][token]
    __shared__ __bf16 Ps[64][72];

    // ---- A-fragments: this wave's 16 X rows, fp32 -> bf16, in registers ----
    bf16x8 a[8];
    {
        const float* xrow = X + ((size_t)b * 64 + wid * 16 + lr) * DIM + lk;
#pragma unroll
        for (int k = 0; k < 8; ++k) {
            float4 v0 = *(const float4*)(xrow + k * 32);
            float4 v1 = *(const float4*)(xrow + k * 32 + 4);
            bf16x8 t;
            t[0] = (__bf16)v0.x; t[1] = (__bf16)v0.y; t[2] = (__bf16)v0.z; t[3] = (__bf16)v0.w;
            t[4] = (__bf16)v1.x; t[5] = (__bf16)v1.y; t[6] = (__bf16)v1.z; t[7] = (__bf16)v1.w;
            a[k] = t;
        }
    }

    // ---- projection: n-tiles [Q0,Q1,K0,K1,V0,V1] ----
    const int tok0 = wid * 16 + (lane >> 4) * 4;
#pragma unroll
    for (int nt = 0; nt < 6; ++nt) {
        const int sec  = nt >> 1;                       // 0=Q 1=K 2=V
        const int wrow = sec * DIM + h * HD + (nt & 1) * 16 + lr;
        const __bf16* wp = Wb + (size_t)wrow * DIM + lk;
        f32x4 acc = {0.f, 0.f, 0.f, 0.f};
#pragma unroll
        for (int k = 0; k < 8; ++k)
            acc = __builtin_amdgcn_mfma_f32_16x16x32_bf16(
                a[k], *(const bf16x8*)(wp + k * 32), acc, 0, 0, 0);
        const float bias = Bi[wrow];                    // per-output-col bias
        const int   col  = (nt & 1) * 16 + lr;
        if (sec == 0) {
#pragma unroll
            for (int r = 0; r < 4; ++r)
                Qs[tok0 + r][col] = (__bf16)((acc[r] + bias) * SCALE);
        } else if (sec == 1) {
#pragma unroll
            for (int r = 0; r < 4; ++r)
                Ks[tok0 + r][col] = (__bf16)(acc[r] + bias);
        } else {
#pragma unroll
            for (int r = 0; r < 4; ++r)
                Vt[col][tok0 + r] = (__bf16)(acc[r] + bias);
        }
    }
    __syncthreads();

    // ---- QK^T: wave owns q-rows wid*16..+15 ----
    const bf16x8 qa = *(const bf16x8*)&Qs[wid * 16 + lr][lk];
    f32x4 s[4];
#pragma unroll
    for (int jt = 0; jt < 4; ++jt) {
        f32x4 z = {0.f, 0.f, 0.f, 0.f};
        s[jt] = __builtin_amdgcn_mfma_f32_16x16x32_bf16(
            qa, *(const bf16x8*)&Ks[jt * 16 + lr][lk], z, 0, 0, 0);
    }

    // ---- softmax per q-row (row = tok0 + r, 16 lanes share a row) ----
    float mx[4], sm[4];
#pragma unroll
    for (int r = 0; r < 4; ++r) {
        float m = fmaxf(fmaxf(s[0][r], s[1][r]), fmaxf(s[2][r], s[3][r]));
#pragma unroll
        for (int off = 1; off < 16; off <<= 1) m = fmaxf(m, __shfl_xor(m, off));
        mx[r] = m;
    }
#pragma unroll
    for (int jt = 0; jt < 4; ++jt)
#pragma unroll
        for (int r = 0; r < 4; ++r) s[jt][r] = __expf(s[jt][r] - mx[r]);
#pragma unroll
    for (int r = 0; r < 4; ++r) {
        float t = s[0][r] + s[1][r] + s[2][r] + s[3][r];
#pragma unroll
        for (int off = 1; off < 16; off <<= 1) t += __shfl_xor(t, off);
        sm[r] = 1.0f / t;
    }
#pragma unroll
    for (int jt = 0; jt < 4; ++jt)
#pragma unroll
        for (int r = 0; r < 4; ++r)
            Ps[tok0 + r][jt * 16 + lr] = (__bf16)(s[jt][r] * sm[r]);

    // ---- PV: O[q][d32] = P @ V ----
    bf16x8 pa[2];
#pragma unroll
    for (int ks = 0; ks < 2; ++ks)
        pa[ks] = *(const bf16x8*)&Ps[wid * 16 + lr][ks * 32 + lk];
#pragma unroll
    for (int dt = 0; dt < 2; ++dt) {
        f32x4 o = {0.f, 0.f, 0.f, 0.f};
#pragma unroll
        for (int ks = 0; ks < 2; ++ks)
            o = __builtin_amdgcn_mfma_f32_16x16x32_bf16(
                pa[ks], *(const bf16x8*)&Vt[dt * 16 + lr][ks * 32 + lk], o, 0, 0, 0);
        const size_t orow = (size_t)b * 64 + tok0;
#pragma unroll
        for (int r = 0; r < 4; ++r)
            O[(orow + r) * DIM + h * HD + dt * 16 + lr] = (__bf16)o[r];
    }
}

// ---------------------------------------------------------------------------
// inner_c fused: MFMA K/V projection of leaf tile + Lq=1 VALU attention.
// ---------------------------------------------------------------------------
__global__ __launch_bounds__(256) void innerc_mfma(
    const float* __restrict__ Xl,    // leaf
    const float* __restrict__ inner, // (2048, 256)
    const __bf16* __restrict__ Wkv,  // set4 rows 256..767 bf16 (512, 256)
    const float* __restrict__ Wq,    // set4 fp32 (use rows 0..255)
    const float* __restrict__ Bi4,   // b_in set4 (768)
    float* __restrict__ Oc)          // (2048, 256) fp32
{
    const int b    = blockIdx.x & 2047;
    const int h    = blockIdx.x >> 11;
    const int tid  = threadIdx.x;
    const int wid  = tid >> 6;
    const int lane = tid & 63;
    const int lr   = lane & 15;
    const int lk   = (lane >> 4) * 8;

    __shared__ __bf16 Kt[32][72];    // [d][token]
    __shared__ __bf16 Vt[32][72];
    __shared__ float  qpart[8][33];
    __shared__ float  qv[32];
    __shared__ float  spart[4][65];
    __shared__ float  ps[64];
    __shared__ float  op[8][33];

    // A-fragments from leaf tile
    bf16x8 a[8];
    {
        const float* xrow = Xl + ((size_t)b * 64 + wid * 16 + lr) * DIM + lk;
#pragma unroll
        for (int k = 0; k < 8; ++k) {
            float4 v0 = *(const float4*)(xrow + k * 32);
            float4 v1 = *(const float4*)(xrow + k * 32 + 4);
            bf16x8 t;
            t[0] = (__bf16)v0.x; t[1] = (__bf16)v0.y; t[2] = (__bf16)v0.z; t[3] = (__bf16)v0.w;
            t[4] = (__bf16)v1.x; t[5] = (__bf16)v1.y; t[6] = (__bf16)v1.z; t[7] = (__bf16)v1.w;
            a[k] = t;
        }
    }

    const int tok0 = wid * 16 + (lane >> 4) * 4;
#pragma unroll
    for (int nt = 0; nt < 4; ++nt) {
        const int sec  = nt >> 1;                       // 0=K 1=V
        const int brow = sec * DIM + h * HD + (nt & 1) * 16 + lr; // row in Wkv buf
        const __bf16* wp = Wkv + (size_t)brow * DIM + lk;
        f32x4 acc = {0.f, 0.f, 0.f, 0.f};
#pragma unroll
        for (int k = 0; k < 8; ++k)
            acc = __builtin_amdgcn_mfma_f32_16x16x32_bf16(
                a[k], *(const bf16x8*)(wp + k * 32), acc, 0, 0, 0);
        const float bias = Bi4[DIM + brow];             // global rows 256..767
        const int   col  = (nt & 1) * 16 + lr;
        if (sec == 0) {
#pragma unroll
            for (int r = 0; r < 4; ++r) Kt[col][tok0 + r] = (__bf16)(acc[r] + bias);
        } else {
#pragma unroll
            for (int r = 0; r < 4; ++r) Vt[col][tok0 + r] = (__bf16)(acc[r] + bias);
        }
    }

    // q projection partials: thread -> (d = tid&31, part = tid>>5)
    {
        const int d = tid & 31, pt = tid >> 5;
        const float4* wr = (const float4*)(Wq + (size_t)(h * HD + d) * DIM + pt * 32);
        const float4* xr = (const float4*)(inner + (size_t)b * DIM + pt * 32);
        float acc = 0.f;
#pragma unroll
        for (int k = 0; k < 8; ++k) acc += dot4(xr[k], wr[k]);
        qpart[pt][d] = acc;
    }
    __syncthreads();
    if (tid < 32) {
        float q = Bi4[h * HD + tid];
#pragma unroll
        for (int p = 0; p < 8; ++p) q += qpart[p][tid];
        qv[tid] = q * SCALE;
    }
    __syncthreads();

    // scores: thread -> (j = tid&63, dp = tid>>6)
    {
        const int j = tid & 63, dp = tid >> 6;
        float acc = 0.f;
#pragma unroll
        for (int i = 0; i < 8; ++i)
            acc += qv[dp * 8 + i] * (float)Kt[dp * 8 + i][j];
        spart[dp][j] = acc;
    }
    __syncthreads();
    if (wid == 0) {
        float sv = spart[0][lane] + spart[1][lane] + spart[2][lane] + spart[3][lane];
        float m = sv;
#pragma unroll
        for (int off = 1; off < 64; off <<= 1) m = fmaxf(m, __shfl_xor(m, off));
        float p = __expf(sv - m);
        float t = p;
#pragma unroll
        for (int off = 1; off < 64; off <<= 1) t += __shfl_xor(t, off);
        ps[lane] = p / t;
    }
    __syncthreads();

    // PV partials: thread -> (d = tid&31, jp = tid>>5)
    {
        const int d = tid & 31, jp = tid >> 5;
        float acc = 0.f;
#pragma unroll
        for (int i = 0; i < 8; ++i)
            acc += ps[jp * 8 + i] * (float)Vt[d][jp * 8 + i];
        op[jp][d] = acc;
    }
    __syncthreads();
    if (tid < 32) {
        float o = 0.f;
#pragma unroll
        for (int p = 0; p < 8; ++p) o += op[p][tid];
        Oc[(size_t)b * DIM + h * HD + tid] = o;
    }
}

// ---------------------------------------------------------------------------
// combine_leaf MFMA: out = wl0*tP[bid] + wl1*(O1 @ Wo1^T + bo1)
// ---------------------------------------------------------------------------
__global__ __launch_bounds__(256) void combleaf_mfma(
    const __bf16* __restrict__ O1, const __bf16* __restrict__ Wob,
    const float* __restrict__ Bo1, const float* __restrict__ tP,
    const float* __restrict__ wleaf, float* __restrict__ out)
{
    const int bid  = blockIdx.x;        // 2048 blocks x 64 rows
    const int tid  = threadIdx.x;
    const int wid  = tid >> 6;
    const int lane = tid & 63;
    const int lr   = lane & 15;
    const int lk   = (lane >> 4) * 8;

    bf16x8 a[8];
    {
        const __bf16* ar = O1 + ((size_t)bid * 64 + wid * 16 + lr) * DIM + lk;
#pragma unroll
        for (int k = 0; k < 8; ++k) a[k] = *(const bf16x8*)(ar + k * 32);
    }
    const float e0 = __expf(wleaf[0]), e1 = __expf(wleaf[1]);
    const float wl0 = e0 / (e0 + e1), wl1 = e1 / (e0 + e1);
    const size_t row0 = (size_t)bid * 64 + wid * 16 + (lane >> 4) * 4;

    for (int nt = 0; nt < 16; ++nt) {
        const __bf16* wp = Wob + (size_t)(nt * 16 + lr) * DIM + lk;
        f32x4 acc = {0.f, 0.f, 0.f, 0.f};
#pragma unroll
        for (int k = 0; k < 8; ++k)
            acc = __builtin_amdgcn_mfma_f32_16x16x32_bf16(
                a[k], *(const bf16x8*)(wp + k * 32), acc, 0, 0, 0);
        const int   o  = nt * 16 + lr;
        const float bo = Bo1[o];
        const float tv = tP[(size_t)bid * DIM + o];
#pragma unroll
        for (int r = 0; r < 4; ++r)
            out[(row0 + r) * DIM + o] = wl0 * tv + wl1 * (acc[r] + bo);
    }
}

// ---------------------------------------------------------------------------
// fp32 fused attention (round-1, kept for the small paths)
// ---------------------------------------------------------------------------
template <int LQ, int LK, int RQ>
__global__ __launch_bounds__(256) void attn_fused(
    const float* __restrict__ Xq, const float* __restrict__ Xkv,
    const float* __restrict__ Wi, const float* __restrict__ Bi,
    float* __restrict__ O)
{
    const int b   = blockIdx.x >> 3;
    const int h   = blockIdx.x & 7;
    const int tid = threadIdx.x;

    __shared__ float Ks[LK][33];
    __shared__ float Vs[LK][33];
    __shared__ float Qs[LQ][33];
    __shared__ float S[RQ][LK + 1];

    const float* xq  = Xq  + (size_t)b * LQ * DIM;
    const float* xkv = Xkv + (size_t)b * LK * DIM;

    {
        const int col   = tid & 63;
        const int which = col >> 5;
        const int d     = col & 31;
        const int row   = DIM + which * DIM + h * HD + d;
        const float4* wr = (const float4*)(Wi + (size_t)row * DIM);
        const float bias = Bi[row];
        constexpr int TT = LK / 4;
        float acc[TT];
#pragma unroll
        for (int i = 0; i < TT; ++i) acc[i] = 0.f;
        const int t0 = tid >> 6;
        for (int k4 = 0; k4 < DIM / 4; ++k4) {
            const float4 w = wr[k4];
#pragma unroll
            for (int i = 0; i < TT; ++i) {
                const int t = t0 + 4 * i;
                const float4 aa = ((const float4*)(xkv + (size_t)t * DIM))[k4];
                acc[i] += dot4(aa, w);
            }
        }
#pragma unroll
        for (int i = 0; i < TT; ++i) {
            const int t = t0 + 4 * i;
            if (which == 0) Ks[t][d] = acc[i] + bias;
            else            Vs[t][d] = acc[i] + bias;
        }
    }
    {
        constexpr int TGQ = (LQ >= 8) ? 8 : LQ;
        constexpr int TT  = LQ / TGQ;
        if (tid < 32 * TGQ) {
            const int d   = tid & 31;
            const int row = h * HD + d;
            const float4* wr = (const float4*)(Wi + (size_t)row * DIM);
            const float bias = Bi[row];
            float acc[TT];
#pragma unroll
            for (int i = 0; i < TT; ++i) acc[i] = 0.f;
            const int t0 = tid >> 5;
            for (int k4 = 0; k4 < DIM / 4; ++k4) {
                const float4 w = wr[k4];
#pragma unroll
                for (int i = 0; i < TT; ++i) {
                    const int t = t0 + TGQ * i;
                    const float4 aa = ((const float4*)(xq + (size_t)t * DIM))[k4];
                    acc[i] += dot4(aa, w);
                }
            }
#pragma unroll
            for (int i = 0; i < TT; ++i) {
                const int t = t0 + TGQ * i;
                Qs[t][d] = (acc[i] + bias) * SCALE;
            }
        }
    }
    __syncthreads();

    for (int q0 = 0; q0 < LQ; q0 += RQ) {
        for (int idx = tid; idx < RQ * LK; idx += 256) {
            const int r = idx / LK;
            const int j = idx - r * LK;
            float acc = 0.f;
#pragma unroll
            for (int d = 0; d < HD; ++d)
                acc += Qs[q0 + r][d] * Ks[j][d];
            S[r][j] = acc;
        }
        __syncthreads();
        if (tid < RQ * 8) {
            const int r   = tid >> 3;
            const int sub = tid & 7;
            float m = -1e30f;
            for (int j = sub; j < LK; j += 8) m = fmaxf(m, S[r][j]);
#pragma unroll
            for (int off = 4; off; off >>= 1) m = fmaxf(m, __shfl_xor(m, off, 8));
            float sum = 0.f;
            for (int j = sub; j < LK; j += 8) {
                const float p = __expf(S[r][j] - m);
                S[r][j] = p;
                sum += p;
            }
#pragma unroll
            for (int off = 4; off; off >>= 1) sum += __shfl_xor(sum, off, 8);
            const float inv = 1.0f / sum;
            for (int j = sub; j < LK; j += 8) S[r][j] *= inv;
        }
        __syncthreads();
        for (int idx = tid; idx < RQ * HD; idx += 256) {
            const int r = idx >> 5;
            const int d = idx & 31;
            float acc = 0.f;
            for (int j = 0; j < LK; ++j)
                acc += S[r][j] * Vs[j][d];
            O[((size_t)(b * LQ + q0 + r)) * DIM + h * HD + d] = acc;
        }
        __syncthreads();
    }
}

// ---------------------------------------------------------------------------
// leaf_p degenerate path (unchanged)
// ---------------------------------------------------------------------------
__global__ __launch_bounds__(256) void leafp_kernel(
    const float* __restrict__ inner, const float* __restrict__ Wi,
    const float* __restrict__ Bi, const float* __restrict__ Wo,
    const float* __restrict__ Bo, float* __restrict__ tP)
{
    const int i   = blockIdx.x;
    const int tid = threadIdx.x;
    __shared__ float xv[DIM];
    __shared__ float vv[DIM];
    xv[tid] = inner[(size_t)i * DIM + tid];
    __syncthreads();
    {
        const int row = 2 * DIM + tid;
        const float4* wr = (const float4*)(Wi + (size_t)row * DIM);
        const float4* xr = (const float4*)xv;
        float acc = Bi[row];
        for (int k = 0; k < DIM / 4; ++k) acc += dot4(xr[k], wr[k]);
        vv[tid] = acc;
    }
    __syncthreads();
    {
        const float4* wr = (const float4*)(Wo + (size_t)tid * DIM);
        const float4* vr = (const float4*)vv;
        float acc = Bo[tid];
        for (int k = 0; k < DIM / 4; ++k) acc += dot4(vr[k], wr[k]);
        tP[(size_t)i * DIM + tid] = acc;
    }
}

// ---------------------------------------------------------------------------
// combine_inner / combine_root (unchanged fp32)
// ---------------------------------------------------------------------------
__global__ __launch_bounds__(256) void combine_inner(
    const float* __restrict__ Op, const float* __restrict__ Osf,
    const float* __restrict__ Oc,
    const float* __restrict__ W2, const float* __restrict__ B2,
    const float* __restrict__ W3, const float* __restrict__ B3,
    const float* __restrict__ W4, const float* __restrict__ B4,
    const float* __restrict__ winner, float* __restrict__ out)
{
    const int n0 = blockIdx.x * 32;
    const int o  = threadIdx.x;
    __shared__ float Ts[32][DIM];
    const float e0 = __expf(winner[0]), e1 = __expf(winner[1]), e2 = __expf(winner[2]);
    const float inv = 1.f / (e0 + e1 + e2);
    const float wt0 = e0 * inv, wt1 = e1 * inv, wt2 = e2 * inv;

    float acc[32];
#pragma unroll
    for (int r = 0; r < 32; ++r) acc[r] = 0.f;
    const float biasacc = wt0 * B2[o] + wt1 * B3[o] + wt2 * B4[o];

#pragma unroll
    for (int term = 0; term < 3; ++term) {
        const float* Ob = (term == 0) ? Op : (term == 1) ? Osf : Oc;
        const float* Wb = (term == 0) ? W2 : (term == 1) ? W3 : W4;
        const float wt  = (term == 0) ? wt0 : (term == 1) ? wt1 : wt2;
        __syncthreads();
        for (int idx = threadIdx.x; idx < 32 * DIM; idx += 256)
            Ts[idx >> 8][idx & 255] = Ob[(size_t)n0 * DIM + idx];
        __syncthreads();
        const float4* wr = (const float4*)(Wb + (size_t)o * DIM);
        for (int k4 = 0; k4 < DIM / 4; ++k4) {
            float4 w = wr[k4];
            w.x *= wt; w.y *= wt; w.z *= wt; w.w *= wt;
#pragma unroll
            for (int r = 0; r < 32; ++r) {
                const float4 aa = *(const float4*)&Ts[r][k4 * 4];
                acc[r] += dot4(aa, w);
            }
        }
    }
#pragma unroll
    for (int r = 0; r < 32; ++r)
        out[(size_t)(n0 + r) * DIM + o] = acc[r] + biasacc;
}

__global__ __launch_bounds__(256) void combine_root(
    const float* __restrict__ Ors, const float* __restrict__ Orc,
    const float* __restrict__ W5, const float* __restrict__ B5,
    const float* __restrict__ wroot, float* __restrict__ out)
{
    const int n0 = blockIdx.x * 32;
    const int o  = threadIdx.x;
    __shared__ float Ts[32][DIM];
    const float e0 = __expf(wroot[0]), e1 = __expf(wroot[1]);
    const float w0 = e0 / (e0 + e1), w1 = e1 / (e0 + e1);
    for (int idx = threadIdx.x; idx < 32 * DIM; idx += 256)
        Ts[idx >> 8][idx & 255] = w0 * Ors[(size_t)n0 * DIM + idx] +
                                  w1 * Orc[(size_t)n0 * DIM + idx];
    __syncthreads();
    float acc[32];
#pragma unroll
    for (int r = 0; r < 32; ++r) acc[r] = 0.f;
    const float4* wr = (const float4*)(W5 + (size_t)o * DIM);
    for (int k4 = 0; k4 < DIM / 4; ++k4) {
        const float4 w = wr[k4];
#pragma unroll
        for (int r = 0; r < 32; ++r) {
            const float4 aa = *(const float4*)&Ts[r][k4 * 4];
            acc[r] += dot4(aa, w);
        }
    }
    const float bo = B5[o];
#pragma unroll
    for (int r = 0; r < 32; ++r)
        out[(size_t)(n0 + r) * DIM + o] = acc[r] + bo;
}

// ---------------------------------------------------------------------------
extern "C" void kernel_launch(void* const* d_in, const int* in_sizes, int n_in,
                              void* d_out, int out_size, void* d_ws, size_t ws_size,
                              hipStream_t stream)
{
    const float* leaf   = (const float*)d_in[0];
    const float* inner  = (const float*)d_in[1];
    const float* root   = (const float*)d_in[2];
    const float* w_in   = (const float*)d_in[3];
    const float* b_in   = (const float*)d_in[4];
    const float* w_out  = (const float*)d_in[5];
    const float* b_out  = (const float*)d_in[6];
    const float* wleaf  = (const float*)d_in[7];
    const float* winner = (const float*)d_in[8];
    const float* wroot  = (const float*)d_in[9];
    float* out = (float*)d_out;

    const size_t WI = 768 * 256, BI = 768, WO = 256 * 256, BO = 256;

    // ws layout (bytes)
    char* ws = (char*)d_ws;
    __bf16* W1b   = (__bf16*)(ws);                    // 768*256   -> 393216 B
    __bf16* W4kvb = (__bf16*)(ws + 393216);           // 512*256   -> 262144 B
    __bf16* Wo1b  = (__bf16*)(ws + 655360);           // 256*256   -> 131072 B
    __bf16* O1b   = (__bf16*)(ws + 786432);           // 131072*256 bf16 -> 67108864 B
    float*  tP    = (float*)(ws + 67895296);          // 2048*256 f32
    float*  Oc    = (float*)(ws + 69992448);
    float*  Op    = (float*)(ws + 72089600);
    float*  Osf   = (float*)(ws + 74186752);
    float*  Ors   = (float*)(ws + 76283904);
    float*  Orc   = (float*)(ws + 76546048);

    // weight conversions
    cvt_f2b<<<192, 256, 0, stream>>>(w_in + 1 * WI, W1b, 768 * 256);
    cvt_f2b<<<128, 256, 0, stream>>>(w_in + 4 * WI + 256 * 256, W4kvb, 512 * 256);
    cvt_f2b<<<64, 256, 0, stream>>>(w_out + 1 * WO, Wo1b, 256 * 256);

    // leaf_p degenerate path
    leafp_kernel<<<2048, 256, 0, stream>>>(inner, w_in, b_in, w_out, b_out, tP);

    // heavy MFMA paths
    leafs_mfma<<<16384, 256, 0, stream>>>(leaf, W1b, b_in + BI, O1b);
    innerc_mfma<<<16384, 256, 0, stream>>>(leaf, inner, W4kvb, w_in + 4 * WI,
                                           b_in + 4 * BI, Oc);

    // small fp32 attention paths
    attn_fused<128, 16, 32><<<16 * 8, 256, 0, stream>>>(inner, root, w_in + 2 * WI, b_in + 2 * BI, Op);
    attn_fused<128, 128, 16><<<16 * 8, 256, 0, stream>>>(inner, inner, w_in + 3 * WI, b_in + 3 * BI, Osf);
    attn_fused<16, 16, 16><<<16 * 8, 256, 0, stream>>>(root, root, w_in + 5 * WI, b_in + 5 * BI, Ors);
    attn_fused<16, 128, 16><<<16 * 8, 256, 0, stream>>>(root, inner, w_in + 5 * WI, b_in + 5 * BI, Orc);

    // combines
    combleaf_mfma<<<2048, 256, 0, stream>>>(O1b, Wo1b, b_out + BO, tP, wleaf, out);
    combine_inner<<<2048 / 32, 256, 0, stream>>>(Op, Osf, Oc, w_out + 2 * WO, b_out + 2 * BO,
                                                 w_out + 3 * WO, b_out + 3 * BO,
                                                 w_out + 4 * WO, b_out + 4 * BO,
                                                 winner, out + 33554432);
    combine_root<<<256 / 32, 256, 0, stream>>>(Ors, Orc, w_out + 5 * WO, b_out + 5 * BO,
                                               wroot, out + 33554432 + 524288);
}

// Round 4
// 1528.181 us; speedup vs baseline: 4.5765x; 1.0916x over previous
//
#include <hip/hip_runtime.h>
#include <hip/hip_bf16.h>
#include <cstdint>

// AttnLayerBU round 4: mega-fusion with alias-free LDS plan.
//   leaf_mega (block = leaf tile, 512 thr): leaf read once -> A-frags in regs;
//   W1 Q/K/V proj -> LDS; 8-head attention -> O1 (global bf16); W4 K/V proj +
//   Lq=1 inner_c attention -> Oc.  Out-projection = round-2 combleaf (verbatim).
// LDS map (133120 B, no live overlaps):
//   0      Qs[64][264] (33792)   | phase B: K4t[256][72] (36864, spills into gap)
//   36864  Ks[64][264] (33792)
//   70656  Vt[256][72] (36864)   | phase B: V4t[256][72] (exact)
//   107520 Pw 8 x [16][72] per-wave (18432)
//   125952 scratch qpart/qv/psm/opart (7168)

#define DIM 256
#define NH 8
#define HD 32

static constexpr float SCALE = 0.17677669529663687f; // 32^-0.5

typedef __bf16 bf16x8 __attribute__((ext_vector_type(8)));
typedef __bf16 bf16x4 __attribute__((ext_vector_type(4)));
typedef float  f32x4  __attribute__((ext_vector_type(4)));

__device__ __forceinline__ float dot4(const float4 a, const float4 b) {
    return a.x * b.x + a.y * b.y + a.z * b.z + a.w * b.w;
}

// ---------------------------------------------------------------------------
__global__ __launch_bounds__(256) void cvt_f2b(const float* __restrict__ s,
                                               __bf16* __restrict__ d, int n) {
    int i = (blockIdx.x * 256 + threadIdx.x) * 4;
    if (i < n) {
        float4 v = *(const float4*)(s + i);
        d[i + 0] = (__bf16)v.x; d[i + 1] = (__bf16)v.y;
        d[i + 2] = (__bf16)v.z; d[i + 3] = (__bf16)v.w;
    }
}

// ---------------------------------------------------------------------------
__global__ __launch_bounds__(512) void leaf_mega(
    const float* __restrict__ X,       // leaf (131072, 256)
    const float* __restrict__ inner,   // (2048, 256)
    const __bf16* __restrict__ W1b,    // set1 W (768,256) bf16
    const float* __restrict__ Bi1,     // set1 b (768)
    const __bf16* __restrict__ W4kvb,  // set4 W rows 256..767 bf16 (512,256)
    const float* __restrict__ W4q,     // set4 W fp32 (rows 0..255 used)
    const float* __restrict__ Bi4,     // set4 b (768)
    __bf16* __restrict__ O1,           // leaf_s attention out (131072,256) bf16
    float* __restrict__ Oc)            // inner_c attn out (2048,256) fp32
{
    extern __shared__ __align__(16) char smem[];
    const int b    = blockIdx.x;
    const int tid  = threadIdx.x;
    const int wid  = tid >> 6;
    const int lane = tid & 63;
    const int lr   = lane & 15;
    const int lk   = (lane >> 4) * 8;
    const int rg   = wid & 3;          // A-row group (rows rg*16..+15)
    const int ch   = wid >> 2;         // n-column half
    const int tok0 = rg * 16 + (lane >> 4) * 4;
    const int prow = (lane >> 4) * 4;

    __bf16* Qs  = (__bf16*)smem;                       // [64][264]
    __bf16* Ks  = (__bf16*)(smem + 36864);             // [64][264]
    __bf16* Vt  = (__bf16*)(smem + 70656);             // [256][72]
    __bf16* Pw  = (__bf16*)(smem + 107520 + wid * 2304); // per-wave [16][72]
    __bf16* K4t = (__bf16*)smem;                       // [256][72] phase B
    __bf16* V4t = (__bf16*)(smem + 70656);             // [256][72] phase B
    float* qpart = (float*)(smem + 125952);            // [2][256]
    float* qv    = qpart + 512;                        // [256]
    float* psm   = qv + 256;                           // [8][64]
    float* opart = psm + 512;                          // [2][256]

    // ---- A-fragments: 16 leaf rows per row-group, fp32 -> bf16 ----
    bf16x8 a[8];
    {
        const float* xrow = X + ((size_t)b * 64 + rg * 16 + lr) * DIM + lk;
#pragma unroll
        for (int k = 0; k < 8; ++k) {
            float4 v0 = *(const float4*)(xrow + k * 32);
            float4 v1 = *(const float4*)(xrow + k * 32 + 4);
            bf16x8 t;
            t[0] = (__bf16)v0.x; t[1] = (__bf16)v0.y; t[2] = (__bf16)v0.z; t[3] = (__bf16)v0.w;
            t[4] = (__bf16)v1.x; t[5] = (__bf16)v1.y; t[6] = (__bf16)v1.z; t[7] = (__bf16)v1.w;
            a[k] = t;
        }
    }

    // ---- Phase A: W1 Q/K/V projection, 24 n-tiles/wave, prefetched ----
    {
        bf16x8 w0[8];
        {
            const __bf16* wp = W1b + (size_t)((ch * 24) * 16 + lr) * DIM + lk;
#pragma unroll
            for (int k = 0; k < 8; ++k) w0[k] = *(const bf16x8*)(wp + k * 32);
        }
        for (int nt = 0; nt < 24; ++nt) {
            const int g = ch * 24 + nt;
            bf16x8 w1[8];
            if (nt + 1 < 24) {
                const __bf16* wp = W1b + (size_t)((g + 1) * 16 + lr) * DIM + lk;
#pragma unroll
                for (int k = 0; k < 8; ++k) w1[k] = *(const bf16x8*)(wp + k * 32);
            }
            f32x4 acc = {0.f, 0.f, 0.f, 0.f};
#pragma unroll
            for (int k = 0; k < 8; ++k)
                acc = __builtin_amdgcn_mfma_f32_16x16x32_bf16(a[k], w0[k], acc, 0, 0, 0);
            const float bias = Bi1[g * 16 + lr];
            if (g < 16) {               // Q (scaled)
                const int col = g * 16 + lr;
#pragma unroll
                for (int r = 0; r < 4; ++r)
                    Qs[(size_t)(tok0 + r) * 264 + col] = (__bf16)((acc[r] + bias) * SCALE);
            } else if (g < 32) {        // K
                const int col = (g - 16) * 16 + lr;
#pragma unroll
                for (int r = 0; r < 4; ++r)
                    Ks[(size_t)(tok0 + r) * 264 + col] = (__bf16)(acc[r] + bias);
            } else {                    // V -> transposed [d][tok]
                const int col = (g - 32) * 16 + lr;
                bf16x4 pv;
#pragma unroll
                for (int r = 0; r < 4; ++r) pv[r] = (__bf16)(acc[r] + bias);
                *(bf16x4*)(Vt + (size_t)col * 72 + tok0) = pv;
            }
#pragma unroll
            for (int k = 0; k < 8; ++k) w0[k] = w1[k];
        }
    }
    __syncthreads();                                   // b1: Q,K,Vt ready

    // ---- QK^T: wave = head h ----
    const int h = wid;
    f32x4 s[4][4];
    {
        bf16x8 kb[4];
#pragma unroll
        for (int kt = 0; kt < 4; ++kt)
            kb[kt] = *(const bf16x8*)(Ks + (size_t)(kt * 16 + lr) * 264 + h * 32 + lk);
#pragma unroll
        for (int qt = 0; qt < 4; ++qt) {
            const bf16x8 qa = *(const bf16x8*)(Qs + (size_t)(qt * 16 + lr) * 264 + h * 32 + lk);
#pragma unroll
            for (int kt = 0; kt < 4; ++kt) {
                f32x4 z = {0.f, 0.f, 0.f, 0.f};
                s[qt][kt] = __builtin_amdgcn_mfma_f32_16x16x32_bf16(qa, kb[kt], z, 0, 0, 0);
            }
        }
    }

    // ---- softmax in registers (each 16-lane group owns its rows) ----
#pragma unroll
    for (int qt = 0; qt < 4; ++qt) {
#pragma unroll
        for (int r = 0; r < 4; ++r) {
            float m = fmaxf(fmaxf(s[qt][0][r], s[qt][1][r]), fmaxf(s[qt][2][r], s[qt][3][r]));
#pragma unroll
            for (int off = 1; off < 16; off <<= 1) m = fmaxf(m, __shfl_xor(m, off));
            const float p0 = __expf(s[qt][0][r] - m), p1 = __expf(s[qt][1][r] - m);
            const float p2 = __expf(s[qt][2][r] - m), p3 = __expf(s[qt][3][r] - m);
            float t = p0 + p1 + p2 + p3;
#pragma unroll
            for (int off = 1; off < 16; off <<= 1) t += __shfl_xor(t, off);
            const float inv = 1.0f / t;
            s[qt][0][r] = p0 * inv; s[qt][1][r] = p1 * inv;
            s[qt][2][r] = p2 * inv; s[qt][3][r] = p3 * inv;
        }
    }

    // ---- PV per q-tile, P via dedicated wave-local LDS, O -> global ----
    {
        bf16x8 vb[2][2];
#pragma unroll
        for (int dt = 0; dt < 2; ++dt)
#pragma unroll
            for (int ks = 0; ks < 2; ++ks)
                vb[dt][ks] = *(const bf16x8*)(Vt + (size_t)(h * 32 + dt * 16 + lr) * 72 + ks * 32 + lk);

#pragma unroll
        for (int qt = 0; qt < 4; ++qt) {
#pragma unroll
            for (int kt = 0; kt < 4; ++kt)
#pragma unroll
                for (int r = 0; r < 4; ++r)
                    Pw[(size_t)(prow + r) * 72 + kt * 16 + lr] = (__bf16)s[qt][kt][r];
            bf16x8 pa[2];
#pragma unroll
            for (int ks = 0; ks < 2; ++ks)
                pa[ks] = *(const bf16x8*)(Pw + (size_t)lr * 72 + ks * 32 + lk);
#pragma unroll
            for (int dt = 0; dt < 2; ++dt) {
                f32x4 o = {0.f, 0.f, 0.f, 0.f};
#pragma unroll
                for (int ks = 0; ks < 2; ++ks)
                    o = __builtin_amdgcn_mfma_f32_16x16x32_bf16(pa[ks], vb[dt][ks], o, 0, 0, 0);
#pragma unroll
                for (int r = 0; r < 4; ++r)
                    O1[((size_t)b * 64 + qt * 16 + prow + r) * DIM + h * 32 + dt * 16 + lr] =
                        (__bf16)o[r];
            }
        }
    }
    __syncthreads();                                   // b5: attention done, LDS free

    // ---- Phase B: W4 K/V projection, 16 n-tiles/wave, prefetched ----
    {
        bf16x8 w0[8];
        {
            const __bf16* wp = W4kvb + (size_t)((ch * 16) * 16 + lr) * DIM + lk;
#pragma unroll
            for (int k = 0; k < 8; ++k) w0[k] = *(const bf16x8*)(wp + k * 32);
        }
        for (int nt = 0; nt < 16; ++nt) {
            const int g = ch * 16 + nt;               // 0..31 over (K4|V4)
            bf16x8 w1[8];
            if (nt + 1 < 16) {
                const __bf16* wp = W4kvb + (size_t)((g + 1) * 16 + lr) * DIM + lk;
#pragma unroll
                for (int k = 0; k < 8; ++k) w1[k] = *(const bf16x8*)(wp + k * 32);
            }
            f32x4 acc = {0.f, 0.f, 0.f, 0.f};
#pragma unroll
            for (int k = 0; k < 8; ++k)
                acc = __builtin_amdgcn_mfma_f32_16x16x32_bf16(a[k], w0[k], acc, 0, 0, 0);
            const float bias = Bi4[256 + g * 16 + lr];
            const int sec = g >> 4;                   // 0=K4 1=V4
            const int col = (g & 15) * 16 + lr;       // global d 0..255
            bf16x4 pv;
#pragma unroll
            for (int r = 0; r < 4; ++r) pv[r] = (__bf16)(acc[r] + bias);
            if (sec == 0) *(bf16x4*)(K4t + (size_t)col * 72 + tok0) = pv;
            else          *(bf16x4*)(V4t + (size_t)col * 72 + tok0) = pv;
#pragma unroll
            for (int k = 0; k < 8; ++k) w0[k] = w1[k];
        }
    }

    // ---- inner_c q-projection (fp32 VALU) ----
    {
        const int o = tid & 255, hf = tid >> 8;
        const float4* wr = (const float4*)(W4q + (size_t)o * DIM + hf * 128);
        const float4* xr = (const float4*)(inner + (size_t)b * DIM + hf * 128);
        float accq = 0.f;
#pragma unroll
        for (int k = 0; k < 32; ++k) accq += dot4(xr[k], wr[k]);
        qpart[hf * 256 + o] = accq;
    }
    __syncthreads();                                   // b6: K4t,V4t,qpart ready
    if (tid < 256) qv[tid] = (qpart[tid] + qpart[256 + tid] + Bi4[tid]) * SCALE;
    __syncthreads();

    // ---- inner_c scores + softmax (wave = head) ----
    {
        const int hh = tid >> 6, j = tid & 63;
        float sv = 0.f;
#pragma unroll
        for (int d = 0; d < 32; ++d)
            sv += qv[hh * 32 + d] * (float)K4t[(size_t)(hh * 32 + d) * 72 + j];
        float m = sv;
#pragma unroll
        for (int off = 1; off < 64; off <<= 1) m = fmaxf(m, __shfl_xor(m, off));
        const float p = __expf(sv - m);
        float t = p;
#pragma unroll
        for (int off = 1; off < 64; off <<= 1) t += __shfl_xor(t, off);
        psm[hh * 64 + j] = p / t;
    }
    __syncthreads();

    // ---- inner_c PV ----
    {
        const int o = tid & 255, hf = tid >> 8;
        const int hh = o >> 5;
        float acc2 = 0.f;
#pragma unroll
        for (int j = 0; j < 32; ++j)
            acc2 += psm[hh * 64 + hf * 32 + j] * (float)V4t[(size_t)o * 72 + hf * 32 + j];
        opart[hf * 256 + o] = acc2;
    }
    __syncthreads();
    if (tid < 256) Oc[(size_t)b * DIM + tid] = opart[tid] + opart[256 + tid];
}

// ---------------------------------------------------------------------------
// combine_leaf MFMA (round-2 verbatim, verified): out = wl0*tP + wl1*(O1 Wo^T + bo)
// ---------------------------------------------------------------------------
__global__ __launch_bounds__(256) void combleaf_mfma(
    const __bf16* __restrict__ O1, const __bf16* __restrict__ Wob,
    const float* __restrict__ Bo1, const float* __restrict__ tP,
    const float* __restrict__ wleaf, float* __restrict__ out)
{
    const int bid  = blockIdx.x;        // 2048 blocks x 64 rows
    const int tid  = threadIdx.x;
    const int wid  = tid >> 6;
    const int lane = tid & 63;
    const int lr   = lane & 15;
    const int lk   = (lane >> 4) * 8;

    bf16x8 a[8];
    {
        const __bf16* ar = O1 + ((size_t)bid * 64 + wid * 16 + lr) * DIM + lk;
#pragma unroll
        for (int k = 0; k < 8; ++k) a[k] = *(const bf16x8*)(ar + k * 32);
    }
    const float e0 = __expf(wleaf[0]), e1 = __expf(wleaf[1]);
    const float wl0 = e0 / (e0 + e1), wl1 = e1 / (e0 + e1);
    const size_t row0 = (size_t)bid * 64 + wid * 16 + (lane >> 4) * 4;

    for (int nt = 0; nt < 16; ++nt) {
        const __bf16* wp = Wob + (size_t)(nt * 16 + lr) * DIM + lk;
        f32x4 acc = {0.f, 0.f, 0.f, 0.f};
#pragma unroll
        for (int k = 0; k < 8; ++k)
            acc = __builtin_amdgcn_mfma_f32_16x16x32_bf16(
                a[k], *(const bf16x8*)(wp + k * 32), acc, 0, 0, 0);
        const int   o  = nt * 16 + lr;
        const float bo = Bo1[o];
        const float tv = tP[(size_t)bid * DIM + o];
#pragma unroll
        for (int r = 0; r < 4; ++r)
            out[(row0 + r) * DIM + o] = wl0 * tv + wl1 * (acc[r] + bo);
    }
}

// ---------------------------------------------------------------------------
// leaf_p degenerate path (round-1 verbatim)
// ---------------------------------------------------------------------------
__global__ __launch_bounds__(256) void leafp_kernel(
    const float* __restrict__ inner, const float* __restrict__ Wi,
    const float* __restrict__ Bi, const float* __restrict__ Wo,
    const float* __restrict__ Bo, float* __restrict__ tP)
{
    const int i   = blockIdx.x;
    const int tid = threadIdx.x;
    __shared__ float xv[DIM];
    __shared__ float vv[DIM];
    xv[tid] = inner[(size_t)i * DIM + tid];
    __syncthreads();
    {
        const int row = 2 * DIM + tid;
        const float4* wr = (const float4*)(Wi + (size_t)row * DIM);
        const float4* xr = (const float4*)xv;
        float acc = Bi[row];
        for (int k = 0; k < DIM / 4; ++k) acc += dot4(xr[k], wr[k]);
        vv[tid] = acc;
    }
    __syncthreads();
    {
        const float4* wr = (const float4*)(Wo + (size_t)tid * DIM);
        const float4* vr = (const float4*)vv;
        float acc = Bo[tid];
        for (int k = 0; k < DIM / 4; ++k) acc += dot4(vr[k], wr[k]);
        tP[(size_t)i * DIM + tid] = acc;
    }
}

// ---------------------------------------------------------------------------
// fp32 fused attention for the small paths (round-1 verbatim)
// ---------------------------------------------------------------------------
template <int LQ, int LK, int RQ>
__global__ __launch_bounds__(256) void attn_fused(
    const float* __restrict__ Xq, const float* __restrict__ Xkv,
    const float* __restrict__ Wi, const float* __restrict__ Bi,
    float* __restrict__ O)
{
    const int b   = blockIdx.x >> 3;
    const int h   = blockIdx.x & 7;
    const int tid = threadIdx.x;

    __shared__ float Ks[LK][33];
    __shared__ float Vs[LK][33];
    __shared__ float Qs[LQ][33];
    __shared__ float S[RQ][LK + 1];

    const float* xq  = Xq  + (size_t)b * LQ * DIM;
    const float* xkv = Xkv + (size_t)b * LK * DIM;

    {
        const int col   = tid & 63;
        const int which = col >> 5;
        const int d     = col & 31;
        const int row   = DIM + which * DIM + h * HD + d;
        const float4* wr = (const float4*)(Wi + (size_t)row * DIM);
        const float bias = Bi[row];
        constexpr int TT = LK / 4;
        float acc[TT];
#pragma unroll
        for (int i = 0; i < TT; ++i) acc[i] = 0.f;
        const int t0 = tid >> 6;
        for (int k4 = 0; k4 < DIM / 4; ++k4) {
            const float4 w = wr[k4];
#pragma unroll
            for (int i = 0; i < TT; ++i) {
                const int t = t0 + 4 * i;
                const float4 aa = ((const float4*)(xkv + (size_t)t * DIM))[k4];
                acc[i] += dot4(aa, w);
            }
        }
#pragma unroll
        for (int i = 0; i < TT; ++i) {
            const int t = t0 + 4 * i;
            if (which == 0) Ks[t][d] = acc[i] + bias;
            else            Vs[t][d] = acc[i] + bias;
        }
    }
    {
        constexpr int TGQ = (LQ >= 8) ? 8 : LQ;
        constexpr int TT  = LQ / TGQ;
        if (tid < 32 * TGQ) {
            const int d   = tid & 31;
            const int row = h * HD + d;
            const float4* wr = (const float4*)(Wi + (size_t)row * DIM);
            const float bias = Bi[row];
            float acc[TT];
#pragma unroll
            for (int i = 0; i < TT; ++i) acc[i] = 0.f;
            const int t0 = tid >> 5;
            for (int k4 = 0; k4 < DIM / 4; ++k4) {
                const float4 w = wr[k4];
#pragma unroll
                for (int i = 0; i < TT; ++i) {
                    const int t = t0 + TGQ * i;
                    const float4 aa = ((const float4*)(xq + (size_t)t * DIM))[k4];
                    acc[i] += dot4(aa, w);
                }
            }
#pragma unroll
            for (int i = 0; i < TT; ++i) {
                const int t = t0 + TGQ * i;
                Qs[t][d] = (acc[i] + bias) * SCALE;
            }
        }
    }
    __syncthreads();

    for (int q0 = 0; q0 < LQ; q0 += RQ) {
        for (int idx = tid; idx < RQ * LK; idx += 256) {
            const int r = idx / LK;
            const int j = idx - r * LK;
            float acc = 0.f;
#pragma unroll
            for (int d = 0; d < HD; ++d)
                acc += Qs[q0 + r][d] * Ks[j][d];
            S[r][j] = acc;
        }
        __syncthreads();
        if (tid < RQ * 8) {
            const int r   = tid >> 3;
            const int sub = tid & 7;
            float m = -1e30f;
            for (int j = sub; j < LK; j += 8) m = fmaxf(m, S[r][j]);
#pragma unroll
            for (int off = 4; off; off >>= 1) m = fmaxf(m, __shfl_xor(m, off, 8));
            float sum = 0.f;
            for (int j = sub; j < LK; j += 8) {
                const float p = __expf(S[r][j] - m);
                S[r][j] = p;
                sum += p;
            }
#pragma unroll
            for (int off = 4; off; off >>= 1) sum += __shfl_xor(sum, off, 8);
            const float inv = 1.0f / sum;
            for (int j = sub; j < LK; j += 8) S[r][j] *= inv;
        }
        __syncthreads();
        for (int idx = tid; idx < RQ * HD; idx += 256) {
            const int r = idx >> 5;
            const int d = idx & 31;
            float acc = 0.f;
            for (int j = 0; j < LK; ++j)
                acc += S[r][j] * Vs[j][d];
            O[((size_t)(b * LQ + q0 + r)) * DIM + h * HD + d] = acc;
        }
        __syncthreads();
    }
}

// ---------------------------------------------------------------------------
// combine_inner / combine_root (round-1 verbatim)
// ---------------------------------------------------------------------------
__global__ __launch_bounds__(256) void combine_inner(
    const float* __restrict__ Op, const float* __restrict__ Osf,
    const float* __restrict__ Oc,
    const float* __restrict__ W2, const float* __restrict__ B2,
    const float* __restrict__ W3, const float* __restrict__ B3,
    const float* __restrict__ W4, const float* __restrict__ B4,
    const float* __restrict__ winner, float* __restrict__ out)
{
    const int n0 = blockIdx.x * 32;
    const int o  = threadIdx.x;
    __shared__ float Ts[32][DIM];
    const float e0 = __expf(winner[0]), e1 = __expf(winner[1]), e2 = __expf(winner[2]);
    const float inv = 1.f / (e0 + e1 + e2);
    const float wt0 = e0 * inv, wt1 = e1 * inv, wt2 = e2 * inv;

    float acc[32];
#pragma unroll
    for (int r = 0; r < 32; ++r) acc[r] = 0.f;
    const float biasacc = wt0 * B2[o] + wt1 * B3[o] + wt2 * B4[o];

#pragma unroll
    for (int term = 0; term < 3; ++term) {
        const float* Ob = (term == 0) ? Op : (term == 1) ? Osf : Oc;
        const float* Wb = (term == 0) ? W2 : (term == 1) ? W3 : W4;
        const float wt  = (term == 0) ? wt0 : (term == 1) ? wt1 : wt2;
        __syncthreads();
        for (int idx = threadIdx.x; idx < 32 * DIM; idx += 256)
            Ts[idx >> 8][idx & 255] = Ob[(size_t)n0 * DIM + idx];
        __syncthreads();
        const float4* wr = (const float4*)(Wb + (size_t)o * DIM);
        for (int k4 = 0; k4 < DIM / 4; ++k4) {
            float4 w = wr[k4];
            w.x *= wt; w.y *= wt; w.z *= wt; w.w *= wt;
#pragma unroll
            for (int r = 0; r < 32; ++r) {
                const float4 aa = *(const float4*)&Ts[r][k4 * 4];
                acc[r] += dot4(aa, w);
            }
        }
    }
#pragma unroll
    for (int r = 0; r < 32; ++r)
        out[(size_t)(n0 + r) * DIM + o] = acc[r] + biasacc;
}

__global__ __launch_bounds__(256) void combine_root(
    const float* __restrict__ Ors, const float* __restrict__ Orc,
    const float* __restrict__ W5, const float* __restrict__ B5,
    const float* __restrict__ wroot, float* __restrict__ out)
{
    const int n0 = blockIdx.x * 32;
    const int o  = threadIdx.x;
    __shared__ float Ts[32][DIM];
    const float e0 = __expf(wroot[0]), e1 = __expf(wroot[1]);
    const float w0 = e0 / (e0 + e1), w1 = e1 / (e0 + e1);
    for (int idx = threadIdx.x; idx < 32 * DIM; idx += 256)
        Ts[idx >> 8][idx & 255] = w0 * Ors[(size_t)n0 * DIM + idx] +
                                  w1 * Orc[(size_t)n0 * DIM + idx];
    __syncthreads();
    float acc[32];
#pragma unroll
    for (int r = 0; r < 32; ++r) acc[r] = 0.f;
    const float4* wr = (const float4*)(W5 + (size_t)o * DIM);
    for (int k4 = 0; k4 < DIM / 4; ++k4) {
        const float4 w = wr[k4];
#pragma unroll
        for (int r = 0; r < 32; ++r) {
            const float4 aa = *(const float4*)&Ts[r][k4 * 4];
            acc[r] += dot4(aa, w);
        }
    }
    const float bo = B5[o];
#pragma unroll
    for (int r = 0; r < 32; ++r)
        out[(size_t)(n0 + r) * DIM + o] = acc[r] + bo;
}

// ---------------------------------------------------------------------------
extern "C" void kernel_launch(void* const* d_in, const int* in_sizes, int n_in,
                              void* d_out, int out_size, void* d_ws, size_t ws_size,
                              hipStream_t stream)
{
    const float* leaf   = (const float*)d_in[0];
    const float* inner  = (const float*)d_in[1];
    const float* root   = (const float*)d_in[2];
    const float* w_in   = (const float*)d_in[3];
    const float* b_in   = (const float*)d_in[4];
    const float* w_out  = (const float*)d_in[5];
    const float* b_out  = (const float*)d_in[6];
    const float* wleaf  = (const float*)d_in[7];
    const float* winner = (const float*)d_in[8];
    const float* wroot  = (const float*)d_in[9];
    float* out = (float*)d_out;

    const size_t WI = 768 * 256, BI = 768, WO = 256 * 256, BO = 256;

    // ws layout
    char* ws = (char*)d_ws;
    __bf16* W1b   = (__bf16*)(ws);                    // 393216 B
    __bf16* W4kvb = (__bf16*)(ws + 393216);           // 262144 B
    __bf16* Wo1b  = (__bf16*)(ws + 655360);           // 131072 B
    __bf16* O1b   = (__bf16*)(ws + 786432);           // 67108864 B
    float*  tP    = (float*)(ws + 67895296);          // 2097152 B
    float*  Oc    = (float*)(ws + 69992448);
    float*  Op    = (float*)(ws + 72089600);
    float*  Osf   = (float*)(ws + 74186752);
    float*  Ors   = (float*)(ws + 76283904);
    float*  Orc   = (float*)(ws + 76546048);

    cvt_f2b<<<192, 256, 0, stream>>>(w_in + 1 * WI, W1b, 768 * 256);
    cvt_f2b<<<128, 256, 0, stream>>>(w_in + 4 * WI + 256 * 256, W4kvb, 512 * 256);
    cvt_f2b<<<64, 256, 0, stream>>>(w_out + 1 * WO, Wo1b, 256 * 256);

    leafp_kernel<<<2048, 256, 0, stream>>>(inner, w_in, b_in, w_out, b_out, tP);

    // mega: leaf_s attention + inner_c (leaf read once)
    leaf_mega<<<2048, 512, 133120, stream>>>(
        leaf, inner, W1b, b_in + 1 * BI, W4kvb, w_in + 4 * WI, b_in + 4 * BI,
        O1b, Oc);

    // small fp32 attention paths
    attn_fused<128, 16, 32><<<16 * 8, 256, 0, stream>>>(inner, root, w_in + 2 * WI, b_in + 2 * BI, Op);
    attn_fused<128, 128, 16><<<16 * 8, 256, 0, stream>>>(inner, inner, w_in + 3 * WI, b_in + 3 * BI, Osf);
    attn_fused<16, 16, 16><<<16 * 8, 256, 0, stream>>>(root, root, w_in + 5 * WI, b_in + 5 * BI, Ors);
    attn_fused<16, 128, 16><<<16 * 8, 256, 0, stream>>>(root, inner, w_in + 5 * WI, b_in + 5 * BI, Orc);

    // combines
    combleaf_mfma<<<2048, 256, 0, stream>>>(O1b, Wo1b, b_out + BO, tP, wleaf, out);
    combine_inner<<<2048 / 32, 256, 0, stream>>>(Op, Osf, Oc, w_out + 2 * WO, b_out + 2 * BO,
                                                 w_out + 3 * WO, b_out + 3 * BO,
                                                 w_out + 4 * WO, b_out + 4 * BO,
                                                 winner, out + 33554432);
    combine_root<<<256 / 32, 256, 0, stream>>>(Ors, Orc, w_out + 5 * WO, b_out + 5 * BO,
                                               wroot, out + 33554432 + 524288);
}

// Round 5
// 1525.168 us; speedup vs baseline: 4.5855x; 1.0020x over previous
//
#include <hip/hip_runtime.h>
#include <hip/hip_bf16.h>
#include <cstdint>

// AttnLayerBU round 5: mega with ILP (split accumulate chains + 2-deep weight
// prefetch) and fused out-projection (combleaf folded in; O never hits HBM).
// LDS map (133120 B):
//   0      Qs[64][264] (33792)   | phase B: K4t[256][72] (36864, incl. gap)
//   36864  Ks[64][264] (33792)
//   70656  Vt[256][72] (36864)   | after vb-loads barrier: Os[64][264];
//                                | phase B: V4t[256][72]
//   107520 Pw 8 x [16][72] per-wave (18432)
//   125952 scratch qpart/qv/psm/opart (7168)
// Barrier chain: b1(QKV ready) -> QK^T+softmax+vb -> b2(Vt reads done) ->
// PV writes Pw+Os -> b3(Os ready) -> out-proj -> b4 -> phase B -> b5...

#define DIM 256
#define NH 8
#define HD 32

static constexpr float SCALE = 0.17677669529663687f; // 32^-0.5

typedef __bf16 bf16x8 __attribute__((ext_vector_type(8)));
typedef __bf16 bf16x4 __attribute__((ext_vector_type(4)));
typedef float  f32x4  __attribute__((ext_vector_type(4)));

__device__ __forceinline__ float dot4(const float4 a, const float4 b) {
    return a.x * b.x + a.y * b.y + a.z * b.z + a.w * b.w;
}

// ---------------------------------------------------------------------------
__global__ __launch_bounds__(256) void cvt_f2b(const float* __restrict__ s,
                                               __bf16* __restrict__ d, int n) {
    int i = (blockIdx.x * 256 + threadIdx.x) * 4;
    if (i < n) {
        float4 v = *(const float4*)(s + i);
        d[i + 0] = (__bf16)v.x; d[i + 1] = (__bf16)v.y;
        d[i + 2] = (__bf16)v.z; d[i + 3] = (__bf16)v.w;
    }
}

// ---------------------------------------------------------------------------
__global__ __launch_bounds__(512, 2) void leaf_mega(
    const float* __restrict__ X,       // leaf (131072, 256)
    const float* __restrict__ inner,   // (2048, 256)
    const __bf16* __restrict__ W1b,    // set1 W (768,256) bf16
    const float* __restrict__ Bi1,     // set1 b (768)
    const __bf16* __restrict__ W4kvb,  // set4 W rows 256..767 bf16 (512,256)
    const float* __restrict__ W4q,     // set4 W fp32 (rows 0..255 used)
    const float* __restrict__ Bi4,     // set4 b (768)
    const __bf16* __restrict__ Wo1b,   // set1 Wo (256,256) bf16
    const float* __restrict__ Bo1,     // set1 bo (256)
    const float* __restrict__ tP,      // leaf_p per-tile vec (2048,256)
    const float* __restrict__ wleaf,   // (2)
    float* __restrict__ outLeaf,       // leaf_out (131072,256) fp32
    float* __restrict__ Oc)            // inner_c attn out (2048,256) fp32
{
    extern __shared__ __align__(16) char smem[];
    const int b    = blockIdx.x;
    const int tid  = threadIdx.x;
    const int wid  = tid >> 6;
    const int lane = tid & 63;
    const int lr   = lane & 15;
    const int lk   = (lane >> 4) * 8;
    const int rg   = wid & 3;          // A-row group (rows rg*16..+15)
    const int ch   = wid >> 2;         // n-column half
    const int tok0 = rg * 16 + (lane >> 4) * 4;
    const int prow = (lane >> 4) * 4;

    __bf16* Qs  = (__bf16*)smem;                       // [64][264]
    __bf16* Ks  = (__bf16*)(smem + 36864);             // [64][264]
    __bf16* Vt  = (__bf16*)(smem + 70656);             // [256][72]
    __bf16* Os  = (__bf16*)(smem + 70656);             // [64][264] (post-b2)
    __bf16* Pw  = (__bf16*)(smem + 107520 + wid * 2304); // per-wave [16][72]
    __bf16* K4t = (__bf16*)smem;                       // [256][72] phase B
    __bf16* V4t = (__bf16*)(smem + 70656);             // [256][72] phase B
    float* qpart = (float*)(smem + 125952);            // [2][256]
    float* qv    = qpart + 512;                        // [256]
    float* psm   = qv + 256;                           // [8][64]
    float* opart = psm + 512;                          // [2][256]

    // ---- A-fragments: 16 leaf rows per row-group, fp32 -> bf16 ----
    bf16x8 a[8];
    {
        const float* xrow = X + ((size_t)b * 64 + rg * 16 + lr) * DIM + lk;
#pragma unroll
        for (int k = 0; k < 8; ++k) {
            float4 v0 = *(const float4*)(xrow + k * 32);
            float4 v1 = *(const float4*)(xrow + k * 32 + 4);
            bf16x8 t;
            t[0] = (__bf16)v0.x; t[1] = (__bf16)v0.y; t[2] = (__bf16)v0.z; t[3] = (__bf16)v0.w;
            t[4] = (__bf16)v1.x; t[5] = (__bf16)v1.y; t[6] = (__bf16)v1.z; t[7] = (__bf16)v1.w;
            a[k] = t;
        }
    }

    // ---- Phase A: W1 Q/K/V projection, 24 tiles/wave, 2-deep prefetch,
    //      split accumulate chains ----
    {
        const int base = ch * 24;
        bf16x8 w0[8], w1[8], w2[8];
        {
            const __bf16* wp = W1b + (size_t)(base * 16 + lr) * DIM + lk;
#pragma unroll
            for (int k = 0; k < 8; ++k) w0[k] = *(const bf16x8*)(wp + k * 32);
        }
        {
            const __bf16* wp = W1b + (size_t)((base + 1) * 16 + lr) * DIM + lk;
#pragma unroll
            for (int k = 0; k < 8; ++k) w1[k] = *(const bf16x8*)(wp + k * 32);
        }
#pragma unroll 3
        for (int nt = 0; nt < 24; ++nt) {
            const int g = base + nt;
            if (nt + 2 < 24) {
                const __bf16* wp = W1b + (size_t)((g + 2) * 16 + lr) * DIM + lk;
#pragma unroll
                for (int k = 0; k < 8; ++k) w2[k] = *(const bf16x8*)(wp + k * 32);
            }
            f32x4 aL = {0.f, 0.f, 0.f, 0.f}, aH = {0.f, 0.f, 0.f, 0.f};
#pragma unroll
            for (int k = 0; k < 4; ++k) {
                aL = __builtin_amdgcn_mfma_f32_16x16x32_bf16(a[k],     w0[k],     aL, 0, 0, 0);
                aH = __builtin_amdgcn_mfma_f32_16x16x32_bf16(a[k + 4], w0[k + 4], aH, 0, 0, 0);
            }
            const f32x4 acc = aL + aH;
            const float bias = Bi1[g * 16 + lr];
            if (g < 16) {               // Q (scaled)
                const int col = g * 16 + lr;
#pragma unroll
                for (int r = 0; r < 4; ++r)
                    Qs[(size_t)(tok0 + r) * 264 + col] = (__bf16)((acc[r] + bias) * SCALE);
            } else if (g < 32) {        // K
                const int col = (g - 16) * 16 + lr;
#pragma unroll
                for (int r = 0; r < 4; ++r)
                    Ks[(size_t)(tok0 + r) * 264 + col] = (__bf16)(acc[r] + bias);
            } else {                    // V -> transposed [d][tok]
                const int col = (g - 32) * 16 + lr;
                bf16x4 pv;
#pragma unroll
                for (int r = 0; r < 4; ++r) pv[r] = (__bf16)(acc[r] + bias);
                *(bf16x4*)(Vt + (size_t)col * 72 + tok0) = pv;
            }
#pragma unroll
            for (int k = 0; k < 8; ++k) { w0[k] = w1[k]; w1[k] = w2[k]; }
        }
    }
    __syncthreads();                                   // b1: Q,K,Vt ready

    // ---- QK^T: wave = head h ----
    const int h = wid;
    f32x4 s[4][4];
    {
        bf16x8 kb[4];
#pragma unroll
        for (int kt = 0; kt < 4; ++kt)
            kb[kt] = *(const bf16x8*)(Ks + (size_t)(kt * 16 + lr) * 264 + h * 32 + lk);
#pragma unroll
        for (int qt = 0; qt < 4; ++qt) {
            const bf16x8 qa = *(const bf16x8*)(Qs + (size_t)(qt * 16 + lr) * 264 + h * 32 + lk);
#pragma unroll
            for (int kt = 0; kt < 4; ++kt) {
                f32x4 z = {0.f, 0.f, 0.f, 0.f};
                s[qt][kt] = __builtin_amdgcn_mfma_f32_16x16x32_bf16(qa, kb[kt], z, 0, 0, 0);
            }
        }
    }

    // ---- softmax in registers ----
#pragma unroll
    for (int qt = 0; qt < 4; ++qt) {
#pragma unroll
        for (int r = 0; r < 4; ++r) {
            float m = fmaxf(fmaxf(s[qt][0][r], s[qt][1][r]), fmaxf(s[qt][2][r], s[qt][3][r]));
#pragma unroll
            for (int off = 1; off < 16; off <<= 1) m = fmaxf(m, __shfl_xor(m, off));
            const float p0 = __expf(s[qt][0][r] - m), p1 = __expf(s[qt][1][r] - m);
            const float p2 = __expf(s[qt][2][r] - m), p3 = __expf(s[qt][3][r] - m);
            float t = p0 + p1 + p2 + p3;
#pragma unroll
            for (int off = 1; off < 16; off <<= 1) t += __shfl_xor(t, off);
            const float inv = 1.0f / t;
            s[qt][0][r] = p0 * inv; s[qt][1][r] = p1 * inv;
            s[qt][2][r] = p2 * inv; s[qt][3][r] = p3 * inv;
        }
    }

    // ---- V fragments to registers, then free the Vt region ----
    bf16x8 vb[2][2];
#pragma unroll
    for (int dt = 0; dt < 2; ++dt)
#pragma unroll
        for (int ks = 0; ks < 2; ++ks)
            vb[dt][ks] = *(const bf16x8*)(Vt + (size_t)(h * 32 + dt * 16 + lr) * 72 + ks * 32 + lk);
    __syncthreads();                                   // b2: all Vt/Qs/Ks reads done

    // ---- PV per q-tile; O -> Os (Vt region overlay) ----
#pragma unroll
    for (int qt = 0; qt < 4; ++qt) {
#pragma unroll
        for (int kt = 0; kt < 4; ++kt)
#pragma unroll
            for (int r = 0; r < 4; ++r)
                Pw[(size_t)(prow + r) * 72 + kt * 16 + lr] = (__bf16)s[qt][kt][r];
        bf16x8 pa[2];
#pragma unroll
        for (int ks = 0; ks < 2; ++ks)
            pa[ks] = *(const bf16x8*)(Pw + (size_t)lr * 72 + ks * 32 + lk);
#pragma unroll
        for (int dt = 0; dt < 2; ++dt) {
            f32x4 o = {0.f, 0.f, 0.f, 0.f};
#pragma unroll
            for (int ks = 0; ks < 2; ++ks)
                o = __builtin_amdgcn_mfma_f32_16x16x32_bf16(pa[ks], vb[dt][ks], o, 0, 0, 0);
#pragma unroll
            for (int r = 0; r < 4; ++r)
                Os[(size_t)(qt * 16 + prow + r) * 264 + h * 32 + dt * 16 + lr] = (__bf16)o[r];
        }
    }
    __syncthreads();                                   // b3: Os complete

    // ---- out-projection + wl mix -> leaf_out (fused combleaf) ----
    {
        const float e0 = __expf(wleaf[0]), e1 = __expf(wleaf[1]);
        const float wl0 = e0 / (e0 + e1), wl1 = e1 / (e0 + e1);
        bf16x8 ao[8];
#pragma unroll
        for (int k = 0; k < 8; ++k)
            ao[k] = *(const bf16x8*)(Os + (size_t)(rg * 16 + lr) * 264 + k * 32 + lk);
        const int obase = ch * 8;                      // 8 n-tiles per wave
        bf16x8 w0[8], w1[8], w2[8];
        {
            const __bf16* wp = Wo1b + (size_t)(obase * 16 + lr) * DIM + lk;
#pragma unroll
            for (int k = 0; k < 8; ++k) w0[k] = *(const bf16x8*)(wp + k * 32);
        }
        {
            const __bf16* wp = Wo1b + (size_t)((obase + 1) * 16 + lr) * DIM + lk;
#pragma unroll
            for (int k = 0; k < 8; ++k) w1[k] = *(const bf16x8*)(wp + k * 32);
        }
#pragma unroll 2
        for (int nt = 0; nt < 8; ++nt) {
            const int g = obase + nt;
            if (nt + 2 < 8) {
                const __bf16* wp = Wo1b + (size_t)((g + 2) * 16 + lr) * DIM + lk;
#pragma unroll
                for (int k = 0; k < 8; ++k) w2[k] = *(const bf16x8*)(wp + k * 32);
            }
            f32x4 aL = {0.f, 0.f, 0.f, 0.f}, aH = {0.f, 0.f, 0.f, 0.f};
#pragma unroll
            for (int k = 0; k < 4; ++k) {
                aL = __builtin_amdgcn_mfma_f32_16x16x32_bf16(ao[k],     w0[k],     aL, 0, 0, 0);
                aH = __builtin_amdgcn_mfma_f32_16x16x32_bf16(ao[k + 4], w0[k + 4], aH, 0, 0, 0);
            }
            const f32x4 acc = aL + aH;
            const int   col = g * 16 + lr;
            const float bo  = Bo1[col];
            const float tv  = tP[(size_t)b * DIM + col];
#pragma unroll
            for (int r = 0; r < 4; ++r)
                outLeaf[((size_t)b * 64 + rg * 16 + prow + r) * DIM + col] =
                    wl0 * tv + wl1 * (acc[r] + bo);
#pragma unroll
            for (int k = 0; k < 8; ++k) { w0[k] = w1[k]; w1[k] = w2[k]; }
        }
    }
    __syncthreads();                                   // b4: Os reads done, LDS free

    // ---- Phase B: W4 K/V projection, 16 tiles/wave, 2-deep prefetch ----
    {
        const int base = ch * 16;
        bf16x8 w0[8], w1[8], w2[8];
        {
            const __bf16* wp = W4kvb + (size_t)(base * 16 + lr) * DIM + lk;
#pragma unroll
            for (int k = 0; k < 8; ++k) w0[k] = *(const bf16x8*)(wp + k * 32);
        }
        {
            const __bf16* wp = W4kvb + (size_t)((base + 1) * 16 + lr) * DIM + lk;
#pragma unroll
            for (int k = 0; k < 8; ++k) w1[k] = *(const bf16x8*)(wp + k * 32);
        }
#pragma unroll 3
        for (int nt = 0; nt < 16; ++nt) {
            const int g = base + nt;                  // 0..31 over (K4|V4)
            if (nt + 2 < 16) {
                const __bf16* wp = W4kvb + (size_t)((g + 2) * 16 + lr) * DIM + lk;
#pragma unroll
                for (int k = 0; k < 8; ++k) w2[k] = *(const bf16x8*)(wp + k * 32);
            }
            f32x4 aL = {0.f, 0.f, 0.f, 0.f}, aH = {0.f, 0.f, 0.f, 0.f};
#pragma unroll
            for (int k = 0; k < 4; ++k) {
                aL = __builtin_amdgcn_mfma_f32_16x16x32_bf16(a[k],     w0[k],     aL, 0, 0, 0);
                aH = __builtin_amdgcn_mfma_f32_16x16x32_bf16(a[k + 4], w0[k + 4], aH, 0, 0, 0);
            }
            const f32x4 acc = aL + aH;
            const float bias = Bi4[256 + g * 16 + lr];
            const int sec = g >> 4;                   // 0=K4 1=V4
            const int col = (g & 15) * 16 + lr;       // d 0..255
            bf16x4 pv;
#pragma unroll
            for (int r = 0; r < 4; ++r) pv[r] = (__bf16)(acc[r] + bias);
            if (sec == 0) *(bf16x4*)(K4t + (size_t)col * 72 + tok0) = pv;
            else          *(bf16x4*)(V4t + (size_t)col * 72 + tok0) = pv;
#pragma unroll
            for (int k = 0; k < 8; ++k) { w0[k] = w1[k]; w1[k] = w2[k]; }
        }
    }

    // ---- inner_c q-projection (fp32 VALU) ----
    {
        const int o = tid & 255, hf = tid >> 8;
        const float4* wr = (const float4*)(W4q + (size_t)o * DIM + hf * 128);
        const float4* xr = (const float4*)(inner + (size_t)b * DIM + hf * 128);
        float accq = 0.f;
#pragma unroll
        for (int k = 0; k < 32; ++k) accq += dot4(xr[k], wr[k]);
        qpart[hf * 256 + o] = accq;
    }
    __syncthreads();                                   // b5: K4t,V4t,qpart ready
    if (tid < 256) qv[tid] = (qpart[tid] + qpart[256 + tid] + Bi4[tid]) * SCALE;
    __syncthreads();

    // ---- inner_c scores + softmax (wave = head) ----
    {
        const int hh = tid >> 6, j = tid & 63;
        float sv = 0.f;
#pragma unroll
        for (int d = 0; d < 32; ++d)
            sv += qv[hh * 32 + d] * (float)K4t[(size_t)(hh * 32 + d) * 72 + j];
        float m = sv;
#pragma unroll
        for (int off = 1; off < 64; off <<= 1) m = fmaxf(m, __shfl_xor(m, off));
        const float p = __expf(sv - m);
        float t = p;
#pragma unroll
        for (int off = 1; off < 64; off <<= 1) t += __shfl_xor(t, off);
        psm[hh * 64 + j] = p / t;
    }
    __syncthreads();

    // ---- inner_c PV ----
    {
        const int o = tid & 255, hf = tid >> 8;
        const int hh = o >> 5;
        float acc2 = 0.f;
#pragma unroll
        for (int j = 0; j < 32; ++j)
            acc2 += psm[hh * 64 + hf * 32 + j] * (float)V4t[(size_t)o * 72 + hf * 32 + j];
        opart[hf * 256 + o] = acc2;
    }
    __syncthreads();
    if (tid < 256) Oc[(size_t)b * DIM + tid] = opart[tid] + opart[256 + tid];
}

// ---------------------------------------------------------------------------
// leaf_p degenerate path (round-1 verbatim)
// ---------------------------------------------------------------------------
__global__ __launch_bounds__(256) void leafp_kernel(
    const float* __restrict__ inner, const float* __restrict__ Wi,
    const float* __restrict__ Bi, const float* __restrict__ Wo,
    const float* __restrict__ Bo, float* __restrict__ tP)
{
    const int i   = blockIdx.x;
    const int tid = threadIdx.x;
    __shared__ float xv[DIM];
    __shared__ float vv[DIM];
    xv[tid] = inner[(size_t)i * DIM + tid];
    __syncthreads();
    {
        const int row = 2 * DIM + tid;
        const float4* wr = (const float4*)(Wi + (size_t)row * DIM);
        const float4* xr = (const float4*)xv;
        float acc = Bi[row];
        for (int k = 0; k < DIM / 4; ++k) acc += dot4(xr[k], wr[k]);
        vv[tid] = acc;
    }
    __syncthreads();
    {
        const float4* wr = (const float4*)(Wo + (size_t)tid * DIM);
        const float4* vr = (const float4*)vv;
        float acc = Bo[tid];
        for (int k = 0; k < DIM / 4; ++k) acc += dot4(vr[k], wr[k]);
        tP[(size_t)i * DIM + tid] = acc;
    }
}

// ---------------------------------------------------------------------------
// fp32 fused attention for the small paths (round-1 verbatim)
// ---------------------------------------------------------------------------
template <int LQ, int LK, int RQ>
__global__ __launch_bounds__(256) void attn_fused(
    const float* __restrict__ Xq, const float* __restrict__ Xkv,
    const float* __restrict__ Wi, const float* __restrict__ Bi,
    float* __restrict__ O)
{
    const int b   = blockIdx.x >> 3;
    const int h   = blockIdx.x & 7;
    const int tid = threadIdx.x;

    __shared__ float Ks[LK][33];
    __shared__ float Vs[LK][33];
    __shared__ float Qs[LQ][33];
    __shared__ float S[RQ][LK + 1];

    const float* xq  = Xq  + (size_t)b * LQ * DIM;
    const float* xkv = Xkv + (size_t)b * LK * DIM;

    {
        const int col   = tid & 63;
        const int which = col >> 5;
        const int d     = col & 31;
        const int row   = DIM + which * DIM + h * HD + d;
        const float4* wr = (const float4*)(Wi + (size_t)row * DIM);
        const float bias = Bi[row];
        constexpr int TT = LK / 4;
        float acc[TT];
#pragma unroll
        for (int i = 0; i < TT; ++i) acc[i] = 0.f;
        const int t0 = tid >> 6;
        for (int k4 = 0; k4 < DIM / 4; ++k4) {
            const float4 w = wr[k4];
#pragma unroll
            for (int i = 0; i < TT; ++i) {
                const int t = t0 + 4 * i;
                const float4 aa = ((const float4*)(xkv + (size_t)t * DIM))[k4];
                acc[i] += dot4(aa, w);
            }
        }
#pragma unroll
        for (int i = 0; i < TT; ++i) {
            const int t = t0 + 4 * i;
            if (which == 0) Ks[t][d] = acc[i] + bias;
            else            Vs[t][d] = acc[i] + bias;
        }
    }
    {
        constexpr int TGQ = (LQ >= 8) ? 8 : LQ;
        constexpr int TT  = LQ / TGQ;
        if (tid < 32 * TGQ) {
            const int d   = tid & 31;
            const int row = h * HD + d;
            const float4* wr = (const float4*)(Wi + (size_t)row * DIM);
            const float bias = Bi[row];
            float acc[TT];
#pragma unroll
            for (int i = 0; i < TT; ++i) acc[i] = 0.f;
            const int t0 = tid >> 5;
            for (int k4 = 0; k4 < DIM / 4; ++k4) {
                const float4 w = wr[k4];
#pragma unroll
                for (int i = 0; i < TT; ++i) {
                    const int t = t0 + TGQ * i;
                    const float4 aa = ((const float4*)(xq + (size_t)t * DIM))[k4];
                    acc[i] += dot4(aa, w);
                }
            }
#pragma unroll
            for (int i = 0; i < TT; ++i) {
                const int t = t0 + TGQ * i;
                Qs[t][d] = (acc[i] + bias) * SCALE;
            }
        }
    }
    __syncthreads();

    for (int q0 = 0; q0 < LQ; q0 += RQ) {
        for (int idx = tid; idx < RQ * LK; idx += 256) {
            const int r = idx / LK;
            const int j = idx - r * LK;
            float acc = 0.f;
#pragma unroll
            for (int d = 0; d < HD; ++d)
                acc += Qs[q0 + r][d] * Ks[j][d];
            S[r][j] = acc;
        }
        __syncthreads();
        if (tid < RQ * 8) {
            const int r   = tid >> 3;
            const int sub = tid & 7;
            float m = -1e30f;
            for (int j = sub; j < LK; j += 8) m = fmaxf(m, S[r][j]);
#pragma unroll
            for (int off = 4; off; off >>= 1) m = fmaxf(m, __shfl_xor(m, off, 8));
            float sum = 0.f;
            for (int j = sub; j < LK; j += 8) {
                const float p = __expf(S[r][j] - m);
                S[r][j] = p;
                sum += p;
            }
#pragma unroll
            for (int off = 4; off; off >>= 1) sum += __shfl_xor(sum, off, 8);
            const float inv = 1.0f / sum;
            for (int j = sub; j < LK; j += 8) S[r][j] *= inv;
        }
        __syncthreads();
        for (int idx = tid; idx < RQ * HD; idx += 256) {
            const int r = idx >> 5;
            const int d = idx & 31;
            float acc = 0.f;
            for (int j = 0; j < LK; ++j)
                acc += S[r][j] * Vs[j][d];
            O[((size_t)(b * LQ + q0 + r)) * DIM + h * HD + d] = acc;
        }
        __syncthreads();
    }
}

// ---------------------------------------------------------------------------
// combine_inner / combine_root (round-1 verbatim)
// ---------------------------------------------------------------------------
__global__ __launch_bounds__(256) void combine_inner(
    const float* __restrict__ Op, const float* __restrict__ Osf,
    const float* __restrict__ Oc,
    const float* __restrict__ W2, const float* __restrict__ B2,
    const float* __restrict__ W3, const float* __restrict__ B3,
    const float* __restrict__ W4, const float* __restrict__ B4,
    const float* __restrict__ winner, float* __restrict__ out)
{
    const int n0 = blockIdx.x * 32;
    const int o  = threadIdx.x;
    __shared__ float Ts[32][DIM];
    const float e0 = __expf(winner[0]), e1 = __expf(winner[1]), e2 = __expf(winner[2]);
    const float inv = 1.f / (e0 + e1 + e2);
    const float wt0 = e0 * inv, wt1 = e1 * inv, wt2 = e2 * inv;

    float acc[32];
#pragma unroll
    for (int r = 0; r < 32; ++r) acc[r] = 0.f;
    const float biasacc = wt0 * B2[o] + wt1 * B3[o] + wt2 * B4[o];

#pragma unroll
    for (int term = 0; term < 3; ++term) {
        const float* Ob = (term == 0) ? Op : (term == 1) ? Osf : Oc;
        const float* Wb = (term == 0) ? W2 : (term == 1) ? W3 : W4;
        const float wt  = (term == 0) ? wt0 : (term == 1) ? wt1 : wt2;
        __syncthreads();
        for (int idx = threadIdx.x; idx < 32 * DIM; idx += 256)
            Ts[idx >> 8][idx & 255] = Ob[(size_t)n0 * DIM + idx];
        __syncthreads();
        const float4* wr = (const float4*)(Wb + (size_t)o * DIM);
        for (int k4 = 0; k4 < DIM / 4; ++k4) {
            float4 w = wr[k4];
            w.x *= wt; w.y *= wt; w.z *= wt; w.w *= wt;
#pragma unroll
            for (int r = 0; r < 32; ++r) {
                const float4 aa = *(const float4*)&Ts[r][k4 * 4];
                acc[r] += dot4(aa, w);
            }
        }
    }
#pragma unroll
    for (int r = 0; r < 32; ++r)
        out[(size_t)(n0 + r) * DIM + o] = acc[r] + biasacc;
}

__global__ __launch_bounds__(256) void combine_root(
    const float* __restrict__ Ors, const float* __restrict__ Orc,
    const float* __restrict__ W5, const float* __restrict__ B5,
    const float* __restrict__ wroot, float* __restrict__ out)
{
    const int n0 = blockIdx.x * 32;
    const int o  = threadIdx.x;
    __shared__ float Ts[32][DIM];
    const float e0 = __expf(wroot[0]), e1 = __expf(wroot[1]);
    const float w0 = e0 / (e0 + e1), w1 = e1 / (e0 + e1);
    for (int idx = threadIdx.x; idx < 32 * DIM; idx += 256)
        Ts[idx >> 8][idx & 255] = w0 * Ors[(size_t)n0 * DIM + idx] +
                                  w1 * Orc[(size_t)n0 * DIM + idx];
    __syncthreads();
    float acc[32];
#pragma unroll
    for (int r = 0; r < 32; ++r) acc[r] = 0.f;
    const float4* wr = (const float4*)(W5 + (size_t)o * DIM);
    for (int k4 = 0; k4 < DIM / 4; ++k4) {
        const float4 w = wr[k4];
#pragma unroll
        for (int r = 0; r < 32; ++r) {
            const float4 aa = *(const float4*)&Ts[r][k4 * 4];
            acc[r] += dot4(aa, w);
        }
    }
    const float bo = B5[o];
#pragma unroll
    for (int r = 0; r < 32; ++r)
        out[(size_t)(n0 + r) * DIM + o] = acc[r] + bo;
}

// ---------------------------------------------------------------------------
extern "C" void kernel_launch(void* const* d_in, const int* in_sizes, int n_in,
                              void* d_out, int out_size, void* d_ws, size_t ws_size,
                              hipStream_t stream)
{
    const float* leaf   = (const float*)d_in[0];
    const float* inner  = (const float*)d_in[1];
    const float* root   = (const float*)d_in[2];
    const float* w_in   = (const float*)d_in[3];
    const float* b_in   = (const float*)d_in[4];
    const float* w_out  = (const float*)d_in[5];
    const float* b_out  = (const float*)d_in[6];
    const float* wleaf  = (const float*)d_in[7];
    const float* winner = (const float*)d_in[8];
    const float* wroot  = (const float*)d_in[9];
    float* out = (float*)d_out;

    const size_t WI = 768 * 256, BI = 768, WO = 256 * 256, BO = 256;

    // ws layout
    char* ws = (char*)d_ws;
    __bf16* W1b   = (__bf16*)(ws);                    // 393216 B
    __bf16* W4kvb = (__bf16*)(ws + 393216);           // 262144 B
    __bf16* Wo1b  = (__bf16*)(ws + 655360);           // 131072 B
    float*  tP    = (float*)(ws + 786432);            // 2097152 B
    float*  Oc    = (float*)(ws + 2883584);           // 2097152 B
    float*  Op    = (float*)(ws + 4980736);
    float*  Osf   = (float*)(ws + 7077888);
    float*  Ors   = (float*)(ws + 9175040);
    float*  Orc   = (float*)(ws + 9437184);

    cvt_f2b<<<192, 256, 0, stream>>>(w_in + 1 * WI, W1b, 768 * 256);
    cvt_f2b<<<128, 256, 0, stream>>>(w_in + 4 * WI + 256 * 256, W4kvb, 512 * 256);
    cvt_f2b<<<64, 256, 0, stream>>>(w_out + 1 * WO, Wo1b, 256 * 256);

    leafp_kernel<<<2048, 256, 0, stream>>>(inner, w_in, b_in, w_out, b_out, tP);

    // mega: leaf_s attention + out-proj + inner_c (leaf read once, O in LDS)
    leaf_mega<<<2048, 512, 133120, stream>>>(
        leaf, inner, W1b, b_in + 1 * BI, W4kvb, w_in + 4 * WI, b_in + 4 * BI,
        Wo1b, b_out + 1 * BO, tP, wleaf, out, Oc);

    // small fp32 attention paths
    attn_fused<128, 16, 32><<<16 * 8, 256, 0, stream>>>(inner, root, w_in + 2 * WI, b_in + 2 * BI, Op);
    attn_fused<128, 128, 16><<<16 * 8, 256, 0, stream>>>(inner, inner, w_in + 3 * WI, b_in + 3 * BI, Osf);
    attn_fused<16, 16, 16><<<16 * 8, 256, 0, stream>>>(root, root, w_in + 5 * WI, b_in + 5 * BI, Ors);
    attn_fused<16, 128, 16><<<16 * 8, 256, 0, stream>>>(root, inner, w_in + 5 * WI, b_in + 5 * BI, Orc);

    // combines
    combine_inner<<<2048 / 32, 256, 0, stream>>>(Op, Osf, Oc, w_out + 2 * WO, b_out + 2 * BO,
                                                 w_out + 3 * WO, b_out + 3 * BO,
                                                 w_out + 4 * WO, b_out + 4 * BO,
                                                 winner, out + 33554432);
    combine_root<<<256 / 32, 256, 0, stream>>>(Ors, Orc, w_out + 5 * WO, b_out + 5 * BO,
                                               wroot, out + 33554432 + 524288);
}

// Round 6
// 1522.923 us; speedup vs baseline: 4.5923x; 1.0015x over previous
//
#include <hip/hip_runtime.h>
#include <hip/hip_bf16.h>
#include <cstdint>

// AttnLayerBU round 6:
//  pre      : leafp + 4 fp32 attn paths, one 2560-block launch (range dispatch)
//  mega2    : block = (leaf tile, head-pair). 8192 x 256thr, 57.6KB LDS ->
//             2 blocks/CU (phase-diverse latency hiding). Leaf A-frags in regs;
//             20-tile unified proj loop (W1 Q/K/V + W4 K/V, 2-deep prefetch);
//             2-head attention -> O1 (global bf16); inner_c slice -> Oc.
//  epilogue : combleaf (out-proj + wl mix) + combine_inner + combine_root.

#define DIM 256
#define NH 8
#define HD 32

static constexpr float SCALE = 0.17677669529663687f; // 32^-0.5

typedef __bf16 bf16x8 __attribute__((ext_vector_type(8)));
typedef __bf16 bf16x4 __attribute__((ext_vector_type(4)));
typedef float  f32x4  __attribute__((ext_vector_type(4)));

__device__ __forceinline__ float dot4(const float4 a, const float4 b) {
    return a.x * b.x + a.y * b.y + a.z * b.z + a.w * b.w;
}

// ---------------------------------------------------------------------------
__global__ __launch_bounds__(256) void cvt_f2b(const float* __restrict__ s,
                                               __bf16* __restrict__ d, int n) {
    int i = (blockIdx.x * 256 + threadIdx.x) * 4;
    if (i < n) {
        float4 v = *(const float4*)(s + i);
        d[i + 0] = (__bf16)v.x; d[i + 1] = (__bf16)v.y;
        d[i + 2] = (__bf16)v.z; d[i + 3] = (__bf16)v.w;
    }
}

// ---------------------------------------------------------------------------
// mega2
// LDS (57600 B): Qs[64][72]@0  Ks@9216  Vt@18432  K4t@27648  V4t@36864
//                Pw 4x[16][72]@46080  scratch(f32 qpart[4][64],qv[64],
//                psm[128],opart[128])@55296
// ---------------------------------------------------------------------------
__global__ __launch_bounds__(256, 2) void mega2(
    const float* __restrict__ X,       // leaf (131072, 256)
    const float* __restrict__ inner,   // (2048, 256)
    const __bf16* __restrict__ W1b,    // set1 W (768,256) bf16
    const float* __restrict__ Bi1,     // set1 b (768)
    const __bf16* __restrict__ W4kvb,  // set4 W rows 256..767 bf16 (512,256)
    const float* __restrict__ W4q,     // set4 W fp32 (rows 0..255 used)
    const float* __restrict__ Bi4,     // set4 b (768)
    __bf16* __restrict__ O1,           // leaf_s attn out (131072,256) bf16
    float* __restrict__ Oc)            // inner_c attn out (2048,256) fp32
{
    __shared__ __align__(16) char smem[57600];
    const int g    = blockIdx.x;
    const int xcd  = g & 7;
    const int idx  = g >> 3;               // 0..1023
    const int b    = xcd * 256 + (idx >> 2);
    const int hg   = idx & 3;              // head-pair: heads 2hg, 2hg+1
    const int tid  = threadIdx.x;
    const int wid  = tid >> 6;             // 0..3
    const int lane = tid & 63;
    const int lr   = lane & 15;
    const int lk   = (lane >> 4) * 8;
    const int prow = (lane >> 4) * 4;
    const int tok0 = wid * 16 + prow;

    __bf16* Qs  = (__bf16*)smem;                    // [64][72]
    __bf16* Ks  = (__bf16*)(smem + 9216);
    __bf16* Vt  = (__bf16*)(smem + 18432);          // [64 d][72 tok]
    __bf16* K4t = (__bf16*)(smem + 27648);
    __bf16* V4t = (__bf16*)(smem + 36864);
    __bf16* Pw  = (__bf16*)(smem + 46080 + wid * 2304);  // wave-local [16][72]
    float* qpart = (float*)(smem + 55296);          // [4][64]
    float* qv    = qpart + 256;                     // [64]
    float* psm   = qv + 64;                         // [2][64]
    float* opart = psm + 128;                       // [2][64]

    // ---- A-fragments: wave wid owns leaf rows wid*16+lr ----
    bf16x8 a[8];
    {
        const float* xrow = X + ((size_t)b * 64 + wid * 16 + lr) * DIM + lk;
#pragma unroll
        for (int k = 0; k < 8; ++k) {
            float4 v0 = *(const float4*)(xrow + k * 32);
            float4 v1 = *(const float4*)(xrow + k * 32 + 4);
            bf16x8 t;
            t[0] = (__bf16)v0.x; t[1] = (__bf16)v0.y; t[2] = (__bf16)v0.z; t[3] = (__bf16)v0.w;
            t[4] = (__bf16)v1.x; t[5] = (__bf16)v1.y; t[6] = (__bf16)v1.z; t[7] = (__bf16)v1.w;
            a[k] = t;
        }
    }

    // ---- unified projection loop: 20 n-tiles, 2-deep prefetch ----
    // t 0-3: Q  4-7: K  8-11: V  (W1b rows sec*256 + hg*64 + sub*16)
    // t 12-15: K4  16-19: V4     (W4kvb rows sec*256 + hg*64 + sub*16)
    {
        auto wp = [&](int t) -> const __bf16* {
            if (t < 12) {
                const int sec = t >> 2, sub = t & 3;
                return W1b + (size_t)(sec * 256 + hg * 64 + sub * 16 + lr) * DIM + lk;
            }
            const int u = t - 12, sec = u >> 2, sub = u & 3;
            return W4kvb + (size_t)(sec * 256 + hg * 64 + sub * 16 + lr) * DIM + lk;
        };
        bf16x8 w0[8], w1[8], w2[8];
        {
            const __bf16* p = wp(0);
#pragma unroll
            for (int k = 0; k < 8; ++k) w0[k] = *(const bf16x8*)(p + k * 32);
        }
        {
            const __bf16* p = wp(1);
#pragma unroll
            for (int k = 0; k < 8; ++k) w1[k] = *(const bf16x8*)(p + k * 32);
        }
#pragma unroll 2
        for (int t = 0; t < 20; ++t) {
            if (t + 2 < 20) {
                const __bf16* p = wp(t + 2);
#pragma unroll
                for (int k = 0; k < 8; ++k) w2[k] = *(const bf16x8*)(p + k * 32);
            }
            f32x4 aL = {0.f, 0.f, 0.f, 0.f}, aH = {0.f, 0.f, 0.f, 0.f};
#pragma unroll
            for (int k = 0; k < 4; ++k) {
                aL = __builtin_amdgcn_mfma_f32_16x16x32_bf16(a[k],     w0[k],     aL, 0, 0, 0);
                aH = __builtin_amdgcn_mfma_f32_16x16x32_bf16(a[k + 4], w0[k + 4], aH, 0, 0, 0);
            }
            const f32x4 acc = aL + aH;
            const int sub = t & 3;
            const int col = sub * 16 + lr;          // block-local col 0..63
            if (t < 4) {                            // Q (scaled)
                const float bias = Bi1[hg * 64 + sub * 16 + lr];
#pragma unroll
                for (int r = 0; r < 4; ++r)
                    Qs[(size_t)(tok0 + r) * 72 + col] = (__bf16)((acc[r] + bias) * SCALE);
            } else if (t < 8) {                     // K
                const float bias = Bi1[256 + hg * 64 + sub * 16 + lr];
#pragma unroll
                for (int r = 0; r < 4; ++r)
                    Ks[(size_t)(tok0 + r) * 72 + col] = (__bf16)(acc[r] + bias);
            } else {
                bf16x4 pv;
                if (t < 12) {                       // V -> [d][tok]
                    const float bias = Bi1[512 + hg * 64 + sub * 16 + lr];
#pragma unroll
                    for (int r = 0; r < 4; ++r) pv[r] = (__bf16)(acc[r] + bias);
                    *(bf16x4*)(Vt + (size_t)col * 72 + tok0) = pv;
                } else if (t < 16) {                // K4 -> [d][tok]
                    const float bias = Bi4[256 + hg * 64 + sub * 16 + lr];
#pragma unroll
                    for (int r = 0; r < 4; ++r) pv[r] = (__bf16)(acc[r] + bias);
                    *(bf16x4*)(K4t + (size_t)col * 72 + tok0) = pv;
                } else {                            // V4 -> [d][tok]
                    const float bias = Bi4[512 + hg * 64 + sub * 16 + lr];
#pragma unroll
                    for (int r = 0; r < 4; ++r) pv[r] = (__bf16)(acc[r] + bias);
                    *(bf16x4*)(V4t + (size_t)col * 72 + tok0) = pv;
                }
            }
#pragma unroll
            for (int k = 0; k < 8; ++k) { w0[k] = w1[k]; w1[k] = w2[k]; }
        }
    }

    // ---- inner_c q-projection partials (fp32 VALU, pre-barrier) ----
    {
        const int o = tid & 63, part = tid >> 6;    // 4 partials x 64 outputs
        const float4* wr = (const float4*)(W4q + (size_t)(hg * 64 + o) * DIM + part * 64);
        const float4* xr = (const float4*)(inner + (size_t)b * DIM + part * 64);
        float accq = 0.f;
#pragma unroll
        for (int k = 0; k < 16; ++k) accq += dot4(xr[k], wr[k]);
        qpart[part * 64 + o] = accq;
    }
    __syncthreads();                                 // b1: all LDS tiles + qpart

    // ---- qv reduce (wave 0) ----
    if (tid < 64)
        qv[tid] = (qpart[tid] + qpart[64 + tid] + qpart[128 + tid] + qpart[192 + tid]
                   + Bi4[hg * 64 + tid]) * SCALE;

    // ---- leaf_s attention: wave = (head hh, q-half qh) ----
    const int hh = wid >> 1;                         // 0/1 within head-pair
    const int qh = wid & 1;
    f32x4 s[2][4];
    {
        bf16x8 kb[4];
#pragma unroll
        for (int kt = 0; kt < 4; ++kt)
            kb[kt] = *(const bf16x8*)(Ks + (size_t)(kt * 16 + lr) * 72 + hh * 32 + lk);
#pragma unroll
        for (int q2 = 0; q2 < 2; ++q2) {
            const int qt = qh * 2 + q2;
            const bf16x8 qa = *(const bf16x8*)(Qs + (size_t)(qt * 16 + lr) * 72 + hh * 32 + lk);
#pragma unroll
            for (int kt = 0; kt < 4; ++kt) {
                f32x4 z = {0.f, 0.f, 0.f, 0.f};
                s[q2][kt] = __builtin_amdgcn_mfma_f32_16x16x32_bf16(qa, kb[kt], z, 0, 0, 0);
            }
        }
    }
    // softmax (16-lane groups own q-rows)
#pragma unroll
    for (int q2 = 0; q2 < 2; ++q2) {
#pragma unroll
        for (int r = 0; r < 4; ++r) {
            float m = fmaxf(fmaxf(s[q2][0][r], s[q2][1][r]), fmaxf(s[q2][2][r], s[q2][3][r]));
#pragma unroll
            for (int off = 1; off < 16; off <<= 1) m = fmaxf(m, __shfl_xor(m, off));
            const float p0 = __expf(s[q2][0][r] - m), p1 = __expf(s[q2][1][r] - m);
            const float p2 = __expf(s[q2][2][r] - m), p3 = __expf(s[q2][3][r] - m);
            float t = p0 + p1 + p2 + p3;
#pragma unroll
            for (int off = 1; off < 16; off <<= 1) t += __shfl_xor(t, off);
            const float inv = 1.0f / t;
            s[q2][0][r] = p0 * inv; s[q2][1][r] = p1 * inv;
            s[q2][2][r] = p2 * inv; s[q2][3][r] = p3 * inv;
        }
    }
    // PV via wave-local P staging; O -> global
    {
        bf16x8 vb[2][2];
#pragma unroll
        for (int dt = 0; dt < 2; ++dt)
#pragma unroll
            for (int ks = 0; ks < 2; ++ks)
                vb[dt][ks] = *(const bf16x8*)(Vt + (size_t)(hh * 32 + dt * 16 + lr) * 72 + ks * 32 + lk);
#pragma unroll
        for (int q2 = 0; q2 < 2; ++q2) {
            const int qt = qh * 2 + q2;
#pragma unroll
            for (int kt = 0; kt < 4; ++kt)
#pragma unroll
                for (int r = 0; r < 4; ++r)
                    Pw[(size_t)(prow + r) * 72 + kt * 16 + lr] = (__bf16)s[q2][kt][r];
            bf16x8 pa[2];
#pragma unroll
            for (int ks = 0; ks < 2; ++ks)
                pa[ks] = *(const bf16x8*)(Pw + (size_t)lr * 72 + ks * 32 + lk);
#pragma unroll
            for (int dt = 0; dt < 2; ++dt) {
                f32x4 o = {0.f, 0.f, 0.f, 0.f};
#pragma unroll
                for (int ks = 0; ks < 2; ++ks)
                    o = __builtin_amdgcn_mfma_f32_16x16x32_bf16(pa[ks], vb[dt][ks], o, 0, 0, 0);
                const int colO = (hg * 2 + hh) * 32 + dt * 16 + lr;
#pragma unroll
                for (int r = 0; r < 4; ++r)
                    O1[((size_t)b * 64 + qt * 16 + prow + r) * DIM + colO] = (__bf16)o[r];
            }
        }
    }
    __syncthreads();                                 // b2: qv ready, PV done

    // ---- inner_c scores + softmax: waves 0,1 = heads 0,1 ----
    if (wid < 2) {
        const int j = lane;
        float sv = 0.f;
#pragma unroll
        for (int d = 0; d < 32; ++d)
            sv += qv[wid * 32 + d] * (float)K4t[(size_t)(wid * 32 + d) * 72 + j];
        float m = sv;
#pragma unroll
        for (int off = 1; off < 64; off <<= 1) m = fmaxf(m, __shfl_xor(m, off));
        const float p = __expf(sv - m);
        float t = p;
#pragma unroll
        for (int off = 1; off < 64; off <<= 1) t += __shfl_xor(t, off);
        psm[wid * 64 + j] = p / t;
    }
    __syncthreads();                                 // b3: psm ready

    // ---- inner_c PV (128 threads) ----
    if (tid < 128) {
        const int o = tid & 63, hf = tid >> 6;
        const int ho = o >> 5;
        float acc2 = 0.f;
#pragma unroll
        for (int j = 0; j < 32; ++j)
            acc2 += psm[ho * 64 + hf * 32 + j] * (float)V4t[(size_t)o * 72 + hf * 32 + j];
        opart[hf * 64 + o] = acc2;
    }
    __syncthreads();                                 // b4
    if (tid < 64)
        Oc[(size_t)b * DIM + hg * 64 + tid] = opart[tid] + opart[64 + tid];
}

// ---------------------------------------------------------------------------
// pre kernel bodies
// ---------------------------------------------------------------------------
__device__ void leafp_body(int i, const float* __restrict__ inner,
                           const float* __restrict__ Wi, const float* __restrict__ Bi,
                           const float* __restrict__ Wo, const float* __restrict__ Bo,
                           float* __restrict__ tP)
{
    const int tid = threadIdx.x;
    __shared__ float xv[DIM];
    __shared__ float vv[DIM];
    xv[tid] = inner[(size_t)i * DIM + tid];
    __syncthreads();
    {
        const int row = 2 * DIM + tid;
        const float4* wr = (const float4*)(Wi + (size_t)row * DIM);
        const float4* xr = (const float4*)xv;
        float acc = Bi[row];
        for (int k = 0; k < DIM / 4; ++k) acc += dot4(xr[k], wr[k]);
        vv[tid] = acc;
    }
    __syncthreads();
    {
        const float4* wr = (const float4*)(Wo + (size_t)tid * DIM);
        const float4* vr = (const float4*)vv;
        float acc = Bo[tid];
        for (int k = 0; k < DIM / 4; ++k) acc += dot4(vr[k], wr[k]);
        tP[(size_t)i * DIM + tid] = acc;
    }
}

template <int LQ, int LK, int RQ>
__device__ void attn_body(int bx, const float* __restrict__ Xq,
                          const float* __restrict__ Xkv,
                          const float* __restrict__ Wi, const float* __restrict__ Bi,
                          float* __restrict__ O, float* __restrict__ sm)
{
    const int b   = bx >> 3;
    const int h   = bx & 7;
    const int tid = threadIdx.x;

    float* KsP = sm;                    // [LK][33]
    float* VsP = KsP + LK * 33;         // [LK][33]
    float* QsP = VsP + LK * 33;         // [LQ][33]
    float* SP  = QsP + LQ * 33;         // [RQ][LK+1]

    const float* xq  = Xq  + (size_t)b * LQ * DIM;
    const float* xkv = Xkv + (size_t)b * LK * DIM;

    {
        const int col   = tid & 63;
        const int which = col >> 5;
        const int d     = col & 31;
        const int row   = DIM + which * DIM + h * HD + d;
        const float4* wr = (const float4*)(Wi + (size_t)row * DIM);
        const float bias = Bi[row];
        constexpr int TT = LK / 4;
        float acc[TT];
#pragma unroll
        for (int i = 0; i < TT; ++i) acc[i] = 0.f;
        const int t0 = tid >> 6;
        for (int k4 = 0; k4 < DIM / 4; ++k4) {
            const float4 w = wr[k4];
#pragma unroll
            for (int i = 0; i < TT; ++i) {
                const int t = t0 + 4 * i;
                const float4 aa = ((const float4*)(xkv + (size_t)t * DIM))[k4];
                acc[i] += dot4(aa, w);
            }
        }
#pragma unroll
        for (int i = 0; i < TT; ++i) {
            const int t = t0 + 4 * i;
            if (which == 0) KsP[t * 33 + d] = acc[i] + bias;
            else            VsP[t * 33 + d] = acc[i] + bias;
        }
    }
    {
        constexpr int TGQ = (LQ >= 8) ? 8 : LQ;
        constexpr int TT  = LQ / TGQ;
        if (tid < 32 * TGQ) {
            const int d   = tid & 31;
            const int row = h * HD + d;
            const float4* wr = (const float4*)(Wi + (size_t)row * DIM);
            const float bias = Bi[row];
            float acc[TT];
#pragma unroll
            for (int i = 0; i < TT; ++i) acc[i] = 0.f;
            const int t0 = tid >> 5;
            for (int k4 = 0; k4 < DIM / 4; ++k4) {
                const float4 w = wr[k4];
#pragma unroll
                for (int i = 0; i < TT; ++i) {
                    const int t = t0 + TGQ * i;
                    const float4 aa = ((const float4*)(xq + (size_t)t * DIM))[k4];
                    acc[i] += dot4(aa, w);
                }
            }
#pragma unroll
            for (int i = 0; i < TT; ++i) {
                const int t = t0 + TGQ * i;
                QsP[t * 33 + d] = (acc[i] + bias) * SCALE;
            }
        }
    }
    __syncthreads();

    for (int q0 = 0; q0 < LQ; q0 += RQ) {
        for (int idx = tid; idx < RQ * LK; idx += 256) {
            const int r = idx / LK;
            const int j = idx - r * LK;
            float acc = 0.f;
#pragma unroll
            for (int d = 0; d < HD; ++d)
                acc += QsP[(q0 + r) * 33 + d] * KsP[j * 33 + d];
            SP[r * (LK + 1) + j] = acc;
        }
        __syncthreads();
        if (tid < RQ * 8) {
            const int r   = tid >> 3;
            const int sub = tid & 7;
            float m = -1e30f;
            for (int j = sub; j < LK; j += 8) m = fmaxf(m, SP[r * (LK + 1) + j]);
#pragma unroll
            for (int off = 4; off; off >>= 1) m = fmaxf(m, __shfl_xor(m, off, 8));
            float sum = 0.f;
            for (int j = sub; j < LK; j += 8) {
                const float p = __expf(SP[r * (LK + 1) + j] - m);
                SP[r * (LK + 1) + j] = p;
                sum += p;
            }
#pragma unroll
            for (int off = 4; off; off >>= 1) sum += __shfl_xor(sum, off, 8);
            const float inv = 1.0f / sum;
            for (int j = sub; j < LK; j += 8) SP[r * (LK + 1) + j] *= inv;
        }
        __syncthreads();
        for (int idx = tid; idx < RQ * HD; idx += 256) {
            const int r = idx >> 5;
            const int d = idx & 31;
            float acc = 0.f;
            for (int j = 0; j < LK; ++j)
                acc += SP[r * (LK + 1) + j] * VsP[j * 33 + d];
            O[((size_t)(b * LQ + q0 + r)) * DIM + h * HD + d] = acc;
        }
        __syncthreads();
    }
}

__global__ __launch_bounds__(256) void pre_kernel(
    const float* __restrict__ inner, const float* __restrict__ root,
    const float* __restrict__ w_in, const float* __restrict__ b_in,
    const float* __restrict__ w_out, const float* __restrict__ b_out,
    float* __restrict__ tP, float* __restrict__ Op, float* __restrict__ Osf,
    float* __restrict__ Ors, float* __restrict__ Orc)
{
    extern __shared__ float smf[];
    const int bid = blockIdx.x;
    const size_t WI = 768 * 256, BI = 768;
    if (bid < 2048)
        leafp_body(bid, inner, w_in, b_in, w_out, b_out, tP);
    else if (bid < 2176)
        attn_body<128, 16, 32>(bid - 2048, inner, root, w_in + 2 * WI, b_in + 2 * BI, Op, smf);
    else if (bid < 2304)
        attn_body<128, 128, 16>(bid - 2176, inner, inner, w_in + 3 * WI, b_in + 3 * BI, Osf, smf);
    else if (bid < 2432)
        attn_body<16, 16, 16>(bid - 2304, root, root, w_in + 5 * WI, b_in + 5 * BI, Ors, smf);
    else
        attn_body<16, 128, 16>(bid - 2432, root, inner, w_in + 5 * WI, b_in + 5 * BI, Orc, smf);
}

// ---------------------------------------------------------------------------
// epilogue bodies
// ---------------------------------------------------------------------------
__device__ void combleaf_body(int bid, const __bf16* __restrict__ O1,
                              const __bf16* __restrict__ Wob,
                              const float* __restrict__ Bo1,
                              const float* __restrict__ tP,
                              const float* __restrict__ wleaf,
                              float* __restrict__ out)
{
    const int tid  = threadIdx.x;
    const int wid  = tid >> 6;
    const int lane = tid & 63;
    const int lr   = lane & 15;
    const int lk   = (lane >> 4) * 8;

    bf16x8 a[8];
    {
        const __bf16* ar = O1 + ((size_t)bid * 64 + wid * 16 + lr) * DIM + lk;
#pragma unroll
        for (int k = 0; k < 8; ++k) a[k] = *(const bf16x8*)(ar + k * 32);
    }
    const float e0 = __expf(wleaf[0]), e1 = __expf(wleaf[1]);
    const float wl0 = e0 / (e0 + e1), wl1 = e1 / (e0 + e1);
    const size_t row0 = (size_t)bid * 64 + wid * 16 + (lane >> 4) * 4;

    for (int nt = 0; nt < 16; ++nt) {
        const __bf16* wpr = Wob + (size_t)(nt * 16 + lr) * DIM + lk;
        f32x4 acc = {0.f, 0.f, 0.f, 0.f};
#pragma unroll
        for (int k = 0; k < 8; ++k)
            acc = __builtin_amdgcn_mfma_f32_16x16x32_bf16(
                a[k], *(const bf16x8*)(wpr + k * 32), acc, 0, 0, 0);
        const int   o  = nt * 16 + lr;
        const float bo = Bo1[o];
        const float tv = tP[(size_t)bid * DIM + o];
#pragma unroll
        for (int r = 0; r < 4; ++r)
            out[(row0 + r) * DIM + o] = wl0 * tv + wl1 * (acc[r] + bo);
    }
}

__device__ void combine_inner_body(int vb, const float* __restrict__ Op,
    const float* __restrict__ Osf, const float* __restrict__ Oc,
    const float* __restrict__ W2, const float* __restrict__ B2,
    const float* __restrict__ W3, const float* __restrict__ B3,
    const float* __restrict__ W4, const float* __restrict__ B4,
    const float* __restrict__ winner, float* __restrict__ out, float* __restrict__ Ts)
{
    const int n0 = vb * 32;
    const int o  = threadIdx.x;
    const float e0 = __expf(winner[0]), e1 = __expf(winner[1]), e2 = __expf(winner[2]);
    const float inv = 1.f / (e0 + e1 + e2);
    const float wt0 = e0 * inv, wt1 = e1 * inv, wt2 = e2 * inv;

    float acc[32];
#pragma unroll
    for (int r = 0; r < 32; ++r) acc[r] = 0.f;
    const float biasacc = wt0 * B2[o] + wt1 * B3[o] + wt2 * B4[o];

#pragma unroll
    for (int term = 0; term < 3; ++term) {
        const float* Ob = (term == 0) ? Op : (term == 1) ? Osf : Oc;
        const float* Wb = (term == 0) ? W2 : (term == 1) ? W3 : W4;
        const float wt  = (term == 0) ? wt0 : (term == 1) ? wt1 : wt2;
        __syncthreads();
        for (int idx = threadIdx.x; idx < 32 * DIM; idx += 256)
            Ts[idx] = Ob[(size_t)n0 * DIM + idx];
        __syncthreads();
        const float4* wr = (const float4*)(Wb + (size_t)o * DIM);
        for (int k4 = 0; k4 < DIM / 4; ++k4) {
            float4 w = wr[k4];
            w.x *= wt; w.y *= wt; w.z *= wt; w.w *= wt;
#pragma unroll
            for (int r = 0; r < 32; ++r) {
                const float4 aa = *(const float4*)&Ts[r * DIM + k4 * 4];
                acc[r] += dot4(aa, w);
            }
        }
    }
#pragma unroll
    for (int r = 0; r < 32; ++r)
        out[(size_t)(n0 + r) * DIM + o] = acc[r] + biasacc;
}

__device__ void combine_root_body(int vb, const float* __restrict__ Ors,
    const float* __restrict__ Orc, const float* __restrict__ W5,
    const float* __restrict__ B5, const float* __restrict__ wroot,
    float* __restrict__ out, float* __restrict__ Ts)
{
    const int n0 = vb * 32;
    const int o  = threadIdx.x;
    const float e0 = __expf(wroot[0]), e1 = __expf(wroot[1]);
    const float w0 = e0 / (e0 + e1), w1 = e1 / (e0 + e1);
    for (int idx = threadIdx.x; idx < 32 * DIM; idx += 256)
        Ts[idx] = w0 * Ors[(size_t)n0 * DIM + idx] + w1 * Orc[(size_t)n0 * DIM + idx];
    __syncthreads();
    float acc[32];
#pragma unroll
    for (int r = 0; r < 32; ++r) acc[r] = 0.f;
    const float4* wr = (const float4*)(W5 + (size_t)o * DIM);
    for (int k4 = 0; k4 < DIM / 4; ++k4) {
        const float4 w = wr[k4];
#pragma unroll
        for (int r = 0; r < 32; ++r) {
            const float4 aa = *(const float4*)&Ts[r * DIM + k4 * 4];
            acc[r] += dot4(aa, w);
        }
    }
    const float bo = B5[o];
#pragma unroll
    for (int r = 0; r < 32; ++r)
        out[(size_t)(n0 + r) * DIM + o] = acc[r] + bo;
}

__global__ __launch_bounds__(256) void epilogue_kernel(
    const __bf16* __restrict__ O1, const __bf16* __restrict__ Wo1b,
    const float* __restrict__ w_out, const float* __restrict__ b_out,
    const float* __restrict__ tP, const float* __restrict__ Op,
    const float* __restrict__ Osf, const float* __restrict__ Oc,
    const float* __restrict__ Ors, const float* __restrict__ Orc,
    const float* __restrict__ wleaf, const float* __restrict__ winner,
    const float* __restrict__ wroot, float* __restrict__ out)
{
    extern __shared__ float smf[];
    const int bid = blockIdx.x;
    const size_t WO = 256 * 256, BO = 256;
    if (bid < 2048)
        combleaf_body(bid, O1, Wo1b, b_out + BO, tP, wleaf, out);
    else if (bid < 2112)
        combine_inner_body(bid - 2048, Op, Osf, Oc,
                           w_out + 2 * WO, b_out + 2 * BO,
                           w_out + 3 * WO, b_out + 3 * BO,
                           w_out + 4 * WO, b_out + 4 * BO,
                           winner, out + 33554432, smf);
    else
        combine_root_body(bid - 2112, Ors, Orc, w_out + 5 * WO, b_out + 5 * BO,
                          wroot, out + 33554432 + 524288, smf);
}

// ---------------------------------------------------------------------------
extern "C" void kernel_launch(void* const* d_in, const int* in_sizes, int n_in,
                              void* d_out, int out_size, void* d_ws, size_t ws_size,
                              hipStream_t stream)
{
    const float* leaf   = (const float*)d_in[0];
    const float* inner  = (const float*)d_in[1];
    const float* root   = (const float*)d_in[2];
    const float* w_in   = (const float*)d_in[3];
    const float* b_in   = (const float*)d_in[4];
    const float* w_out  = (const float*)d_in[5];
    const float* b_out  = (const float*)d_in[6];
    const float* wleaf  = (const float*)d_in[7];
    const float* winner = (const float*)d_in[8];
    const float* wroot  = (const float*)d_in[9];
    float* out = (float*)d_out;

    const size_t WI = 768 * 256, BI = 768, WO = 256 * 256;

    // ws layout
    char* ws = (char*)d_ws;
    __bf16* W1b   = (__bf16*)(ws);                    // 393216 B
    __bf16* W4kvb = (__bf16*)(ws + 393216);           // 262144 B
    __bf16* Wo1b  = (__bf16*)(ws + 655360);           // 131072 B
    __bf16* O1b   = (__bf16*)(ws + 786432);           // 67108864 B
    float*  tP    = (float*)(ws + 67895296);          // 2097152 B
    float*  Oc    = (float*)(ws + 69992448);
    float*  Op    = (float*)(ws + 72089600);
    float*  Osf   = (float*)(ws + 74186752);
    float*  Ors   = (float*)(ws + 76283904);
    float*  Orc   = (float*)(ws + 76546048);

    cvt_f2b<<<192, 256, 0, stream>>>(w_in + 1 * WI, W1b, 768 * 256);
    cvt_f2b<<<128, 256, 0, stream>>>(w_in + 4 * WI + 256 * 256, W4kvb, 512 * 256);
    cvt_f2b<<<64, 256, 0, stream>>>(w_out + 1 * WO, Wo1b, 256 * 256);

    // pre: leafp + 4 small fp32 attention paths (one launch)
    pre_kernel<<<2560, 256, 58944, stream>>>(inner, root, w_in, b_in, w_out, b_out,
                                             tP, Op, Osf, Ors, Orc);

    // mega2: leaf QKV/K4V4 proj + leaf_s attention + inner_c
    mega2<<<8192, 256, 0, stream>>>(leaf, inner, W1b, b_in + 1 * BI, W4kvb,
                                    w_in + 4 * WI, b_in + 4 * BI, O1b, Oc);

    // epilogue: combleaf + combine_inner + combine_root (one launch)
    epilogue_kernel<<<2120, 256, 32768, stream>>>(O1b, Wo1b, w_out, b_out, tP,
                                                  Op, Osf, Oc, Ors, Orc,
                                                  wleaf, winner, wroot, out);
}

// Round 7
// 1007.071 us; speedup vs baseline: 6.9446x; 1.5122x over previous
//
#include <hip/hip_runtime.h>
#include <hip/hip_bf16.h>
#include <cstdint>

// AttnLayerBU round 7: mega2 with LDS-staged weight tiles (double-buffered,
// cooperative coalesced loads, one barrier/tile) replacing per-wave global
// B-operand loads (which spilled + serialized at L2 latency). combleaf gets
// the same staging. All math / index mappings verbatim from the passing r6.

#define DIM 256
#define NH 8
#define HD 32

static constexpr float SCALE = 0.17677669529663687f; // 32^-0.5

typedef __bf16 bf16x8 __attribute__((ext_vector_type(8)));
typedef __bf16 bf16x4 __attribute__((ext_vector_type(4)));
typedef float  f32x4  __attribute__((ext_vector_type(4)));

__device__ __forceinline__ float dot4(const float4 a, const float4 b) {
    return a.x * b.x + a.y * b.y + a.z * b.z + a.w * b.w;
}

// ---------------------------------------------------------------------------
__global__ __launch_bounds__(256) void cvt_f2b(const float* __restrict__ s,
                                               __bf16* __restrict__ d, int n) {
    int i = (blockIdx.x * 256 + threadIdx.x) * 4;
    if (i < n) {
        float4 v = *(const float4*)(s + i);
        d[i + 0] = (__bf16)v.x; d[i + 1] = (__bf16)v.y;
        d[i + 2] = (__bf16)v.z; d[i + 3] = (__bf16)v.w;
    }
}

// ---------------------------------------------------------------------------
// mega2
// LDS (74496 B): Qs[64][72]@0  Ks@9216  Vt@18432  K4t@27648  V4t@36864
//   Pw 4x[16][72]@46080  scratch@55296(2304)  Bs[2][16][264]@57600(16896)
// ---------------------------------------------------------------------------
__global__ __launch_bounds__(256, 2) void mega2(
    const float* __restrict__ X,       // leaf (131072, 256)
    const float* __restrict__ inner,   // (2048, 256)
    const __bf16* __restrict__ W1b,    // set1 W (768,256) bf16
    const float* __restrict__ Bi1,     // set1 b (768)
    const __bf16* __restrict__ W4kvb,  // set4 W rows 256..767 bf16 (512,256)
    const float* __restrict__ W4q,     // set4 W fp32 (rows 0..255 used)
    const float* __restrict__ Bi4,     // set4 b (768)
    __bf16* __restrict__ O1,           // leaf_s attn out (131072,256) bf16
    float* __restrict__ Oc)            // inner_c attn out (2048,256) fp32
{
    __shared__ __align__(16) char smem[74496];
    const int g    = blockIdx.x;
    const int xcd  = g & 7;
    const int idx  = g >> 3;               // 0..1023
    const int b    = xcd * 256 + (idx >> 2);
    const int hg   = idx & 3;              // head-pair: heads 2hg, 2hg+1
    const int tid  = threadIdx.x;
    const int wid  = tid >> 6;             // 0..3
    const int lane = tid & 63;
    const int lr   = lane & 15;
    const int lk   = (lane >> 4) * 8;
    const int prow = (lane >> 4) * 4;
    const int tok0 = wid * 16 + prow;

    __bf16* Qs  = (__bf16*)smem;                    // [64][72]
    __bf16* Ks  = (__bf16*)(smem + 9216);
    __bf16* Vt  = (__bf16*)(smem + 18432);          // [64 d][72 tok]
    __bf16* K4t = (__bf16*)(smem + 27648);
    __bf16* V4t = (__bf16*)(smem + 36864);
    __bf16* Pw  = (__bf16*)(smem + 46080 + wid * 2304);  // wave-local [16][72]
    float* qpart = (float*)(smem + 55296);          // [4][64]
    float* qv    = qpart + 256;                     // [64]
    float* psm   = qv + 64;                         // [2][64]
    float* opart = psm + 128;                       // [2][64]
    __bf16* Bs  = (__bf16*)(smem + 57600);          // [2][16][264]

    // ---- A-fragments: wave wid owns leaf rows wid*16+lr ----
    bf16x8 a[8];
    {
        const float* xrow = X + ((size_t)b * 64 + wid * 16 + lr) * DIM + lk;
#pragma unroll
        for (int k = 0; k < 8; ++k) {
            float4 v0 = *(const float4*)(xrow + k * 32);
            float4 v1 = *(const float4*)(xrow + k * 32 + 4);
            bf16x8 t;
            t[0] = (__bf16)v0.x; t[1] = (__bf16)v0.y; t[2] = (__bf16)v0.z; t[3] = (__bf16)v0.w;
            t[4] = (__bf16)v1.x; t[5] = (__bf16)v1.y; t[6] = (__bf16)v1.z; t[7] = (__bf16)v1.w;
            a[k] = t;
        }
    }

    // ---- unified projection loop: 20 n-tiles, LDS double-buffered B ----
    // t 0-3: Q  4-7: K  8-11: V   (W1b  rows sec*256 + hg*64 + sub*16 ..+15)
    // t 12-15: K4  16-19: V4      (W4kvb rows sec*256 + hg*64 + sub*16 ..+15)
    {
        const int srow = tid >> 5;              // 0..7
        const int scol = (tid & 31) * 8;        // bf16 elems
        auto wsrc = [&](int t) -> const __bf16* {
            if (t < 12) {
                const int sec = t >> 2, sub = t & 3;
                return W1b + (size_t)(sec * 256 + hg * 64 + sub * 16) * DIM;
            }
            const int u = t - 12, sec = u >> 2, sub = u & 3;
            return W4kvb + (size_t)(sec * 256 + hg * 64 + sub * 16) * DIM;
        };
        {   // prologue: stage tile 0 into buf 0
            const __bf16* p = wsrc(0);
            bf16x8 g0 = *(const bf16x8*)(p + (size_t)srow * DIM + scol);
            bf16x8 g1 = *(const bf16x8*)(p + (size_t)(8 + srow) * DIM + scol);
            *(bf16x8*)(Bs + srow * 264 + scol) = g0;
            *(bf16x8*)(Bs + (8 + srow) * 264 + scol) = g1;
        }
        __syncthreads();

        for (int t = 0; t < 20; ++t) {
            const int cur = t & 1;
            const __bf16* Bc = Bs + cur * 4224;
            bf16x8 g0, g1;
            if (t + 1 < 20) {               // issue next-tile loads early
                const __bf16* p = wsrc(t + 1);
                g0 = *(const bf16x8*)(p + (size_t)srow * DIM + scol);
                g1 = *(const bf16x8*)(p + (size_t)(8 + srow) * DIM + scol);
            }
            f32x4 aL = {0.f, 0.f, 0.f, 0.f}, aH = {0.f, 0.f, 0.f, 0.f};
#pragma unroll
            for (int kk = 0; kk < 4; ++kk) {
                const bf16x8 bL = *(const bf16x8*)(Bc + lr * 264 + kk * 32 + lk);
                aL = __builtin_amdgcn_mfma_f32_16x16x32_bf16(a[kk], bL, aL, 0, 0, 0);
            }
#pragma unroll
            for (int kk = 0; kk < 4; ++kk) {
                const bf16x8 bH = *(const bf16x8*)(Bc + lr * 264 + (kk + 4) * 32 + lk);
                aH = __builtin_amdgcn_mfma_f32_16x16x32_bf16(a[kk + 4], bH, aH, 0, 0, 0);
            }
            const f32x4 acc = aL + aH;
            const int sub = t & 3;
            const int col = sub * 16 + lr;          // block-local col 0..63
            if (t < 4) {                            // Q (scaled)
                const float bias = Bi1[hg * 64 + sub * 16 + lr];
#pragma unroll
                for (int r = 0; r < 4; ++r)
                    Qs[(size_t)(tok0 + r) * 72 + col] = (__bf16)((acc[r] + bias) * SCALE);
            } else if (t < 8) {                     // K
                const float bias = Bi1[256 + hg * 64 + sub * 16 + lr];
#pragma unroll
                for (int r = 0; r < 4; ++r)
                    Ks[(size_t)(tok0 + r) * 72 + col] = (__bf16)(acc[r] + bias);
            } else {
                bf16x4 pv;
                if (t < 12) {                       // V -> [d][tok]
                    const float bias = Bi1[512 + hg * 64 + sub * 16 + lr];
#pragma unroll
                    for (int r = 0; r < 4; ++r) pv[r] = (__bf16)(acc[r] + bias);
                    *(bf16x4*)(Vt + (size_t)col * 72 + tok0) = pv;
                } else if (t < 16) {                // K4 -> [d][tok]
                    const float bias = Bi4[256 + hg * 64 + sub * 16 + lr];
#pragma unroll
                    for (int r = 0; r < 4; ++r) pv[r] = (__bf16)(acc[r] + bias);
                    *(bf16x4*)(K4t + (size_t)col * 72 + tok0) = pv;
                } else {                            // V4 -> [d][tok]
                    const float bias = Bi4[512 + hg * 64 + sub * 16 + lr];
#pragma unroll
                    for (int r = 0; r < 4; ++r) pv[r] = (__bf16)(acc[r] + bias);
                    *(bf16x4*)(V4t + (size_t)col * 72 + tok0) = pv;
                }
            }
            if (t + 1 < 20) {                       // write next tile
                __bf16* Bn = Bs + (cur ^ 1) * 4224;
                *(bf16x8*)(Bn + srow * 264 + scol) = g0;
                *(bf16x8*)(Bn + (8 + srow) * 264 + scol) = g1;
            }
            __syncthreads();
        }
    }

    // ---- inner_c q-projection partials (fp32 VALU) ----
    {
        const int o = tid & 63, part = tid >> 6;    // 4 partials x 64 outputs
        const float4* wr = (const float4*)(W4q + (size_t)(hg * 64 + o) * DIM + part * 64);
        const float4* xr = (const float4*)(inner + (size_t)b * DIM + part * 64);
        float accq = 0.f;
#pragma unroll
        for (int k = 0; k < 16; ++k) accq += dot4(xr[k], wr[k]);
        qpart[part * 64 + o] = accq;
    }
    __syncthreads();                                 // b1: all LDS tiles + qpart

    // ---- qv reduce (wave 0) ----
    if (tid < 64)
        qv[tid] = (qpart[tid] + qpart[64 + tid] + qpart[128 + tid] + qpart[192 + tid]
                   + Bi4[hg * 64 + tid]) * SCALE;

    // ---- leaf_s attention: wave = (head hh, q-half qh) ----
    const int hh = wid >> 1;                         // 0/1 within head-pair
    const int qh = wid & 1;
    f32x4 s[2][4];
    {
        bf16x8 kb[4];
#pragma unroll
        for (int kt = 0; kt < 4; ++kt)
            kb[kt] = *(const bf16x8*)(Ks + (size_t)(kt * 16 + lr) * 72 + hh * 32 + lk);
#pragma unroll
        for (int q2 = 0; q2 < 2; ++q2) {
            const int qt = qh * 2 + q2;
            const bf16x8 qa = *(const bf16x8*)(Qs + (size_t)(qt * 16 + lr) * 72 + hh * 32 + lk);
#pragma unroll
            for (int kt = 0; kt < 4; ++kt) {
                f32x4 z = {0.f, 0.f, 0.f, 0.f};
                s[q2][kt] = __builtin_amdgcn_mfma_f32_16x16x32_bf16(qa, kb[kt], z, 0, 0, 0);
            }
        }
    }
    // softmax (16-lane groups own q-rows)
#pragma unroll
    for (int q2 = 0; q2 < 2; ++q2) {
#pragma unroll
        for (int r = 0; r < 4; ++r) {
            float m = fmaxf(fmaxf(s[q2][0][r], s[q2][1][r]), fmaxf(s[q2][2][r], s[q2][3][r]));
#pragma unroll
            for (int off = 1; off < 16; off <<= 1) m = fmaxf(m, __shfl_xor(m, off));
            const float p0 = __expf(s[q2][0][r] - m), p1 = __expf(s[q2][1][r] - m);
            const float p2 = __expf(s[q2][2][r] - m), p3 = __expf(s[q2][3][r] - m);
            float t = p0 + p1 + p2 + p3;
#pragma unroll
            for (int off = 1; off < 16; off <<= 1) t += __shfl_xor(t, off);
            const float inv = 1.0f / t;
            s[q2][0][r] = p0 * inv; s[q2][1][r] = p1 * inv;
            s[q2][2][r] = p2 * inv; s[q2][3][r] = p3 * inv;
        }
    }
    // PV via wave-local P staging; O -> global
    {
        bf16x8 vb[2][2];
#pragma unroll
        for (int dt = 0; dt < 2; ++dt)
#pragma unroll
            for (int ks = 0; ks < 2; ++ks)
                vb[dt][ks] = *(const bf16x8*)(Vt + (size_t)(hh * 32 + dt * 16 + lr) * 72 + ks * 32 + lk);
#pragma unroll
        for (int q2 = 0; q2 < 2; ++q2) {
            const int qt = qh * 2 + q2;
#pragma unroll
            for (int kt = 0; kt < 4; ++kt)
#pragma unroll
                for (int r = 0; r < 4; ++r)
                    Pw[(size_t)(prow + r) * 72 + kt * 16 + lr] = (__bf16)s[q2][kt][r];
            bf16x8 pa[2];
#pragma unroll
            for (int ks = 0; ks < 2; ++ks)
                pa[ks] = *(const bf16x8*)(Pw + (size_t)lr * 72 + ks * 32 + lk);
#pragma unroll
            for (int dt = 0; dt < 2; ++dt) {
                f32x4 o = {0.f, 0.f, 0.f, 0.f};
#pragma unroll
                for (int ks = 0; ks < 2; ++ks)
                    o = __builtin_amdgcn_mfma_f32_16x16x32_bf16(pa[ks], vb[dt][ks], o, 0, 0, 0);
                const int colO = (hg * 2 + hh) * 32 + dt * 16 + lr;
#pragma unroll
                for (int r = 0; r < 4; ++r)
                    O1[((size_t)b * 64 + qt * 16 + prow + r) * DIM + colO] = (__bf16)o[r];
            }
        }
    }
    __syncthreads();                                 // b2: qv ready, PV done

    // ---- inner_c scores + softmax: waves 0,1 = heads 0,1 ----
    if (wid < 2) {
        const int j = lane;
        float sv = 0.f;
#pragma unroll
        for (int d = 0; d < 32; ++d)
            sv += qv[wid * 32 + d] * (float)K4t[(size_t)(wid * 32 + d) * 72 + j];
        float m = sv;
#pragma unroll
        for (int off = 1; off < 64; off <<= 1) m = fmaxf(m, __shfl_xor(m, off));
        const float p = __expf(sv - m);
        float t = p;
#pragma unroll
        for (int off = 1; off < 64; off <<= 1) t += __shfl_xor(t, off);
        psm[wid * 64 + j] = p / t;
    }
    __syncthreads();                                 // b3: psm ready

    // ---- inner_c PV (128 threads) ----
    if (tid < 128) {
        const int o = tid & 63, hf = tid >> 6;
        const int ho = o >> 5;
        float acc2 = 0.f;
#pragma unroll
        for (int j = 0; j < 32; ++j)
            acc2 += psm[ho * 64 + hf * 32 + j] * (float)V4t[(size_t)o * 72 + hf * 32 + j];
        opart[hf * 64 + o] = acc2;
    }
    __syncthreads();                                 // b4
    if (tid < 64)
        Oc[(size_t)b * DIM + hg * 64 + tid] = opart[tid] + opart[64 + tid];
}

// ---------------------------------------------------------------------------
// pre kernel bodies (r6 verbatim)
// ---------------------------------------------------------------------------
__device__ void leafp_body(int i, const float* __restrict__ inner,
                           const float* __restrict__ Wi, const float* __restrict__ Bi,
                           const float* __restrict__ Wo, const float* __restrict__ Bo,
                           float* __restrict__ tP)
{
    const int tid = threadIdx.x;
    __shared__ float xv[DIM];
    __shared__ float vv[DIM];
    xv[tid] = inner[(size_t)i * DIM + tid];
    __syncthreads();
    {
        const int row = 2 * DIM + tid;
        const float4* wr = (const float4*)(Wi + (size_t)row * DIM);
        const float4* xr = (const float4*)xv;
        float acc = Bi[row];
        for (int k = 0; k < DIM / 4; ++k) acc += dot4(xr[k], wr[k]);
        vv[tid] = acc;
    }
    __syncthreads();
    {
        const float4* wr = (const float4*)(Wo + (size_t)tid * DIM);
        const float4* vr = (const float4*)vv;
        float acc = Bo[tid];
        for (int k = 0; k < DIM / 4; ++k) acc += dot4(vr[k], wr[k]);
        tP[(size_t)i * DIM + tid] = acc;
    }
}

template <int LQ, int LK, int RQ>
__device__ void attn_body(int bx, const float* __restrict__ Xq,
                          const float* __restrict__ Xkv,
                          const float* __restrict__ Wi, const float* __restrict__ Bi,
                          float* __restrict__ O, float* __restrict__ sm)
{
    const int b   = bx >> 3;
    const int h   = bx & 7;
    const int tid = threadIdx.x;

    float* KsP = sm;                    // [LK][33]
    float* VsP = KsP + LK * 33;         // [LK][33]
    float* QsP = VsP + LK * 33;         // [LQ][33]
    float* SP  = QsP + LQ * 33;         // [RQ][LK+1]

    const float* xq  = Xq  + (size_t)b * LQ * DIM;
    const float* xkv = Xkv + (size_t)b * LK * DIM;

    {
        const int col   = tid & 63;
        const int which = col >> 5;
        const int d     = col & 31;
        const int row   = DIM + which * DIM + h * HD + d;
        const float4* wr = (const float4*)(Wi + (size_t)row * DIM);
        const float bias = Bi[row];
        constexpr int TT = LK / 4;
        float acc[TT];
#pragma unroll
        for (int i = 0; i < TT; ++i) acc[i] = 0.f;
        const int t0 = tid >> 6;
        for (int k4 = 0; k4 < DIM / 4; ++k4) {
            const float4 w = wr[k4];
#pragma unroll
            for (int i = 0; i < TT; ++i) {
                const int t = t0 + 4 * i;
                const float4 aa = ((const float4*)(xkv + (size_t)t * DIM))[k4];
                acc[i] += dot4(aa, w);
            }
        }
#pragma unroll
        for (int i = 0; i < TT; ++i) {
            const int t = t0 + 4 * i;
            if (which == 0) KsP[t * 33 + d] = acc[i] + bias;
            else            VsP[t * 33 + d] = acc[i] + bias;
        }
    }
    {
        constexpr int TGQ = (LQ >= 8) ? 8 : LQ;
        constexpr int TT  = LQ / TGQ;
        if (tid < 32 * TGQ) {
            const int d   = tid & 31;
            const int row = h * HD + d;
            const float4* wr = (const float4*)(Wi + (size_t)row * DIM);
            const float bias = Bi[row];
            float acc[TT];
#pragma unroll
            for (int i = 0; i < TT; ++i) acc[i] = 0.f;
            const int t0 = tid >> 5;
            for (int k4 = 0; k4 < DIM / 4; ++k4) {
                const float4 w = wr[k4];
#pragma unroll
                for (int i = 0; i < TT; ++i) {
                    const int t = t0 + TGQ * i;
                    const float4 aa = ((const float4*)(xq + (size_t)t * DIM))[k4];
                    acc[i] += dot4(aa, w);
                }
            }
#pragma unroll
            for (int i = 0; i < TT; ++i) {
                const int t = t0 + TGQ * i;
                QsP[t * 33 + d] = (acc[i] + bias) * SCALE;
            }
        }
    }
    __syncthreads();

    for (int q0 = 0; q0 < LQ; q0 += RQ) {
        for (int idx = tid; idx < RQ * LK; idx += 256) {
            const int r = idx / LK;
            const int j = idx - r * LK;
            float acc = 0.f;
#pragma unroll
            for (int d = 0; d < HD; ++d)
                acc += QsP[(q0 + r) * 33 + d] * KsP[j * 33 + d];
            SP[r * (LK + 1) + j] = acc;
        }
        __syncthreads();
        if (tid < RQ * 8) {
            const int r   = tid >> 3;
            const int sub = tid & 7;
            float m = -1e30f;
            for (int j = sub; j < LK; j += 8) m = fmaxf(m, SP[r * (LK + 1) + j]);
#pragma unroll
            for (int off = 4; off; off >>= 1) m = fmaxf(m, __shfl_xor(m, off, 8));
            float sum = 0.f;
            for (int j = sub; j < LK; j += 8) {
                const float p = __expf(SP[r * (LK + 1) + j] - m);
                SP[r * (LK + 1) + j] = p;
                sum += p;
            }
#pragma unroll
            for (int off = 4; off; off >>= 1) sum += __shfl_xor(sum, off, 8);
            const float inv = 1.0f / sum;
            for (int j = sub; j < LK; j += 8) SP[r * (LK + 1) + j] *= inv;
        }
        __syncthreads();
        for (int idx = tid; idx < RQ * HD; idx += 256) {
            const int r = idx >> 5;
            const int d = idx & 31;
            float acc = 0.f;
            for (int j = 0; j < LK; ++j)
                acc += SP[r * (LK + 1) + j] * VsP[j * 33 + d];
            O[((size_t)(b * LQ + q0 + r)) * DIM + h * HD + d] = acc;
        }
        __syncthreads();
    }
}

__global__ __launch_bounds__(256) void pre_kernel(
    const float* __restrict__ inner, const float* __restrict__ root,
    const float* __restrict__ w_in, const float* __restrict__ b_in,
    const float* __restrict__ w_out, const float* __restrict__ b_out,
    float* __restrict__ tP, float* __restrict__ Op, float* __restrict__ Osf,
    float* __restrict__ Ors, float* __restrict__ Orc)
{
    extern __shared__ float smf[];
    const int bid = blockIdx.x;
    const size_t WI = 768 * 256, BI = 768;
    if (bid < 2048)
        leafp_body(bid, inner, w_in, b_in, w_out, b_out, tP);
    else if (bid < 2176)
        attn_body<128, 16, 32>(bid - 2048, inner, root, w_in + 2 * WI, b_in + 2 * BI, Op, smf);
    else if (bid < 2304)
        attn_body<128, 128, 16>(bid - 2176, inner, inner, w_in + 3 * WI, b_in + 3 * BI, Osf, smf);
    else if (bid < 2432)
        attn_body<16, 16, 16>(bid - 2304, root, root, w_in + 5 * WI, b_in + 5 * BI, Ors, smf);
    else
        attn_body<16, 128, 16>(bid - 2432, root, inner, w_in + 5 * WI, b_in + 5 * BI, Orc, smf);
}

// ---------------------------------------------------------------------------
// epilogue bodies
// ---------------------------------------------------------------------------
__device__ void combleaf_body(int bid, const __bf16* __restrict__ O1,
                              const __bf16* __restrict__ Wob,
                              const float* __restrict__ Bo1,
                              const float* __restrict__ tP,
                              const float* __restrict__ wleaf,
                              float* __restrict__ out, char* __restrict__ sm)
{
    const int tid  = threadIdx.x;
    const int wid  = tid >> 6;
    const int lane = tid & 63;
    const int lr   = lane & 15;
    const int lk   = (lane >> 4) * 8;
    __bf16* Bs = (__bf16*)sm;           // [2][16][264]
    const int srow = tid >> 5;          // 0..7
    const int scol = (tid & 31) * 8;

    bf16x8 a[8];
    {
        const __bf16* ar = O1 + ((size_t)bid * 64 + wid * 16 + lr) * DIM + lk;
#pragma unroll
        for (int k = 0; k < 8; ++k) a[k] = *(const bf16x8*)(ar + k * 32);
    }
    const float e0 = __expf(wleaf[0]), e1 = __expf(wleaf[1]);
    const float wl0 = e0 / (e0 + e1), wl1 = e1 / (e0 + e1);
    const size_t row0 = (size_t)bid * 64 + wid * 16 + (lane >> 4) * 4;

    {   // stage tile 0
        bf16x8 g0 = *(const bf16x8*)(Wob + (size_t)srow * DIM + scol);
        bf16x8 g1 = *(const bf16x8*)(Wob + (size_t)(8 + srow) * DIM + scol);
        *(bf16x8*)(Bs + srow * 264 + scol) = g0;
        *(bf16x8*)(Bs + (8 + srow) * 264 + scol) = g1;
    }
    __syncthreads();

    for (int nt = 0; nt < 16; ++nt) {
        const int cur = nt & 1;
        const __bf16* Bc = Bs + cur * 4224;
        bf16x8 g0, g1;
        if (nt + 1 < 16) {
            const __bf16* p = Wob + (size_t)((nt + 1) * 16) * DIM;
            g0 = *(const bf16x8*)(p + (size_t)srow * DIM + scol);
            g1 = *(const bf16x8*)(p + (size_t)(8 + srow) * DIM + scol);
        }
        f32x4 acc = {0.f, 0.f, 0.f, 0.f};
#pragma unroll
        for (int k = 0; k < 8; ++k)
            acc = __builtin_amdgcn_mfma_f32_16x16x32_bf16(
                a[k], *(const bf16x8*)(Bc + lr * 264 + k * 32 + lk), acc, 0, 0, 0);
        const int   o  = nt * 16 + lr;
        const float bo = Bo1[o];
        const float tv = tP[(size_t)bid * DIM + o];
#pragma unroll
        for (int r = 0; r < 4; ++r)
            out[(row0 + r) * DIM + o] = wl0 * tv + wl1 * (acc[r] + bo);
        if (nt + 1 < 16) {
            __bf16* Bn = Bs + (cur ^ 1) * 4224;
            *(bf16x8*)(Bn + srow * 264 + scol) = g0;
            *(bf16x8*)(Bn + (8 + srow) * 264 + scol) = g1;
        }
        __syncthreads();
    }
}

__device__ void combine_inner_body(int vb, const float* __restrict__ Op,
    const float* __restrict__ Osf, const float* __restrict__ Oc,
    const float* __restrict__ W2, const float* __restrict__ B2,
    const float* __restrict__ W3, const float* __restrict__ B3,
    const float* __restrict__ W4, const float* __restrict__ B4,
    const float* __restrict__ winner, float* __restrict__ out, float* __restrict__ Ts)
{
    const int n0 = vb * 32;
    const int o  = threadIdx.x;
    const float e0 = __expf(winner[0]), e1 = __expf(winner[1]), e2 = __expf(winner[2]);
    const float inv = 1.f / (e0 + e1 + e2);
    const float wt0 = e0 * inv, wt1 = e1 * inv, wt2 = e2 * inv;

    float acc[32];
#pragma unroll
    for (int r = 0; r < 32; ++r) acc[r] = 0.f;
    const float biasacc = wt0 * B2[o] + wt1 * B3[o] + wt2 * B4[o];

#pragma unroll
    for (int term = 0; term < 3; ++term) {
        const float* Ob = (term == 0) ? Op : (term == 1) ? Osf : Oc;
        const float* Wb = (term == 0) ? W2 : (term == 1) ? W3 : W4;
        const float wt  = (term == 0) ? wt0 : (term == 1) ? wt1 : wt2;
        __syncthreads();
        for (int idx = threadIdx.x; idx < 32 * DIM; idx += 256)
            Ts[idx] = Ob[(size_t)n0 * DIM + idx];
        __syncthreads();
        const float4* wr = (const float4*)(Wb + (size_t)o * DIM);
        for (int k4 = 0; k4 < DIM / 4; ++k4) {
            float4 w = wr[k4];
            w.x *= wt; w.y *= wt; w.z *= wt; w.w *= wt;
#pragma unroll
            for (int r = 0; r < 32; ++r) {
                const float4 aa = *(const float4*)&Ts[r * DIM + k4 * 4];
                acc[r] += dot4(aa, w);
            }
        }
    }
#pragma unroll
    for (int r = 0; r < 32; ++r)
        out[(size_t)(n0 + r) * DIM + o] = acc[r] + biasacc;
}

__device__ void combine_root_body(int vb, const float* __restrict__ Ors,
    const float* __restrict__ Orc, const float* __restrict__ W5,
    const float* __restrict__ B5, const float* __restrict__ wroot,
    float* __restrict__ out, float* __restrict__ Ts)
{
    const int n0 = vb * 32;
    const int o  = threadIdx.x;
    const float e0 = __expf(wroot[0]), e1 = __expf(wroot[1]);
    const float w0 = e0 / (e0 + e1), w1 = e1 / (e0 + e1);
    for (int idx = threadIdx.x; idx < 32 * DIM; idx += 256)
        Ts[idx] = w0 * Ors[(size_t)n0 * DIM + idx] + w1 * Orc[(size_t)n0 * DIM + idx];
    __syncthreads();
    float acc[32];
#pragma unroll
    for (int r = 0; r < 32; ++r) acc[r] = 0.f;
    const float4* wr = (const float4*)(W5 + (size_t)o * DIM);
    for (int k4 = 0; k4 < DIM / 4; ++k4) {
        const float4 w = wr[k4];
#pragma unroll
        for (int r = 0; r < 32; ++r) {
            const float4 aa = *(const float4*)&Ts[r * DIM + k4 * 4];
            acc[r] += dot4(aa, w);
        }
    }
    const float bo = B5[o];
#pragma unroll
    for (int r = 0; r < 32; ++r)
        out[(size_t)(n0 + r) * DIM + o] = acc[r] + bo;
}

__global__ __launch_bounds__(256) void epilogue_kernel(
    const __bf16* __restrict__ O1, const __bf16* __restrict__ Wo1b,
    const float* __restrict__ w_out, const float* __restrict__ b_out,
    const float* __restrict__ tP, const float* __restrict__ Op,
    const float* __restrict__ Osf, const float* __restrict__ Oc,
    const float* __restrict__ Ors, const float* __restrict__ Orc,
    const float* __restrict__ wleaf, const float* __restrict__ winner,
    const float* __restrict__ wroot, float* __restrict__ out)
{
    extern __shared__ float smf[];
    const int bid = blockIdx.x;
    const size_t WO = 256 * 256, BO = 256;
    if (bid < 2048)
        combleaf_body(bid, O1, Wo1b, b_out + BO, tP, wleaf, out, (char*)smf);
    else if (bid < 2112)
        combine_inner_body(bid - 2048, Op, Osf, Oc,
                           w_out + 2 * WO, b_out + 2 * BO,
                           w_out + 3 * WO, b_out + 3 * BO,
                           w_out + 4 * WO, b_out + 4 * BO,
                           winner, out + 33554432, smf);
    else
        combine_root_body(bid - 2112, Ors, Orc, w_out + 5 * WO, b_out + 5 * BO,
                          wroot, out + 33554432 + 524288, smf);
}

// ---------------------------------------------------------------------------
extern "C" void kernel_launch(void* const* d_in, const int* in_sizes, int n_in,
                              void* d_out, int out_size, void* d_ws, size_t ws_size,
                              hipStream_t stream)
{
    const float* leaf   = (const float*)d_in[0];
    const float* inner  = (const float*)d_in[1];
    const float* root   = (const float*)d_in[2];
    const float* w_in   = (const float*)d_in[3];
    const float* b_in   = (const float*)d_in[4];
    const float* w_out  = (const float*)d_in[5];
    const float* b_out  = (const float*)d_in[6];
    const float* wleaf  = (const float*)d_in[7];
    const float* winner = (const float*)d_in[8];
    const float* wroot  = (const float*)d_in[9];
    float* out = (float*)d_out;

    const size_t WI = 768 * 256, BI = 768, WO = 256 * 256;

    // ws layout
    char* ws = (char*)d_ws;
    __bf16* W1b   = (__bf16*)(ws);                    // 393216 B
    __bf16* W4kvb = (__bf16*)(ws + 393216);           // 262144 B
    __bf16* Wo1b  = (__bf16*)(ws + 655360);           // 131072 B
    __bf16* O1b   = (__bf16*)(ws + 786432);           // 67108864 B
    float*  tP    = (float*)(ws + 67895296);          // 2097152 B
    float*  Oc    = (float*)(ws + 69992448);
    float*  Op    = (float*)(ws + 72089600);
    float*  Osf   = (float*)(ws + 74186752);
    float*  Ors   = (float*)(ws + 76283904);
    float*  Orc   = (float*)(ws + 76546048);

    cvt_f2b<<<192, 256, 0, stream>>>(w_in + 1 * WI, W1b, 768 * 256);
    cvt_f2b<<<128, 256, 0, stream>>>(w_in + 4 * WI + 256 * 256, W4kvb, 512 * 256);
    cvt_f2b<<<64, 256, 0, stream>>>(w_out + 1 * WO, Wo1b, 256 * 256);

    // pre: leafp + 4 small fp32 attention paths (one launch)
    pre_kernel<<<2560, 256, 58944, stream>>>(inner, root, w_in, b_in, w_out, b_out,
                                             tP, Op, Osf, Ors, Orc);

    // mega2: leaf QKV/K4V4 proj (LDS-staged weights) + leaf_s attn + inner_c
    mega2<<<8192, 256, 0, stream>>>(leaf, inner, W1b, b_in + 1 * BI, W4kvb,
                                    w_in + 4 * WI, b_in + 4 * BI, O1b, Oc);

    // epilogue: combleaf (LDS-staged Wo) + combine_inner + combine_root
    epilogue_kernel<<<2120, 256, 32768, stream>>>(O1b, Wo1b, w_out, b_out, tP,
                                                  Op, Osf, Oc, Ors, Orc,
                                                  wleaf, winner, wroot, out);
}

// Round 8
// 728.582 us; speedup vs baseline: 9.5990x; 1.3822x over previous
//
#include <hip/hip_runtime.h>
#include <hip/hip_bf16.h>
#include <cstdint>

// AttnLayerBU round 8: single fused_main launch = mega2 (8192 blocks, verbatim
// r7 body) + 4 fp32 attn paths (512 blocks) + leafp as MFMA 2-stage GEMM
// (32 blocks), aux blocks first so they hide under mega2. Epilogue unchanged.

#define DIM 256
#define NH 8
#define HD 32

static constexpr float SCALE = 0.17677669529663687f; // 32^-0.5

typedef __bf16 bf16x8 __attribute__((ext_vector_type(8)));
typedef __bf16 bf16x4 __attribute__((ext_vector_type(4)));
typedef float  f32x4  __attribute__((ext_vector_type(4)));

__device__ __forceinline__ float dot4(const float4 a, const float4 b) {
    return a.x * b.x + a.y * b.y + a.z * b.z + a.w * b.w;
}

// ---------------------------------------------------------------------------
__global__ __launch_bounds__(256) void cvt_f2b(const float* __restrict__ s,
                                               __bf16* __restrict__ d, int n) {
    int i = (blockIdx.x * 256 + threadIdx.x) * 4;
    if (i < n) {
        float4 v = *(const float4*)(s + i);
        d[i + 0] = (__bf16)v.x; d[i + 1] = (__bf16)v.y;
        d[i + 2] = (__bf16)v.z; d[i + 3] = (__bf16)v.w;
    }
}

// ---------------------------------------------------------------------------
// mega2 body (r7 verbatim, smem passed in)
// LDS (74496 B): Qs[64][72]@0  Ks@9216  Vt@18432  K4t@27648  V4t@36864
//   Pw 4x[16][72]@46080  scratch@55296(2304)  Bs[2][16][264]@57600(16896)
// ---------------------------------------------------------------------------
__device__ void mega2_body(int g,
    const float* __restrict__ X, const float* __restrict__ inner,
    const __bf16* __restrict__ W1b, const float* __restrict__ Bi1,
    const __bf16* __restrict__ W4kvb, const float* __restrict__ W4q,
    const float* __restrict__ Bi4, __bf16* __restrict__ O1,
    float* __restrict__ Oc, char* __restrict__ smem)
{
    const int xcd  = g & 7;
    const int idx  = g >> 3;               // 0..1023
    const int b    = xcd * 256 + (idx >> 2);
    const int hg   = idx & 3;              // head-pair: heads 2hg, 2hg+1
    const int tid  = threadIdx.x;
    const int wid  = tid >> 6;             // 0..3
    const int lane = tid & 63;
    const int lr   = lane & 15;
    const int lk   = (lane >> 4) * 8;
    const int prow = (lane >> 4) * 4;
    const int tok0 = wid * 16 + prow;

    __bf16* Qs  = (__bf16*)smem;                    // [64][72]
    __bf16* Ks  = (__bf16*)(smem + 9216);
    __bf16* Vt  = (__bf16*)(smem + 18432);          // [64 d][72 tok]
    __bf16* K4t = (__bf16*)(smem + 27648);
    __bf16* V4t = (__bf16*)(smem + 36864);
    __bf16* Pw  = (__bf16*)(smem + 46080 + wid * 2304);  // wave-local [16][72]
    float* qpart = (float*)(smem + 55296);          // [4][64]
    float* qv    = qpart + 256;                     // [64]
    float* psm   = qv + 64;                         // [2][64]
    float* opart = psm + 128;                       // [2][64]
    __bf16* Bs  = (__bf16*)(smem + 57600);          // [2][16][264]

    // ---- A-fragments ----
    bf16x8 a[8];
    {
        const float* xrow = X + ((size_t)b * 64 + wid * 16 + lr) * DIM + lk;
#pragma unroll
        for (int k = 0; k < 8; ++k) {
            float4 v0 = *(const float4*)(xrow + k * 32);
            float4 v1 = *(const float4*)(xrow + k * 32 + 4);
            bf16x8 t;
            t[0] = (__bf16)v0.x; t[1] = (__bf16)v0.y; t[2] = (__bf16)v0.z; t[3] = (__bf16)v0.w;
            t[4] = (__bf16)v1.x; t[5] = (__bf16)v1.y; t[6] = (__bf16)v1.z; t[7] = (__bf16)v1.w;
            a[k] = t;
        }
    }

    // ---- unified projection loop: 20 n-tiles, LDS double-buffered B ----
    {
        const int srow = tid >> 5;              // 0..7
        const int scol = (tid & 31) * 8;        // bf16 elems
        auto wsrc = [&](int t) -> const __bf16* {
            if (t < 12) {
                const int sec = t >> 2, sub = t & 3;
                return W1b + (size_t)(sec * 256 + hg * 64 + sub * 16) * DIM;
            }
            const int u = t - 12, sec = u >> 2, sub = u & 3;
            return W4kvb + (size_t)(sec * 256 + hg * 64 + sub * 16) * DIM;
        };
        {
            const __bf16* p = wsrc(0);
            bf16x8 g0 = *(const bf16x8*)(p + (size_t)srow * DIM + scol);
            bf16x8 g1 = *(const bf16x8*)(p + (size_t)(8 + srow) * DIM + scol);
            *(bf16x8*)(Bs + srow * 264 + scol) = g0;
            *(bf16x8*)(Bs + (8 + srow) * 264 + scol) = g1;
        }
        __syncthreads();

        for (int t = 0; t < 20; ++t) {
            const int cur = t & 1;
            const __bf16* Bc = Bs + cur * 4224;
            bf16x8 g0, g1;
            if (t + 1 < 20) {
                const __bf16* p = wsrc(t + 1);
                g0 = *(const bf16x8*)(p + (size_t)srow * DIM + scol);
                g1 = *(const bf16x8*)(p + (size_t)(8 + srow) * DIM + scol);
            }
            f32x4 aL = {0.f, 0.f, 0.f, 0.f}, aH = {0.f, 0.f, 0.f, 0.f};
#pragma unroll
            for (int kk = 0; kk < 4; ++kk) {
                const bf16x8 bL = *(const bf16x8*)(Bc + lr * 264 + kk * 32 + lk);
                aL = __builtin_amdgcn_mfma_f32_16x16x32_bf16(a[kk], bL, aL, 0, 0, 0);
            }
#pragma unroll
            for (int kk = 0; kk < 4; ++kk) {
                const bf16x8 bH = *(const bf16x8*)(Bc + lr * 264 + (kk + 4) * 32 + lk);
                aH = __builtin_amdgcn_mfma_f32_16x16x32_bf16(a[kk + 4], bH, aH, 0, 0, 0);
            }
            const f32x4 acc = aL + aH;
            const int sub = t & 3;
            const int col = sub * 16 + lr;
            if (t < 4) {
                const float bias = Bi1[hg * 64 + sub * 16 + lr];
#pragma unroll
                for (int r = 0; r < 4; ++r)
                    Qs[(size_t)(tok0 + r) * 72 + col] = (__bf16)((acc[r] + bias) * SCALE);
            } else if (t < 8) {
                const float bias = Bi1[256 + hg * 64 + sub * 16 + lr];
#pragma unroll
                for (int r = 0; r < 4; ++r)
                    Ks[(size_t)(tok0 + r) * 72 + col] = (__bf16)(acc[r] + bias);
            } else {
                bf16x4 pv;
                if (t < 12) {
                    const float bias = Bi1[512 + hg * 64 + sub * 16 + lr];
#pragma unroll
                    for (int r = 0; r < 4; ++r) pv[r] = (__bf16)(acc[r] + bias);
                    *(bf16x4*)(Vt + (size_t)col * 72 + tok0) = pv;
                } else if (t < 16) {
                    const float bias = Bi4[256 + hg * 64 + sub * 16 + lr];
#pragma unroll
                    for (int r = 0; r < 4; ++r) pv[r] = (__bf16)(acc[r] + bias);
                    *(bf16x4*)(K4t + (size_t)col * 72 + tok0) = pv;
                } else {
                    const float bias = Bi4[512 + hg * 64 + sub * 16 + lr];
#pragma unroll
                    for (int r = 0; r < 4; ++r) pv[r] = (__bf16)(acc[r] + bias);
                    *(bf16x4*)(V4t + (size_t)col * 72 + tok0) = pv;
                }
            }
            if (t + 1 < 20) {
                __bf16* Bn = Bs + (cur ^ 1) * 4224;
                *(bf16x8*)(Bn + srow * 264 + scol) = g0;
                *(bf16x8*)(Bn + (8 + srow) * 264 + scol) = g1;
            }
            __syncthreads();
        }
    }

    // ---- inner_c q-projection partials ----
    {
        const int o = tid & 63, part = tid >> 6;
        const float4* wr = (const float4*)(W4q + (size_t)(hg * 64 + o) * DIM + part * 64);
        const float4* xr = (const float4*)(inner + (size_t)b * DIM + part * 64);
        float accq = 0.f;
#pragma unroll
        for (int k = 0; k < 16; ++k) accq += dot4(xr[k], wr[k]);
        qpart[part * 64 + o] = accq;
    }
    __syncthreads();

    if (tid < 64)
        qv[tid] = (qpart[tid] + qpart[64 + tid] + qpart[128 + tid] + qpart[192 + tid]
                   + Bi4[hg * 64 + tid]) * SCALE;

    // ---- leaf_s attention: wave = (head hh, q-half qh) ----
    const int hh = wid >> 1;
    const int qh = wid & 1;
    f32x4 s[2][4];
    {
        bf16x8 kb[4];
#pragma unroll
        for (int kt = 0; kt < 4; ++kt)
            kb[kt] = *(const bf16x8*)(Ks + (size_t)(kt * 16 + lr) * 72 + hh * 32 + lk);
#pragma unroll
        for (int q2 = 0; q2 < 2; ++q2) {
            const int qt = qh * 2 + q2;
            const bf16x8 qa = *(const bf16x8*)(Qs + (size_t)(qt * 16 + lr) * 72 + hh * 32 + lk);
#pragma unroll
            for (int kt = 0; kt < 4; ++kt) {
                f32x4 z = {0.f, 0.f, 0.f, 0.f};
                s[q2][kt] = __builtin_amdgcn_mfma_f32_16x16x32_bf16(qa, kb[kt], z, 0, 0, 0);
            }
        }
    }
#pragma unroll
    for (int q2 = 0; q2 < 2; ++q2) {
#pragma unroll
        for (int r = 0; r < 4; ++r) {
            float m = fmaxf(fmaxf(s[q2][0][r], s[q2][1][r]), fmaxf(s[q2][2][r], s[q2][3][r]));
#pragma unroll
            for (int off = 1; off < 16; off <<= 1) m = fmaxf(m, __shfl_xor(m, off));
            const float p0 = __expf(s[q2][0][r] - m), p1 = __expf(s[q2][1][r] - m);
            const float p2 = __expf(s[q2][2][r] - m), p3 = __expf(s[q2][3][r] - m);
            float t = p0 + p1 + p2 + p3;
#pragma unroll
            for (int off = 1; off < 16; off <<= 1) t += __shfl_xor(t, off);
            const float inv = 1.0f / t;
            s[q2][0][r] = p0 * inv; s[q2][1][r] = p1 * inv;
            s[q2][2][r] = p2 * inv; s[q2][3][r] = p3 * inv;
        }
    }
    {
        bf16x8 vb[2][2];
#pragma unroll
        for (int dt = 0; dt < 2; ++dt)
#pragma unroll
            for (int ks = 0; ks < 2; ++ks)
                vb[dt][ks] = *(const bf16x8*)(Vt + (size_t)(hh * 32 + dt * 16 + lr) * 72 + ks * 32 + lk);
#pragma unroll
        for (int q2 = 0; q2 < 2; ++q2) {
            const int qt = qh * 2 + q2;
#pragma unroll
            for (int kt = 0; kt < 4; ++kt)
#pragma unroll
                for (int r = 0; r < 4; ++r)
                    Pw[(size_t)(prow + r) * 72 + kt * 16 + lr] = (__bf16)s[q2][kt][r];
            bf16x8 pa[2];
#pragma unroll
            for (int ks = 0; ks < 2; ++ks)
                pa[ks] = *(const bf16x8*)(Pw + (size_t)lr * 72 + ks * 32 + lk);
#pragma unroll
            for (int dt = 0; dt < 2; ++dt) {
                f32x4 o = {0.f, 0.f, 0.f, 0.f};
#pragma unroll
                for (int ks = 0; ks < 2; ++ks)
                    o = __builtin_amdgcn_mfma_f32_16x16x32_bf16(pa[ks], vb[dt][ks], o, 0, 0, 0);
                const int colO = (hg * 2 + hh) * 32 + dt * 16 + lr;
#pragma unroll
                for (int r = 0; r < 4; ++r)
                    O1[((size_t)b * 64 + qt * 16 + prow + r) * DIM + colO] = (__bf16)o[r];
            }
        }
    }
    __syncthreads();

    if (wid < 2) {
        const int j = lane;
        float sv = 0.f;
#pragma unroll
        for (int d = 0; d < 32; ++d)
            sv += qv[wid * 32 + d] * (float)K4t[(size_t)(wid * 32 + d) * 72 + j];
        float m = sv;
#pragma unroll
        for (int off = 1; off < 64; off <<= 1) m = fmaxf(m, __shfl_xor(m, off));
        const float p = __expf(sv - m);
        float t = p;
#pragma unroll
        for (int off = 1; off < 64; off <<= 1) t += __shfl_xor(t, off);
        psm[wid * 64 + j] = p / t;
    }
    __syncthreads();

    if (tid < 128) {
        const int o = tid & 63, hf = tid >> 6;
        const int ho = o >> 5;
        float acc2 = 0.f;
#pragma unroll
        for (int j = 0; j < 32; ++j)
            acc2 += psm[ho * 64 + hf * 32 + j] * (float)V4t[(size_t)o * 72 + hf * 32 + j];
        opart[hf * 64 + o] = acc2;
    }
    __syncthreads();
    if (tid < 64)
        Oc[(size_t)b * DIM + hg * 64 + tid] = opart[tid] + opart[64 + tid];
}

// ---------------------------------------------------------------------------
// leafp as MFMA 2-stage GEMM: tP = (inner @ Wv0^T + bv0) @ Wo0^T + bo0
// LDS: tV[64][264]@0 (33792)  Bs[2][16][264]@33792 (16896)
// ---------------------------------------------------------------------------
__device__ void leafp_mfma_body(int bid, const float* __restrict__ inner,
    const __bf16* __restrict__ Wv0b, const __bf16* __restrict__ Wo0b,
    const float* __restrict__ b_in0, const float* __restrict__ b_out0,
    float* __restrict__ tP, char* __restrict__ smem)
{
    __bf16* tV = (__bf16*)smem;             // [64][264]
    __bf16* Bs = (__bf16*)(smem + 33792);   // [2][16][264]
    const int tid  = threadIdx.x;
    const int wid  = tid >> 6;
    const int lane = tid & 63;
    const int lr   = lane & 15;
    const int lk   = (lane >> 4) * 8;
    const int prow = (lane >> 4) * 4;
    const int tok0 = wid * 16 + prow;
    const int srow = tid >> 5;
    const int scol = (tid & 31) * 8;

    // stage-1 A-frags: inner rows fp32 -> bf16
    bf16x8 a[8];
    {
        const float* xrow = inner + ((size_t)bid * 64 + wid * 16 + lr) * DIM + lk;
#pragma unroll
        for (int k = 0; k < 8; ++k) {
            float4 v0 = *(const float4*)(xrow + k * 32);
            float4 v1 = *(const float4*)(xrow + k * 32 + 4);
            bf16x8 t;
            t[0] = (__bf16)v0.x; t[1] = (__bf16)v0.y; t[2] = (__bf16)v0.z; t[3] = (__bf16)v0.w;
            t[4] = (__bf16)v1.x; t[5] = (__bf16)v1.y; t[6] = (__bf16)v1.z; t[7] = (__bf16)v1.w;
            a[k] = t;
        }
    }

    // ---- stage 1: tV = inner @ Wv0^T + bv0  (16 tiles, dbuf staging) ----
    {
        bf16x8 g0 = *(const bf16x8*)(Wv0b + (size_t)srow * DIM + scol);
        bf16x8 g1 = *(const bf16x8*)(Wv0b + (size_t)(8 + srow) * DIM + scol);
        *(bf16x8*)(Bs + srow * 264 + scol) = g0;
        *(bf16x8*)(Bs + (8 + srow) * 264 + scol) = g1;
    }
    __syncthreads();
    for (int t = 0; t < 16; ++t) {
        const int cur = t & 1;
        const __bf16* Bc = Bs + cur * 4224;
        bf16x8 g0, g1;
        if (t + 1 < 16) {
            const __bf16* p = Wv0b + (size_t)((t + 1) * 16) * DIM;
            g0 = *(const bf16x8*)(p + (size_t)srow * DIM + scol);
            g1 = *(const bf16x8*)(p + (size_t)(8 + srow) * DIM + scol);
        }
        f32x4 acc = {0.f, 0.f, 0.f, 0.f};
#pragma unroll
        for (int k = 0; k < 8; ++k)
            acc = __builtin_amdgcn_mfma_f32_16x16x32_bf16(
                a[k], *(const bf16x8*)(Bc + lr * 264 + k * 32 + lk), acc, 0, 0, 0);
        const float bias = b_in0[512 + t * 16 + lr];
#pragma unroll
        for (int r = 0; r < 4; ++r)
            tV[(size_t)(tok0 + r) * 264 + t * 16 + lr] = (__bf16)(acc[r] + bias);
        if (t + 1 < 16) {
            __bf16* Bn = Bs + (cur ^ 1) * 4224;
            *(bf16x8*)(Bn + srow * 264 + scol) = g0;
            *(bf16x8*)(Bn + (8 + srow) * 264 + scol) = g1;
        }
        __syncthreads();
    }

    // ---- stage 2: tP = tV @ Wo0^T + bo0 ----
    bf16x8 a2[8];
#pragma unroll
    for (int k = 0; k < 8; ++k)
        a2[k] = *(const bf16x8*)(tV + (size_t)(wid * 16 + lr) * 264 + k * 32 + lk);
    {
        bf16x8 g0 = *(const bf16x8*)(Wo0b + (size_t)srow * DIM + scol);
        bf16x8 g1 = *(const bf16x8*)(Wo0b + (size_t)(8 + srow) * DIM + scol);
        *(bf16x8*)(Bs + srow * 264 + scol) = g0;
        *(bf16x8*)(Bs + (8 + srow) * 264 + scol) = g1;
    }
    __syncthreads();
    for (int t = 0; t < 16; ++t) {
        const int cur = t & 1;
        const __bf16* Bc = Bs + cur * 4224;
        bf16x8 g0, g1;
        if (t + 1 < 16) {
            const __bf16* p = Wo0b + (size_t)((t + 1) * 16) * DIM;
            g0 = *(const bf16x8*)(p + (size_t)srow * DIM + scol);
            g1 = *(const bf16x8*)(p + (size_t)(8 + srow) * DIM + scol);
        }
        f32x4 acc = {0.f, 0.f, 0.f, 0.f};
#pragma unroll
        for (int k = 0; k < 8; ++k)
            acc = __builtin_amdgcn_mfma_f32_16x16x32_bf16(
                a2[k], *(const bf16x8*)(Bc + lr * 264 + k * 32 + lk), acc, 0, 0, 0);
        const float bo = b_out0[t * 16 + lr];
#pragma unroll
        for (int r = 0; r < 4; ++r)
            tP[((size_t)bid * 64 + wid * 16 + prow + r) * DIM + t * 16 + lr] = acc[r] + bo;
        if (t + 1 < 16) {
            __bf16* Bn = Bs + (cur ^ 1) * 4224;
            *(bf16x8*)(Bn + srow * 264 + scol) = g0;
            *(bf16x8*)(Bn + (8 + srow) * 264 + scol) = g1;
        }
        __syncthreads();
    }
}

// ---------------------------------------------------------------------------
// fp32 fused attention body (r7 verbatim)
// ---------------------------------------------------------------------------
template <int LQ, int LK, int RQ>
__device__ void attn_body(int bx, const float* __restrict__ Xq,
                          const float* __restrict__ Xkv,
                          const float* __restrict__ Wi, const float* __restrict__ Bi,
                          float* __restrict__ O, float* __restrict__ sm)
{
    const int b   = bx >> 3;
    const int h   = bx & 7;
    const int tid = threadIdx.x;

    float* KsP = sm;                    // [LK][33]
    float* VsP = KsP + LK * 33;         // [LK][33]
    float* QsP = VsP + LK * 33;         // [LQ][33]
    float* SP  = QsP + LQ * 33;         // [RQ][LK+1]

    const float* xq  = Xq  + (size_t)b * LQ * DIM;
    const float* xkv = Xkv + (size_t)b * LK * DIM;

    {
        const int col   = tid & 63;
        const int which = col >> 5;
        const int d     = col & 31;
        const int row   = DIM + which * DIM + h * HD + d;
        const float4* wr = (const float4*)(Wi + (size_t)row * DIM);
        const float bias = Bi[row];
        constexpr int TT = LK / 4;
        float acc[TT];
#pragma unroll
        for (int i = 0; i < TT; ++i) acc[i] = 0.f;
        const int t0 = tid >> 6;
        for (int k4 = 0; k4 < DIM / 4; ++k4) {
            const float4 w = wr[k4];
#pragma unroll
            for (int i = 0; i < TT; ++i) {
                const int t = t0 + 4 * i;
                const float4 aa = ((const float4*)(xkv + (size_t)t * DIM))[k4];
                acc[i] += dot4(aa, w);
            }
        }
#pragma unroll
        for (int i = 0; i < TT; ++i) {
            const int t = t0 + 4 * i;
            if (which == 0) KsP[t * 33 + d] = acc[i] + bias;
            else            VsP[t * 33 + d] = acc[i] + bias;
        }
    }
    {
        constexpr int TGQ = (LQ >= 8) ? 8 : LQ;
        constexpr int TT  = LQ / TGQ;
        if (tid < 32 * TGQ) {
            const int d   = tid & 31;
            const int row = h * HD + d;
            const float4* wr = (const float4*)(Wi + (size_t)row * DIM);
            const float bias = Bi[row];
            float acc[TT];
#pragma unroll
            for (int i = 0; i < TT; ++i) acc[i] = 0.f;
            const int t0 = tid >> 5;
            for (int k4 = 0; k4 < DIM / 4; ++k4) {
                const float4 w = wr[k4];
#pragma unroll
                for (int i = 0; i < TT; ++i) {
                    const int t = t0 + TGQ * i;
                    const float4 aa = ((const float4*)(xq + (size_t)t * DIM))[k4];
                    acc[i] += dot4(aa, w);
                }
            }
#pragma unroll
            for (int i = 0; i < TT; ++i) {
                const int t = t0 + TGQ * i;
                QsP[t * 33 + d] = (acc[i] + bias) * SCALE;
            }
        }
    }
    __syncthreads();

    for (int q0 = 0; q0 < LQ; q0 += RQ) {
        for (int idx = tid; idx < RQ * LK; idx += 256) {
            const int r = idx / LK;
            const int j = idx - r * LK;
            float acc = 0.f;
#pragma unroll
            for (int d = 0; d < HD; ++d)
                acc += QsP[(q0 + r) * 33 + d] * KsP[j * 33 + d];
            SP[r * (LK + 1) + j] = acc;
        }
        __syncthreads();
        if (tid < RQ * 8) {
            const int r   = tid >> 3;
            const int sub = tid & 7;
            float m = -1e30f;
            for (int j = sub; j < LK; j += 8) m = fmaxf(m, SP[r * (LK + 1) + j]);
#pragma unroll
            for (int off = 4; off; off >>= 1) m = fmaxf(m, __shfl_xor(m, off, 8));
            float sum = 0.f;
            for (int j = sub; j < LK; j += 8) {
                const float p = __expf(SP[r * (LK + 1) + j] - m);
                SP[r * (LK + 1) + j] = p;
                sum += p;
            }
#pragma unroll
            for (int off = 4; off; off >>= 1) sum += __shfl_xor(sum, off, 8);
            const float inv = 1.0f / sum;
            for (int j = sub; j < LK; j += 8) SP[r * (LK + 1) + j] *= inv;
        }
        __syncthreads();
        for (int idx = tid; idx < RQ * HD; idx += 256) {
            const int r = idx >> 5;
            const int d = idx & 31;
            float acc = 0.f;
            for (int j = 0; j < LK; ++j)
                acc += SP[r * (LK + 1) + j] * VsP[j * 33 + d];
            O[((size_t)(b * LQ + q0 + r)) * DIM + h * HD + d] = acc;
        }
        __syncthreads();
    }
}

// ---------------------------------------------------------------------------
// fused_main: aux blocks first (hide under mega2), then 8192 mega2 blocks.
// ---------------------------------------------------------------------------
__global__ __launch_bounds__(256, 2) void fused_main(
    const float* __restrict__ leaf, const float* __restrict__ inner,
    const float* __restrict__ root,
    const float* __restrict__ w_in, const float* __restrict__ b_in,
    const float* __restrict__ b_out,
    const __bf16* __restrict__ W1b, const __bf16* __restrict__ W4kvb,
    const __bf16* __restrict__ Wv0b, const __bf16* __restrict__ Wo0b,
    __bf16* __restrict__ O1, float* __restrict__ Oc, float* __restrict__ tP,
    float* __restrict__ Op, float* __restrict__ Osf,
    float* __restrict__ Ors, float* __restrict__ Orc)
{
    extern __shared__ __align__(16) char smem[];
    const int bid = blockIdx.x;
    const size_t WI = 768 * 256, BI = 768;
    if (bid < 128)
        attn_body<128, 128, 16>(bid, inner, inner, w_in + 3 * WI, b_in + 3 * BI,
                                Osf, (float*)smem);
    else if (bid < 256)
        attn_body<128, 16, 32>(bid - 128, inner, root, w_in + 2 * WI, b_in + 2 * BI,
                               Op, (float*)smem);
    else if (bid < 384)
        attn_body<16, 128, 16>(bid - 256, root, inner, w_in + 5 * WI, b_in + 5 * BI,
                               Orc, (float*)smem);
    else if (bid < 512)
        attn_body<16, 16, 16>(bid - 384, root, root, w_in + 5 * WI, b_in + 5 * BI,
                              Ors, (float*)smem);
    else if (bid < 544)
        leafp_mfma_body(bid - 512, inner, Wv0b, Wo0b, b_in, b_out, tP, smem);
    else
        mega2_body(bid - 544, leaf, inner, W1b, b_in + 1 * BI, W4kvb,
                   w_in + 4 * WI, b_in + 4 * BI, O1, Oc, smem);
}

// ---------------------------------------------------------------------------
// epilogue bodies (r7 verbatim)
// ---------------------------------------------------------------------------
__device__ void combleaf_body(int bid, const __bf16* __restrict__ O1,
                              const __bf16* __restrict__ Wob,
                              const float* __restrict__ Bo1,
                              const float* __restrict__ tP,
                              const float* __restrict__ wleaf,
                              float* __restrict__ out, char* __restrict__ sm)
{
    const int tid  = threadIdx.x;
    const int wid  = tid >> 6;
    const int lane = tid & 63;
    const int lr   = lane & 15;
    const int lk   = (lane >> 4) * 8;
    __bf16* Bs = (__bf16*)sm;           // [2][16][264]
    const int srow = tid >> 5;
    const int scol = (tid & 31) * 8;

    bf16x8 a[8];
    {
        const __bf16* ar = O1 + ((size_t)bid * 64 + wid * 16 + lr) * DIM + lk;
#pragma unroll
        for (int k = 0; k < 8; ++k) a[k] = *(const bf16x8*)(ar + k * 32);
    }
    const float e0 = __expf(wleaf[0]), e1 = __expf(wleaf[1]);
    const float wl0 = e0 / (e0 + e1), wl1 = e1 / (e0 + e1);
    const size_t row0 = (size_t)bid * 64 + wid * 16 + (lane >> 4) * 4;

    {
        bf16x8 g0 = *(const bf16x8*)(Wob + (size_t)srow * DIM + scol);
        bf16x8 g1 = *(const bf16x8*)(Wob + (size_t)(8 + srow) * DIM + scol);
        *(bf16x8*)(Bs + srow * 264 + scol) = g0;
        *(bf16x8*)(Bs + (8 + srow) * 264 + scol) = g1;
    }
    __syncthreads();

    for (int nt = 0; nt < 16; ++nt) {
        const int cur = nt & 1;
        const __bf16* Bc = Bs + cur * 4224;
        bf16x8 g0, g1;
        if (nt + 1 < 16) {
            const __bf16* p = Wob + (size_t)((nt + 1) * 16) * DIM;
            g0 = *(const bf16x8*)(p + (size_t)srow * DIM + scol);
            g1 = *(const bf16x8*)(p + (size_t)(8 + srow) * DIM + scol);
        }
        f32x4 acc = {0.f, 0.f, 0.f, 0.f};
#pragma unroll
        for (int k = 0; k < 8; ++k)
            acc = __builtin_amdgcn_mfma_f32_16x16x32_bf16(
                a[k], *(const bf16x8*)(Bc + lr * 264 + k * 32 + lk), acc, 0, 0, 0);
        const int   o  = nt * 16 + lr;
        const float bo = Bo1[o];
        const float tv = tP[(size_t)bid * DIM + o];
#pragma unroll
        for (int r = 0; r < 4; ++r)
            out[(row0 + r) * DIM + o] = wl0 * tv + wl1 * (acc[r] + bo);
        if (nt + 1 < 16) {
            __bf16* Bn = Bs + (cur ^ 1) * 4224;
            *(bf16x8*)(Bn + srow * 264 + scol) = g0;
            *(bf16x8*)(Bn + (8 + srow) * 264 + scol) = g1;
        }
        __syncthreads();
    }
}

__device__ void combine_inner_body(int vb, const float* __restrict__ Op,
    const float* __restrict__ Osf, const float* __restrict__ Oc,
    const float* __restrict__ W2, const float* __restrict__ B2,
    const float* __restrict__ W3, const float* __restrict__ B3,
    const float* __restrict__ W4, const float* __restrict__ B4,
    const float* __restrict__ winner, float* __restrict__ out, float* __restrict__ Ts)
{
    const int n0 = vb * 32;
    const int o  = threadIdx.x;
    const float e0 = __expf(winner[0]), e1 = __expf(winner[1]), e2 = __expf(winner[2]);
    const float inv = 1.f / (e0 + e1 + e2);
    const float wt0 = e0 * inv, wt1 = e1 * inv, wt2 = e2 * inv;

    float acc[32];
#pragma unroll
    for (int r = 0; r < 32; ++r) acc[r] = 0.f;
    const float biasacc = wt0 * B2[o] + wt1 * B3[o] + wt2 * B4[o];

#pragma unroll
    for (int term = 0; term < 3; ++term) {
        const float* Ob = (term == 0) ? Op : (term == 1) ? Osf : Oc;
        const float* Wb = (term == 0) ? W2 : (term == 1) ? W3 : W4;
        const float wt  = (term == 0) ? wt0 : (term == 1) ? wt1 : wt2;
        __syncthreads();
        for (int idx = threadIdx.x; idx < 32 * DIM; idx += 256)
            Ts[idx] = Ob[(size_t)n0 * DIM + idx];
        __syncthreads();
        const float4* wr = (const float4*)(Wb + (size_t)o * DIM);
        for (int k4 = 0; k4 < DIM / 4; ++k4) {
            float4 w = wr[k4];
            w.x *= wt; w.y *= wt; w.z *= wt; w.w *= wt;
#pragma unroll
            for (int r = 0; r < 32; ++r) {
                const float4 aa = *(const float4*)&Ts[r * DIM + k4 * 4];
                acc[r] += dot4(aa, w);
            }
        }
    }
#pragma unroll
    for (int r = 0; r < 32; ++r)
        out[(size_t)(n0 + r) * DIM + o] = acc[r] + biasacc;
}

__device__ void combine_root_body(int vb, const float* __restrict__ Ors,
    const float* __restrict__ Orc, const float* __restrict__ W5,
    const float* __restrict__ B5, const float* __restrict__ wroot,
    float* __restrict__ out, float* __restrict__ Ts)
{
    const int n0 = vb * 32;
    const int o  = threadIdx.x;
    const float e0 = __expf(wroot[0]), e1 = __expf(wroot[1]);
    const float w0 = e0 / (e0 + e1), w1 = e1 / (e0 + e1);
    for (int idx = threadIdx.x; idx < 32 * DIM; idx += 256)
        Ts[idx] = w0 * Ors[(size_t)n0 * DIM + idx] + w1 * Orc[(size_t)n0 * DIM + idx];
    __syncthreads();
    float acc[32];
#pragma unroll
    for (int r = 0; r < 32; ++r) acc[r] = 0.f;
    const float4* wr = (const float4*)(W5 + (size_t)o * DIM);
    for (int k4 = 0; k4 < DIM / 4; ++k4) {
        const float4 w = wr[k4];
#pragma unroll
        for (int r = 0; r < 32; ++r) {
            const float4 aa = *(const float4*)&Ts[r * DIM + k4 * 4];
            acc[r] += dot4(aa, w);
        }
    }
    const float bo = B5[o];
#pragma unroll
    for (int r = 0; r < 32; ++r)
        out[(size_t)(n0 + r) * DIM + o] = acc[r] + bo;
}

__global__ __launch_bounds__(256) void epilogue_kernel(
    const __bf16* __restrict__ O1, const __bf16* __restrict__ Wo1b,
    const float* __restrict__ w_out, const float* __restrict__ b_out,
    const float* __restrict__ tP, const float* __restrict__ Op,
    const float* __restrict__ Osf, const float* __restrict__ Oc,
    const float* __restrict__ Ors, const float* __restrict__ Orc,
    const float* __restrict__ wleaf, const float* __restrict__ winner,
    const float* __restrict__ wroot, float* __restrict__ out)
{
    extern __shared__ float smf[];
    const int bid = blockIdx.x;
    const size_t WO = 256 * 256, BO = 256;
    if (bid < 2048)
        combleaf_body(bid, O1, Wo1b, b_out + BO, tP, wleaf, out, (char*)smf);
    else if (bid < 2112)
        combine_inner_body(bid - 2048, Op, Osf, Oc,
                           w_out + 2 * WO, b_out + 2 * BO,
                           w_out + 3 * WO, b_out + 3 * BO,
                           w_out + 4 * WO, b_out + 4 * BO,
                           winner, out + 33554432, smf);
    else
        combine_root_body(bid - 2112, Ors, Orc, w_out + 5 * WO, b_out + 5 * BO,
                          wroot, out + 33554432 + 524288, smf);
}

// ---------------------------------------------------------------------------
extern "C" void kernel_launch(void* const* d_in, const int* in_sizes, int n_in,
                              void* d_out, int out_size, void* d_ws, size_t ws_size,
                              hipStream_t stream)
{
    const float* leaf   = (const float*)d_in[0];
    const float* inner  = (const float*)d_in[1];
    const float* root   = (const float*)d_in[2];
    const float* w_in   = (const float*)d_in[3];
    const float* b_in   = (const float*)d_in[4];
    const float* w_out  = (const float*)d_in[5];
    const float* b_out  = (const float*)d_in[6];
    const float* wleaf  = (const float*)d_in[7];
    const float* winner = (const float*)d_in[8];
    const float* wroot  = (const float*)d_in[9];
    float* out = (float*)d_out;

    const size_t WI = 768 * 256, WO = 256 * 256;

    // ws layout
    char* ws = (char*)d_ws;
    __bf16* W1b   = (__bf16*)(ws);                    // 393216 B
    __bf16* W4kvb = (__bf16*)(ws + 393216);           // 262144 B
    __bf16* Wo1b  = (__bf16*)(ws + 655360);           // 131072 B
    __bf16* Wv0b  = (__bf16*)(ws + 786432);           // 131072 B
    __bf16* Wo0b  = (__bf16*)(ws + 917504);           // 131072 B
    __bf16* O1b   = (__bf16*)(ws + 1048576);          // 67108864 B
    float*  tP    = (float*)(ws + 68157440);          // 2097152 B
    float*  Oc    = (float*)(ws + 70254592);
    float*  Op    = (float*)(ws + 72351744);
    float*  Osf   = (float*)(ws + 74448896);
    float*  Ors   = (float*)(ws + 76546048);
    float*  Orc   = (float*)(ws + 76808192);

    cvt_f2b<<<192, 256, 0, stream>>>(w_in + 1 * WI, W1b, 768 * 256);
    cvt_f2b<<<128, 256, 0, stream>>>(w_in + 4 * WI + 256 * 256, W4kvb, 512 * 256);
    cvt_f2b<<<64, 256, 0, stream>>>(w_out + 1 * WO, Wo1b, 256 * 256);
    cvt_f2b<<<64, 256, 0, stream>>>(w_in + 512 * 256, Wv0b, 256 * 256);
    cvt_f2b<<<64, 256, 0, stream>>>(w_out, Wo0b, 256 * 256);

    // fused main: aux (4 attn + leafp-MFMA) + mega2
    fused_main<<<8736, 256, 74496, stream>>>(
        leaf, inner, root, w_in, b_in, b_out, W1b, W4kvb, Wv0b, Wo0b,
        O1b, Oc, tP, Op, Osf, Ors, Orc);

    // epilogue: combleaf + combine_inner + combine_root
    epilogue_kernel<<<2120, 256, 32768, stream>>>(O1b, Wo1b, w_out, b_out, tP,
                                                  Op, Osf, Oc, Ors, Orc,
                                                  wleaf, winner, wroot, out);
}